// Round 1
// 307.250 us; speedup vs baseline: 1.0303x; 1.0303x over previous
//
#include <hip/hip_runtime.h>
#include <math.h>

#define N1 961
#define N2 960
#define KF 240
#define HW2 3844   // 62*62
#define NPIX 15376 // 4*62*62
#define XDSZ 492032 // 4*128*961
#define L2E 1.44269504f

typedef float v2f __attribute__((ext_vector_type(2)));

__global__ void k_zero(float* p, int n) {
  int i = blockIdx.x * 256 + threadIdx.x;
  if (i < n) p[i] = 0.f;
}

// down conv v4: 2x2 px x 4 co per thread, K-split x8 (1024 blocks = 4/CU).
__global__ __launch_bounds__(256) void k_down(const float* __restrict__ x,
                                              const float* __restrict__ w,
                                              float* __restrict__ p0, float* __restrict__ p1,
                                              float* __restrict__ p2, float* __restrict__ p3,
                                              float* __restrict__ p4, float* __restrict__ p5,
                                              float* __restrict__ p6, float* __restrict__ p7) {
  __shared__ float iS[4][18][72];
  __shared__ float wS[4][16][16];  // [ci][tap][co16]
  int tid = threadIdx.x;
  int bid = blockIdx.x;
  int kchunk = bid & 7;
  int rowtile = (bid >> 3) & 3;
  int cog = (bid >> 5) & 7;
  int b = bid >> 8;
  int r0 = rowtile * 8;
  int wv = tid >> 6, lane = tid & 63;
  int pc = lane & 15, pr = lane >> 4;
  float acc[4][4];  // [px][co]
  #pragma unroll
  for (int i = 0; i < 4; i++)
    #pragma unroll
    for (int j = 0; j < 4; j++) acc[i][j] = 0.f;
  const float* xb = x + (size_t)b * 64 * 4096;
  for (int sub = 0; sub < 2; sub++) {
    int cibase = kchunk * 8 + sub * 4;
    __syncthreads();
    for (int e = tid; e < 4 * 18 * 66; e += 256) {
      int dx = e % 66; int t = e / 66;
      int dy = t % 18; int ci = t / 18;
      int iy = 2 * r0 + dy;
      iS[ci][dy][dx] = (dx < 64 && iy < 64)
                           ? xb[(size_t)(cibase + ci) * 4096 + iy * 64 + dx] : 0.f;
    }
    for (int e = tid; e < 1024; e += 256) {
      int co = e & 15, tap = (e >> 4) & 15, ci = e >> 8;
      wS[ci][tap][co] = w[(size_t)(cog * 16 + co) * 1024 + (cibase + ci) * 16 + tap];
    }
    __syncthreads();
    #pragma unroll
    for (int ci = 0; ci < 4; ci++) {
      float xr[6][6];
      #pragma unroll
      for (int rr = 0; rr < 6; rr++)
        #pragma unroll
        for (int jj = 0; jj < 3; jj++) {
          float2 v2 = *(const float2*)&iS[ci][4 * pr + rr][4 * pc + 2 * jj];
          xr[rr][2 * jj] = v2.x; xr[rr][2 * jj + 1] = v2.y;
        }
      #pragma unroll
      for (int ky = 0; ky < 4; ky++)
        #pragma unroll
        for (int kx = 0; kx < 4; kx++) {
          float4 wq = *(const float4*)&wS[ci][ky * 4 + kx][wv * 4];  // broadcast
          #pragma unroll
          for (int dy2 = 0; dy2 < 2; dy2++)
            #pragma unroll
            for (int dx2 = 0; dx2 < 2; dx2++) {
              float xv = xr[2 * dy2 + ky][2 * dx2 + kx];
              int px = dy2 * 2 + dx2;
              acc[px][0] += wq.x * xv; acc[px][1] += wq.y * xv;
              acc[px][2] += wq.z * xv; acc[px][3] += wq.w * xv;
            }
        }
    }
  }
  float* parts[8] = {p0, p1, p2, p3, p4, p5, p6, p7};
  float* xo = parts[kchunk] + (size_t)b * 128 * N1;
  #pragma unroll
  for (int dy2 = 0; dy2 < 2; dy2++) {
    int r = r0 + 2 * pr + dy2;
    if (r >= 31) continue;
    #pragma unroll
    for (int dx2 = 0; dx2 < 2; dx2++) {
      int c = 2 * pc + dx2;
      if (c >= 31) continue;
      #pragma unroll
      for (int cc = 0; cc < 4; cc++)
        xo[(size_t)(cog * 16 + wv * 4 + cc) * N1 + r * 31 + c] = acc[dy2 * 2 + dx2][cc];
    }
  }
}

// combine 7 K-partials + xd(8th partial) + bias -> xd
__global__ __launch_bounds__(256) void k_combine(const float* __restrict__ p0,
                                                 const float* __restrict__ p1,
                                                 const float* __restrict__ p2,
                                                 const float* __restrict__ p3,
                                                 const float* __restrict__ p4,
                                                 const float* __restrict__ p5,
                                                 const float* __restrict__ p6,
                                                 const float* __restrict__ bias,
                                                 float* __restrict__ xd) {
  int i = blockIdx.x * 256 + threadIdx.x;
  if (i >= XDSZ) return;
  int co = (i / N1) & 127;
  float s = ((p0[i] + p1[i]) + (p2[i] + p3[i])) + ((p4[i] + p5[i]) + (p6[i] + xd[i]));
  xd[i] = bias[co] + s;
}

// weight pre-transpose for upconv scalar path:
// wT[((par*128 + ci)*16 + cw)*16 + t*4 + c] = w[ci][cw*4+c][wo_par(t)]
// (131072 floats = 512 KB; each wave's 16 weights per ci are contiguous + 64B aligned)
__global__ __launch_bounds__(256) void k_wtr(const float* __restrict__ w,
                                             float* __restrict__ wT) {
  int idx = blockIdx.x * 256 + threadIdx.x;
  int c = idx & 3;
  int t = (idx >> 2) & 3;
  int cw = (idx >> 4) & 15;
  int ci = (idx >> 8) & 127;
  int par = idx >> 15;
  int py = par >> 1, px = par & 1;
  int a = t >> 1, d = t & 1;
  int tap = (3 - (py + 2 * a)) * 4 + (3 - (px + 2 * d));
  int co = cw * 4 + c;
  wT[idx] = w[(size_t)ci * 1024 + co * 16 + tap];
}

#define QKV_EXPR(off) make_float4( \
    t0 * Ws[(off)] + t1 * Ws[12 + (off)] + t2 * Ws[24 + (off)] + t3 * Ws[36 + (off)] + Bs[(off)], \
    t0 * Ws[(off)+1] + t1 * Ws[12 + (off)+1] + t2 * Ws[24 + (off)+1] + t3 * Ws[36 + (off)+1] + Bs[(off)+1], \
    t0 * Ws[(off)+2] + t1 * Ws[12 + (off)+2] + t2 * Ws[24 + (off)+2] + t3 * Ws[36 + (off)+2] + Bs[(off)+2], \
    t0 * Ws[(off)+3] + t1 * Ws[12 + (off)+3] + t2 * Ws[24 + (off)+3] + t3 * Ws[36 + (off)+3] + Bs[(off)+3])

// load qkv weights; q-columns (0..3) pre-scaled by log2(e) so exp(s) == exp2(k.q')
#define LOAD_W_SCALED(wqkv, bqkv) do { \
    if (tid < 48) { float wv_ = (wqkv)[tid]; if ((tid % 12) < 4) wv_ *= L2E; Ws[tid] = wv_; } \
    if (tid < 12) { float bv_ = (bqkv)[tid]; if (tid < 4) bv_ *= L2E; Bs[tid] = bv_; } \
  } while (0)

// attention 1: 2 rows/thread (packed v2f), 4-way m-split. grid = 128 bg x 8 chunks.
__global__ __launch_bounds__(256) void k_attn1(const float* __restrict__ xd,
                                               const float* __restrict__ wqkv,
                                               const float* __restrict__ bqkv,
                                               float* __restrict__ o1,
                                               float* __restrict__ rowstat) {
  __shared__ float4 qvv[2 * N1];
  __shared__ float Ws[48], Bs[12];
  int tid = threadIdx.x;
  int chunk = blockIdx.x & 7;
  int bg = blockIdx.x >> 3;
  int b = bg >> 5, g = bg & 31;
  LOAD_W_SCALED(wqkv, bqkv);
  __syncthreads();
  const float* xp0 = xd + (size_t)(b * 128 + g * 4) * N1;
  for (int nn = tid; nn < N1; nn += 256) {
    float t0 = xp0[nn], t1 = xp0[N1 + nn], t2 = xp0[2 * N1 + nn], t3 = xp0[3 * N1 + nn];
    qvv[2 * nn]     = QKV_EXPR(0);
    qvv[2 * nn + 1] = QKV_EXPR(8);
  }
  __syncthreads();
  int wv = tid >> 6, lane = tid & 63;
  int q4 = lane >> 4;
  int n0 = chunk * 128 + wv * 32 + (lane & 15);
  if (n0 >= N1) return;  // all quarter-partners share n0 -> exit together
  int n1 = n0 + 16;
  bool v1 = n1 < N1;
  int n1c = v1 ? n1 : n0;
  float t0 = xp0[n0], t1 = xp0[N1 + n0], t2 = xp0[2 * N1 + n0], t3 = xp0[3 * N1 + n0];
  float4 kr0 = QKV_EXPR(4);
  t0 = xp0[n1c]; t1 = xp0[N1 + n1c]; t2 = xp0[2 * N1 + n1c]; t3 = xp0[3 * N1 + n1c];
  float4 kr1 = QKV_EXPR(4);
  v2f krx = {kr0.x, kr1.x}, kry = {kr0.y, kr1.y};
  v2f krz = {kr0.z, kr1.z}, krw = {kr0.w, kr1.w};
  int ns = q4 * 241;
  int ne = (ns + 241 < N1) ? ns + 241 : N1;
  v2f sum = {0.f, 0.f}, A0 = {0.f, 0.f}, A1 = {0.f, 0.f}, A2 = {0.f, 0.f}, A3 = {0.f, 0.f};
  #pragma unroll 4
  for (int m = ns; m < ne; m++) {
    float4 q = qvv[2 * m];
    float4 v = qvv[2 * m + 1];
    v2f s = krx * q.x + kry * q.y + krz * q.z + krw * q.w;  // v_pk_fma_f32
    v2f e;
    e.x = __builtin_amdgcn_exp2f(s.x);
    e.y = __builtin_amdgcn_exp2f(s.y);
    sum += e;
    A0 += e * v.x; A1 += e * v.y; A2 += e * v.z; A3 += e * v.w;
  }
  #pragma unroll
  for (int off = 16; off <= 32; off <<= 1) {
    sum.x += __shfl_xor(sum.x, off, 64); sum.y += __shfl_xor(sum.y, off, 64);
    A0.x += __shfl_xor(A0.x, off, 64);   A0.y += __shfl_xor(A0.y, off, 64);
    A1.x += __shfl_xor(A1.x, off, 64);   A1.y += __shfl_xor(A1.y, off, 64);
    A2.x += __shfl_xor(A2.x, off, 64);   A2.y += __shfl_xor(A2.y, off, 64);
    A3.x += __shfl_xor(A3.x, off, 64);   A3.y += __shfl_xor(A3.y, off, 64);
  }
  if (q4 != 0) return;
  float* o1p = o1 + (size_t)(b * 128 + g * 4) * N1;
  float inv0 = 1.0f / sum.x;
  o1p[n0] = A0.x * inv0;
  o1p[N1 + n0] = A1.x * inv0;
  o1p[2 * N1 + n0] = A2.x * inv0;
  o1p[3 * N1 + n0] = A3.x * inv0;
  if (g < 16) rowstat[(size_t)(b * 16 + g) * N1 + n0] = inv0;
  if (v1) {
    float inv1 = 1.0f / sum.y;
    o1p[n1] = A0.y * inv1;
    o1p[N1 + n1] = A1.y * inv1;
    o1p[2 * N1 + n1] = A2.y * inv1;
    o1p[3 * N1 + n1] = A3.y * inv1;
    if (g < 16) rowstat[(size_t)(b * 16 + g) * N1 + n1] = inv1;
  }
}

// coarse: 2 cols/thread (packed v2f), 8-way n-split. grid = 64 bg x 16 chunks.
__global__ __launch_bounds__(256) void k_coarse(const float* __restrict__ xd,
                                                const float* __restrict__ wqkv,
                                                const float* __restrict__ bqkv,
                                                const float* __restrict__ rowstat,
                                                float* __restrict__ coarse) {
  __shared__ float4 kS[N1];
  __shared__ float rs[N1];
  __shared__ float Ws[48], Bs[12];
  int tid = threadIdx.x;
  int chunk = blockIdx.x & 15;
  int bg = blockIdx.x >> 4;
  int b = bg >> 4, g = bg & 15;
  LOAD_W_SCALED(wqkv, bqkv);
  __syncthreads();
  const float* xp0 = xd + (size_t)(b * 128 + g * 4) * N1;
  const float* rp = rowstat + (size_t)(b * 16 + g) * N1;
  for (int nn = tid; nn < N1; nn += 256) {
    float t0 = xp0[nn], t1 = xp0[N1 + nn], t2 = xp0[2 * N1 + nn], t3 = xp0[3 * N1 + nn];
    kS[nn] = QKV_EXPR(4);
    rs[nn] = rp[nn];
  }
  __syncthreads();
  int wv = tid >> 6, lane = tid & 63;
  int oc = lane >> 3;
  int m0 = chunk * 64 + wv * 16 + (lane & 7);
  if (m0 >= N1) return;  // octant partners share m0 -> exit together
  int m1 = m0 + 8;
  bool v1 = m1 < N1;
  int m1c = v1 ? m1 : m0;
  float t0 = xp0[m0], t1 = xp0[N1 + m0], t2 = xp0[2 * N1 + m0], t3 = xp0[3 * N1 + m0];
  float4 q0 = QKV_EXPR(0);  // pre-scaled by log2e
  t0 = xp0[m1c]; t1 = xp0[N1 + m1c]; t2 = xp0[2 * N1 + m1c]; t3 = xp0[3 * N1 + m1c];
  float4 q1 = QKV_EXPR(0);
  v2f qx = {q0.x, q1.x}, qy = {q0.y, q1.y}, qz = {q0.z, q1.z}, qw = {q0.w, q1.w};
  int ns = oc * 121;
  int ne = (ns + 121 < N1) ? ns + 121 : N1;
  v2f c = {0.f, 0.f};
  #pragma unroll 4
  for (int n = ns; n < ne; n++) {
    float4 k = kS[n];
    float r = rs[n];
    v2f s = qx * k.x + qy * k.y + qz * k.z + qw * k.w;
    v2f e;
    e.x = __builtin_amdgcn_exp2f(s.x);
    e.y = __builtin_amdgcn_exp2f(s.y);
    c += e * r;
  }
  #pragma unroll
  for (int off = 8; off <= 32; off <<= 1) {
    c.x += __shfl_xor(c.x, off, 64);
    c.y += __shfl_xor(c.y, off, 64);
  }
  if (oc != 0) return;
  coarse[(size_t)(b * 16 + g) * N1 + m0] = c.x;
  if (v1) coarse[(size_t)(b * 16 + g) * N1 + m1] = c.y;
}

// top-240 per (b,g<16): bitonic over 1024 packed keys
__global__ __launch_bounds__(256) void k_topk(const float* __restrict__ coarse,
                                              int* __restrict__ topk) {
  __shared__ unsigned long long keys[1024];
  int tid = threadIdx.x;
  int bg = blockIdx.x;
  const float* cp = coarse + (size_t)bg * N1;
  for (int i = tid; i < 1024; i += 256) {
    unsigned long long key = 0ull;
    if (i < N1) {
      unsigned fb = __float_as_uint(cp[i]);
      key = ((unsigned long long)fb << 32) | (unsigned)(N1 - 1 - i);
    }
    keys[i] = key;
  }
  __syncthreads();
  for (int k2 = 2; k2 <= 1024; k2 <<= 1) {
    for (int j = k2 >> 1; j > 0; j >>= 1) {
      for (int i = tid; i < 1024; i += 256) {
        int ixj = i ^ j;
        if (ixj > i) {
          unsigned long long a = keys[i], bb = keys[ixj];
          bool up = ((i & k2) == 0);
          if ((a > bb) == up) { keys[i] = bb; keys[ixj] = a; }
        }
      }
      __syncthreads();
    }
  }
  if (tid < KF) {
    unsigned long long key = keys[1023 - tid];
    topk[(size_t)bg * KF + tid] = (N1 - 1) - (int)(unsigned)(key & 0xffffffffull);
  }
}

// transposed conv, per-parity: o1(4,128,31,31) -> yacc = 2*coarse_out (4,64,62,62)
// v5: weights via scalar path (SMEM) from pre-transposed wT; no wS LDS, no b128
// broadcasts. Each wave reads 16 wave-uniform floats per ci (readfirstlane makes
// the address provably uniform -> s_load; SGPR operand feeds v_fmac directly).
__global__ __launch_bounds__(256) void k_upconv(const float* __restrict__ o1,
                                                const float* __restrict__ wT,
                                                const float* __restrict__ bias,
                                                float* __restrict__ yacc) {
  __shared__ float iS[16][9][12];
  int tid = threadIdx.x;
  int bid = blockIdx.x;
  int b = bid >> 8;
  int cog = (bid >> 6) & 3;
  int par = (bid >> 4) & 3;
  int py = par >> 1, px = par & 1;
  int tile = bid & 15;
  int r0 = (tile >> 2) * 8, c0 = (tile & 3) * 8;
  int wv = tid >> 6, lane = tid & 63;
  int pr = lane >> 3, pc = lane & 7;
  int cwu = __builtin_amdgcn_readfirstlane(cog * 4 + wv);  // co-quad 0..15, wave-uniform
  // wT float4 layout: [(par*128 + ci)*16 + cw][t] ; per-ci stride = 64 float4
  const float4* wq = (const float4*)wT + ((size_t)par * 2048 + cwu) * 4;
  int cobase = cog * 16 + wv * 4;
  float acc[4] = {0.f, 0.f, 0.f, 0.f};
  const float* ob = o1 + (size_t)b * 128 * N1;
  for (int ch = 0; ch < 8; ch++) {
    __syncthreads();
    for (int e = tid; e < 16 * 81; e += 256) {
      int dx = e % 9; int t = e / 9;
      int dy = t % 9; int ci = t / 9;
      int iy = r0 + py - 1 + dy, ix = c0 + px - 1 + dx;
      float v = 0.f;
      if (iy >= 0 && iy < 31 && ix >= 0 && ix < 31)
        v = ob[(size_t)(ch * 16 + ci) * N1 + iy * 31 + ix];
      iS[ci][dy][dx] = v;
    }
    __syncthreads();
    #pragma unroll
    for (int ci = 0; ci < 16; ci++) {
      int cig = ch * 16 + ci;
      float4 w0 = wq[(size_t)cig * 64 + 0];
      float4 w1 = wq[(size_t)cig * 64 + 1];
      float4 w2 = wq[(size_t)cig * 64 + 2];
      float4 w3 = wq[(size_t)cig * 64 + 3];
      float x00 = iS[ci][pr][pc],     x01 = iS[ci][pr][pc + 1];
      float x10 = iS[ci][pr + 1][pc], x11 = iS[ci][pr + 1][pc + 1];
      acc[0] += w0.x * x00; acc[1] += w0.y * x00; acc[2] += w0.z * x00; acc[3] += w0.w * x00;
      acc[0] += w1.x * x01; acc[1] += w1.y * x01; acc[2] += w1.z * x01; acc[3] += w1.w * x01;
      acc[0] += w2.x * x10; acc[1] += w2.y * x10; acc[2] += w2.z * x10; acc[3] += w2.w * x10;
      acc[0] += w3.x * x11; acc[1] += w3.y * x11; acc[2] += w3.z * x11; acc[3] += w3.w * x11;
    }
  }
  int r = r0 + pr, c = c0 + pc;
  if (r >= 31 || c >= 31) return;
  int y = 2 * r + py, xx = 2 * c + px;
  #pragma unroll
  for (int cc = 0; cc < 4; cc++) {
    int co = cobase + cc;
    yacc[(size_t)(b * 64 + co) * HW2 + y * 62 + xx] = 2.0f * (acc[cc] + bias[co]);
  }
}

// attention 2: 2 rows/thread (packed v2f), 4-way m-split. grid = 64 bg x 8 chunks.
__global__ __launch_bounds__(256) void k_attn2(const float* __restrict__ yacc,
                                               const float* __restrict__ wqkv,
                                               const float* __restrict__ bqkv,
                                               const int* __restrict__ topk,
                                               float4* __restrict__ o2,
                                               int* __restrict__ coordg) {
  __shared__ float4 qvv[2 * N2];
  __shared__ float Ws[48], Bs[12];
  int tid = threadIdx.x;
  int chunk = blockIdx.x & 7;
  int bg = blockIdx.x >> 3;
  int b = bg >> 4, g = bg & 15;
  LOAD_W_SCALED(wqkv, bqkv);
  __syncthreads();
  const float* yp0 = yacc + (size_t)(b * 64 + g * 4) * HW2;
  const int* ip = topk + (size_t)bg * KF;
  for (int nn = tid; nn < N2; nn += 256) {
    int tt = nn >> 2, i = (nn >> 1) & 1, j = nn & 1;
    int p = ip[tt];
    int ph = p / 31, pw = p - ph * 31;
    int cc = (2 * ph + i) * 62 + (2 * pw + j);
    float t0 = 0.5f * yp0[cc], t1 = 0.5f * yp0[HW2 + cc];
    float t2 = 0.5f * yp0[2 * HW2 + cc], t3 = 0.5f * yp0[3 * HW2 + cc];
    qvv[2 * nn]     = QKV_EXPR(0);
    qvv[2 * nn + 1] = QKV_EXPR(8);
  }
  __syncthreads();
  int wv = tid >> 6, lane = tid & 63;
  int q4 = lane >> 4;
  int n0 = chunk * 128 + wv * 32 + (lane & 15);
  if (n0 >= N2) return;
  int n1 = n0 + 16;
  bool v1 = n1 < N2;
  int n1c = v1 ? n1 : n0;
  int tt = n0 >> 2, i = (n0 >> 1) & 1, j = n0 & 1;
  int p = ip[tt];
  int ph = p / 31, pw = p - ph * 31;
  int cc0 = (2 * ph + i) * 62 + (2 * pw + j);
  float t0 = 0.5f * yp0[cc0], t1 = 0.5f * yp0[HW2 + cc0];
  float t2 = 0.5f * yp0[2 * HW2 + cc0], t3 = 0.5f * yp0[3 * HW2 + cc0];
  float4 kr0 = QKV_EXPR(4);
  tt = n1c >> 2; i = (n1c >> 1) & 1; j = n1c & 1;
  p = ip[tt];
  ph = p / 31; pw = p - ph * 31;
  int cc1 = (2 * ph + i) * 62 + (2 * pw + j);
  t0 = 0.5f * yp0[cc1]; t1 = 0.5f * yp0[HW2 + cc1];
  t2 = 0.5f * yp0[2 * HW2 + cc1]; t3 = 0.5f * yp0[3 * HW2 + cc1];
  float4 kr1 = QKV_EXPR(4);
  v2f krx = {kr0.x, kr1.x}, kry = {kr0.y, kr1.y};
  v2f krz = {kr0.z, kr1.z}, krw = {kr0.w, kr1.w};
  int ns = q4 * 240;
  int ne = ns + 240;
  v2f sum = {0.f, 0.f}, A0 = {0.f, 0.f}, A1 = {0.f, 0.f}, A2 = {0.f, 0.f}, A3 = {0.f, 0.f};
  #pragma unroll 4
  for (int m = ns; m < ne; m++) {
    float4 q = qvv[2 * m];
    float4 v = qvv[2 * m + 1];
    v2f s = krx * q.x + kry * q.y + krz * q.z + krw * q.w;
    v2f e;
    e.x = __builtin_amdgcn_exp2f(s.x);
    e.y = __builtin_amdgcn_exp2f(s.y);
    sum += e;
    A0 += e * v.x; A1 += e * v.y; A2 += e * v.z; A3 += e * v.w;
  }
  #pragma unroll
  for (int off = 16; off <= 32; off <<= 1) {
    sum.x += __shfl_xor(sum.x, off, 64); sum.y += __shfl_xor(sum.y, off, 64);
    A0.x += __shfl_xor(A0.x, off, 64);   A0.y += __shfl_xor(A0.y, off, 64);
    A1.x += __shfl_xor(A1.x, off, 64);   A1.y += __shfl_xor(A1.y, off, 64);
    A2.x += __shfl_xor(A2.x, off, 64);   A2.y += __shfl_xor(A2.y, off, 64);
    A3.x += __shfl_xor(A3.x, off, 64);   A3.y += __shfl_xor(A3.y, off, 64);
  }
  if (q4 != 0) return;
  float inv0 = 1.0f / sum.x;
  size_t oi = (size_t)bg * N2 + n0;
  o2[oi] = make_float4(A0.x * inv0, A1.x * inv0, A2.x * inv0, A3.x * inv0);
  coordg[oi] = cc0;
  if (v1) {
    float inv1 = 1.0f / sum.y;
    oi = (size_t)bg * N2 + n1;
    o2[oi] = make_float4(A0.y * inv1, A1.y * inv1, A2.y * inv1, A3.y * inv1);
    coordg[oi] = cc1;
  }
}

// scatter-add attn2 output into yacc (disjoint targets)
__global__ __launch_bounds__(256) void k_scatter(float* __restrict__ yacc,
                                                 const float4* __restrict__ o2,
                                                 const int* __restrict__ coordg) {
  int idx = blockIdx.x * 256 + threadIdx.x;
  if (idx >= 64 * N2) return;
  int bg = idx / N2;
  int b = bg >> 4, g = bg & 15;
  float4 o = o2[idx];
  int cc = coordg[idx];
  float* yp0 = yacc + (size_t)(b * 64 + g * 4) * HW2;
  yp0[cc] += o.x;
  yp0[HW2 + cc] += o.y;
  yp0[2 * HW2 + cc] += o.z;
  yp0[3 * HW2 + cc] += o.w;
}

// depthwise 3x3, pad 1
__global__ __launch_bounds__(256) void k_dwconv(const float* __restrict__ yin,
                                                const float* __restrict__ w,
                                                float* __restrict__ z1) {
  int idx = blockIdx.x * 256 + threadIdx.x;
  if (idx >= 64 * NPIX) return;
  int x = idx % 62; int t = idx / 62;
  int y = t % 62; t /= 62;
  int c = t % 64;
  int plane = idx / HW2;
  const float* yp = yin + (size_t)plane * HW2;
  const float* wp = w + c * 9;
  float acc = 0.f;
  #pragma unroll
  for (int ky = 0; ky < 3; ky++) {
    int yy = y + ky - 1;
    if (yy < 0 || yy > 61) continue;
    #pragma unroll
    for (int kx = 0; kx < 3; kx++) {
      int xx = x + kx - 1;
      if (xx < 0 || xx > 61) continue;
      acc += yp[yy * 62 + xx] * wp[ky * 3 + kx];
    }
  }
  z1[idx] = acc;
}

__device__ __forceinline__ float wave_sum(float x) {
  #pragma unroll
  for (int off = 32; off > 0; off >>= 1) x += __shfl_xor(x, off, 64);
  return x;
}

// per-channel sum/sumsq; grid 1024 = c(64) x b(4) x seg(4: 961 px each)
__global__ __launch_bounds__(256) void k_stats(const float* __restrict__ buf,
                                               float* __restrict__ stats) {
  __shared__ float red[8];
  int bid = blockIdx.x;
  int seg = bid & 3;
  int b = (bid >> 2) & 3;
  int c = bid >> 4;
  const float* p = buf + (size_t)(b * 64 + c) * HW2;
  int i0 = seg * 961;
  float s = 0.f, s2 = 0.f;
  for (int i = i0 + threadIdx.x; i < i0 + 961; i += 256) {
    float z = p[i]; s += z; s2 += z * z;
  }
  s = wave_sum(s); s2 = wave_sum(s2);
  int wave = threadIdx.x >> 6, lane = threadIdx.x & 63;
  if (lane == 0) { red[wave] = s; red[4 + wave] = s2; }
  __syncthreads();
  if (threadIdx.x == 0) {
    atomicAdd(&stats[c], red[0] + red[1] + red[2] + red[3]);
    atomicAdd(&stats[64 + c], red[4] + red[5] + red[6] + red[7]);
  }
}

__global__ void k_bnparam(const float* __restrict__ stats, const float* __restrict__ gamma,
                          const float* __restrict__ beta, float* __restrict__ par) {
  int c = threadIdx.x;
  if (c < 64) {
    float m = stats[c] * (1.0f / NPIX);
    float v = stats[64 + c] * (1.0f / NPIX) - m * m;
    float a = gamma[c] * rsqrtf(v + 1e-5f);
    par[c] = a; par[64 + c] = beta[c] - m * a;
  }
}

// pointwise 1x1, co-split x16 (4 co/block): grid = pixblocks(61) x cog(16)
__global__ __launch_bounds__(256) void k_pwconv(const float* __restrict__ z1,
                                                const float* __restrict__ wpw,
                                                const float* __restrict__ par,
                                                float* __restrict__ z2) {
  __shared__ float w[4 * 64];
  __shared__ float aa[64], cb[64];
  int tid = threadIdx.x;
  int cog = blockIdx.x & 15;
  int pb = blockIdx.x >> 4;
  if (tid < 64) { aa[tid] = par[tid]; cb[tid] = par[64 + tid]; }
  for (int i = tid; i < 256; i += 256) w[i] = wpw[cog * 256 + i];
  __syncthreads();
  int pix = pb * 256 + tid;
  if (pix >= NPIX) return;
  int b = pix / HW2, p = pix - b * HW2;
  float h[64];
  #pragma unroll
  for (int ci = 0; ci < 64; ci++) {
    float z = z1[(size_t)(b * 64 + ci) * HW2 + p];
    z = aa[ci] * z + cb[ci];
    h[ci] = fminf(fmaxf(z, 0.f), 6.f);
  }
  #pragma unroll
  for (int cc = 0; cc < 4; cc++) {
    float acc = 0.f;
    #pragma unroll
    for (int ci = 0; ci < 64; ci++) acc += h[ci] * w[cc * 64 + ci];
    z2[(size_t)(b * 64 + cog * 4 + cc) * HW2 + p] = acc;
  }
}

__global__ __launch_bounds__(256) void k_final(const float* __restrict__ z2,
                                               const float* __restrict__ par,
                                               float* __restrict__ out) {
  int idx = blockIdx.x * 256 + threadIdx.x;
  if (idx >= 64 * NPIX) return;
  int c = (idx / HW2) & 63;
  float z = par[c] * z2[idx] + par[64 + c];
  out[idx] = fminf(fmaxf(z, 0.f), 6.f);
}

extern "C" void kernel_launch(void* const* d_in, const int* in_sizes, int n_in,
                              void* d_out, int out_size, void* d_ws, size_t ws_size,
                              hipStream_t stream) {
  const float* x       = (const float*)d_in[0];
  const float* w_down  = (const float*)d_in[1];
  const float* b_down  = (const float*)d_in[2];
  const float* w_qkv_c = (const float*)d_in[3];
  const float* b_qkv_c = (const float*)d_in[4];
  const float* w_up    = (const float*)d_in[5];
  const float* b_up    = (const float*)d_in[6];
  const float* w_qkv_t = (const float*)d_in[7];
  const float* b_qkv_t = (const float*)d_in[8];
  const float* w_dw    = (const float*)d_in[9];
  const float* g_dw    = (const float*)d_in[10];
  const float* be_dw   = (const float*)d_in[11];
  const float* w_pw    = (const float*)d_in[12];
  const float* g_pw    = (const float*)d_in[13];
  const float* be_pw   = (const float*)d_in[14];
  float* out = (float*)d_out;

  float* ws    = (float*)d_ws;
  float* xd    = ws;                       // 492032 = 4*128*961
  float* o1    = xd + 492032;              // 492032
  int*   topk  = (int*)(o1 + 492032);      // 15360 = 4*16*240
  float* yacc  = (float*)(topk + 15360);   // 984064 = 4*64*62*62
  float* z1    = yacc + 984064;            // 984064
  float* z2    = z1 + 984064;              // 984064
  float* stats = z2 + 984064;              // 256
  float* par   = stats + 256;              // 256

  // disjoint-lifetime aliases:
  // k_down partials (pre-attn): o1, yacc(x2), z1(x2), z2(x2), xd -- all dead until combine
  float*  rowstat = z1;                    // 4*16*961 floats (post-combine)
  float*  coarse  = z1 + 61504;            // 4*16*961 floats
  float4* o2      = (float4*)z2;           // 4*16*960 float4
  int*    coordg  = (int*)(z2 + 245760);   // 61440 ints
  // wT: 131072 floats; lives in z2 between k_combine (frees the down-partials)
  // and k_attn2 (o2 reuses z2) -- upconv has consumed it by then
  float*  wT      = z2;

  k_zero<<<1, 256, 0, stream>>>(stats, 256);
  k_down<<<1024, 256, 0, stream>>>(x, w_down,
                                   o1, yacc, yacc + 492032, z1, z1 + 492032,
                                   z2, z2 + 492032, xd);
  k_combine<<<(XDSZ + 255) / 256, 256, 0, stream>>>(o1, yacc, yacc + 492032, z1,
                                                    z1 + 492032, z2, z2 + 492032,
                                                    b_down, xd);
  k_wtr<<<512, 256, 0, stream>>>(w_up, wT);
  k_attn1<<<1024, 256, 0, stream>>>(xd, w_qkv_c, b_qkv_c, o1, rowstat);
  k_coarse<<<1024, 256, 0, stream>>>(xd, w_qkv_c, b_qkv_c, rowstat, coarse);
  k_topk<<<64, 256, 0, stream>>>(coarse, topk);
  k_upconv<<<1024, 256, 0, stream>>>(o1, wT, b_up, yacc);
  k_attn2<<<512, 256, 0, stream>>>(yacc, w_qkv_t, b_qkv_t, topk, o2, coordg);
  k_scatter<<<(64 * N2 + 255) / 256, 256, 0, stream>>>(yacc, o2, coordg);
  k_dwconv<<<(64 * NPIX + 255) / 256, 256, 0, stream>>>(yacc, w_dw, z1);
  k_stats<<<1024, 256, 0, stream>>>(z1, stats);
  k_bnparam<<<1, 64, 0, stream>>>(stats, g_dw, be_dw, par);
  k_pwconv<<<61 * 16, 256, 0, stream>>>(z1, w_pw, par, z2);
  k_stats<<<1024, 256, 0, stream>>>(z2, stats + 128);
  k_bnparam<<<1, 64, 0, stream>>>(stats + 128, g_pw, be_pw, par + 128);
  k_final<<<(64 * NPIX + 255) / 256, 256, 0, stream>>>(z2, par + 128, out);
}

// Round 2
// 306.488 us; speedup vs baseline: 1.0329x; 1.0025x over previous
//
#include <hip/hip_runtime.h>
#include <math.h>

#define N1 961
#define N2 960
#define KF 240
#define HW2 3844   // 62*62
#define NPIX 15376 // 4*62*62
#define XDSZ 492032 // 4*128*961
#define L2E 1.44269504f

typedef float v2f __attribute__((ext_vector_type(2)));

__global__ void k_zero(float* p, int n) {
  int i = blockIdx.x * 256 + threadIdx.x;
  if (i < n) p[i] = 0.f;
}

// down conv v4: 2x2 px x 4 co per thread, K-split x8 (1024 blocks = 4/CU).
__global__ __launch_bounds__(256) void k_down(const float* __restrict__ x,
                                              const float* __restrict__ w,
                                              float* __restrict__ p0, float* __restrict__ p1,
                                              float* __restrict__ p2, float* __restrict__ p3,
                                              float* __restrict__ p4, float* __restrict__ p5,
                                              float* __restrict__ p6, float* __restrict__ p7) {
  __shared__ float iS[4][18][72];
  __shared__ float wS[4][16][16];  // [ci][tap][co16]
  int tid = threadIdx.x;
  int bid = blockIdx.x;
  int kchunk = bid & 7;
  int rowtile = (bid >> 3) & 3;
  int cog = (bid >> 5) & 7;
  int b = bid >> 8;
  int r0 = rowtile * 8;
  int wv = tid >> 6, lane = tid & 63;
  int pc = lane & 15, pr = lane >> 4;
  float acc[4][4];  // [px][co]
  #pragma unroll
  for (int i = 0; i < 4; i++)
    #pragma unroll
    for (int j = 0; j < 4; j++) acc[i][j] = 0.f;
  const float* xb = x + (size_t)b * 64 * 4096;
  for (int sub = 0; sub < 2; sub++) {
    int cibase = kchunk * 8 + sub * 4;
    __syncthreads();
    for (int e = tid; e < 4 * 18 * 66; e += 256) {
      int dx = e % 66; int t = e / 66;
      int dy = t % 18; int ci = t / 18;
      int iy = 2 * r0 + dy;
      iS[ci][dy][dx] = (dx < 64 && iy < 64)
                           ? xb[(size_t)(cibase + ci) * 4096 + iy * 64 + dx] : 0.f;
    }
    for (int e = tid; e < 1024; e += 256) {
      int co = e & 15, tap = (e >> 4) & 15, ci = e >> 8;
      wS[ci][tap][co] = w[(size_t)(cog * 16 + co) * 1024 + (cibase + ci) * 16 + tap];
    }
    __syncthreads();
    #pragma unroll
    for (int ci = 0; ci < 4; ci++) {
      float xr[6][6];
      #pragma unroll
      for (int rr = 0; rr < 6; rr++)
        #pragma unroll
        for (int jj = 0; jj < 3; jj++) {
          float2 v2 = *(const float2*)&iS[ci][4 * pr + rr][4 * pc + 2 * jj];
          xr[rr][2 * jj] = v2.x; xr[rr][2 * jj + 1] = v2.y;
        }
      #pragma unroll
      for (int ky = 0; ky < 4; ky++)
        #pragma unroll
        for (int kx = 0; kx < 4; kx++) {
          float4 wq = *(const float4*)&wS[ci][ky * 4 + kx][wv * 4];  // broadcast
          #pragma unroll
          for (int dy2 = 0; dy2 < 2; dy2++)
            #pragma unroll
            for (int dx2 = 0; dx2 < 2; dx2++) {
              float xv = xr[2 * dy2 + ky][2 * dx2 + kx];
              int px = dy2 * 2 + dx2;
              acc[px][0] += wq.x * xv; acc[px][1] += wq.y * xv;
              acc[px][2] += wq.z * xv; acc[px][3] += wq.w * xv;
            }
        }
    }
  }
  float* parts[8] = {p0, p1, p2, p3, p4, p5, p6, p7};
  float* xo = parts[kchunk] + (size_t)b * 128 * N1;
  #pragma unroll
  for (int dy2 = 0; dy2 < 2; dy2++) {
    int r = r0 + 2 * pr + dy2;
    if (r >= 31) continue;
    #pragma unroll
    for (int dx2 = 0; dx2 < 2; dx2++) {
      int c = 2 * pc + dx2;
      if (c >= 31) continue;
      #pragma unroll
      for (int cc = 0; cc < 4; cc++)
        xo[(size_t)(cog * 16 + wv * 4 + cc) * N1 + r * 31 + c] = acc[dy2 * 2 + dx2][cc];
    }
  }
}

// combine 7 K-partials + xd(8th partial) + bias -> xd
__global__ __launch_bounds__(256) void k_combine(const float* __restrict__ p0,
                                                 const float* __restrict__ p1,
                                                 const float* __restrict__ p2,
                                                 const float* __restrict__ p3,
                                                 const float* __restrict__ p4,
                                                 const float* __restrict__ p5,
                                                 const float* __restrict__ p6,
                                                 const float* __restrict__ bias,
                                                 float* __restrict__ xd) {
  int i = blockIdx.x * 256 + threadIdx.x;
  if (i >= XDSZ) return;
  int co = (i / N1) & 127;
  float s = ((p0[i] + p1[i]) + (p2[i] + p3[i])) + ((p4[i] + p5[i]) + (p6[i] + xd[i]));
  xd[i] = bias[co] + s;
}

// weight pre-transpose for upconv scalar path:
// wT[((par*128 + ci)*16 + cw)*16 + t*4 + c] = w[ci][cw*4+c][wo_par(t)]
__global__ __launch_bounds__(256) void k_wtr(const float* __restrict__ w,
                                             float* __restrict__ wT) {
  int idx = blockIdx.x * 256 + threadIdx.x;
  int c = idx & 3;
  int t = (idx >> 2) & 3;
  int cw = (idx >> 4) & 15;
  int ci = (idx >> 8) & 127;
  int par = idx >> 15;
  int py = par >> 1, px = par & 1;
  int a = t >> 1, d = t & 1;
  int tap = (3 - (py + 2 * a)) * 4 + (3 - (px + 2 * d));
  int co = cw * 4 + c;
  wT[idx] = w[(size_t)ci * 1024 + co * 16 + tap];
}

// QKV projection with weights read via the SCALAR path (uniform s_load; SGPR
// operand feeds v_fma directly). No L2E pre-scale here -- callers fold L2E
// into their per-thread k/q registers instead.
#define QKV_G(off) make_float4( \
    t0 * wqkv[(off)] + t1 * wqkv[12 + (off)] + t2 * wqkv[24 + (off)] + t3 * wqkv[36 + (off)] + bqkv[(off)], \
    t0 * wqkv[(off)+1] + t1 * wqkv[12 + (off)+1] + t2 * wqkv[24 + (off)+1] + t3 * wqkv[36 + (off)+1] + bqkv[(off)+1], \
    t0 * wqkv[(off)+2] + t1 * wqkv[12 + (off)+2] + t2 * wqkv[24 + (off)+2] + t3 * wqkv[36 + (off)+2] + bqkv[(off)+2], \
    t0 * wqkv[(off)+3] + t1 * wqkv[12 + (off)+3] + t2 * wqkv[24 + (off)+3] + t3 * wqkv[36 + (off)+3] + bqkv[(off)+3])

__device__ __forceinline__ void red2(v2f& a, int off) {
  a.x += __shfl_xor(a.x, off, 64);
  a.y += __shfl_xor(a.y, off, 64);
}

// attention 1 v3: 4 rows/thread (2x v2f pairs), strided 8-way m-split.
// grid = 128 bg x 8 chunks (chunk = 128 rows). Halves LDS b128 traffic vs R=2.
__global__ __launch_bounds__(256) void k_attn1(const float* __restrict__ xd,
                                               const float* __restrict__ wqkv,
                                               const float* __restrict__ bqkv,
                                               float* __restrict__ o1,
                                               float* __restrict__ rowstat) {
  __shared__ float4 qvv[2 * N1];
  int tid = threadIdx.x;
  int chunk = blockIdx.x & 7;
  int bg = blockIdx.x >> 3;
  int b = bg >> 5, g = bg & 31;
  const float* xp0 = xd + (size_t)(b * 128 + g * 4) * N1;
  for (int nn = tid; nn < N1; nn += 256) {
    float t0 = xp0[nn], t1 = xp0[N1 + nn], t2 = xp0[2 * N1 + nn], t3 = xp0[3 * N1 + nn];
    qvv[2 * nn]     = QKV_G(0);
    qvv[2 * nn + 1] = QKV_G(8);
  }
  __syncthreads();
  int wv = tid >> 6, lane = tid & 63;
  int oc = lane >> 3;
  int n0 = chunk * 128 + wv * 32 + (lane & 7);
  if (n0 >= N1) return;  // reduce-partners share n0 -> exit together
  int nr[4]; bool vld[4];
  float4 kr[4];
  #pragma unroll
  for (int i2 = 0; i2 < 4; i2++) {
    int n = n0 + 8 * i2; nr[i2] = n; vld[i2] = n < N1;
    int nc = vld[i2] ? n : n0;
    float t0 = xp0[nc], t1 = xp0[N1 + nc], t2 = xp0[2 * N1 + nc], t3 = xp0[3 * N1 + nc];
    float4 kk = QKV_G(4);
    kr[i2] = make_float4(kk.x * L2E, kk.y * L2E, kk.z * L2E, kk.w * L2E);
  }
  v2f kax = {kr[0].x, kr[1].x}, kay = {kr[0].y, kr[1].y};
  v2f kaz = {kr[0].z, kr[1].z}, kaw = {kr[0].w, kr[1].w};
  v2f kbx = {kr[2].x, kr[3].x}, kby = {kr[2].y, kr[3].y};
  v2f kbz = {kr[2].z, kr[3].z}, kbw = {kr[2].w, kr[3].w};
  v2f suma = {0.f, 0.f}, sumb = {0.f, 0.f};
  v2f Aa0 = {0.f, 0.f}, Aa1 = {0.f, 0.f}, Aa2 = {0.f, 0.f}, Aa3 = {0.f, 0.f};
  v2f Ab0 = {0.f, 0.f}, Ab1 = {0.f, 0.f}, Ab2 = {0.f, 0.f}, Ab3 = {0.f, 0.f};
  // strided split: octant oc handles m == oc (mod 8) -> 2-way bank aliasing (free)
  #pragma unroll 4
  for (int m = oc; m < N1; m += 8) {
    float4 q = qvv[2 * m];
    float4 v = qvv[2 * m + 1];
    v2f sa = kax * q.x + kay * q.y + kaz * q.z + kaw * q.w;
    v2f sb = kbx * q.x + kby * q.y + kbz * q.z + kbw * q.w;
    v2f ea, eb;
    ea.x = __builtin_amdgcn_exp2f(sa.x); ea.y = __builtin_amdgcn_exp2f(sa.y);
    eb.x = __builtin_amdgcn_exp2f(sb.x); eb.y = __builtin_amdgcn_exp2f(sb.y);
    suma += ea; sumb += eb;
    Aa0 += ea * v.x; Aa1 += ea * v.y; Aa2 += ea * v.z; Aa3 += ea * v.w;
    Ab0 += eb * v.x; Ab1 += eb * v.y; Ab2 += eb * v.z; Ab3 += eb * v.w;
  }
  #pragma unroll
  for (int off = 8; off <= 32; off <<= 1) {
    red2(suma, off); red2(sumb, off);
    red2(Aa0, off); red2(Aa1, off); red2(Aa2, off); red2(Aa3, off);
    red2(Ab0, off); red2(Ab1, off); red2(Ab2, off); red2(Ab3, off);
  }
  if (oc != 0) return;
  float* o1p = o1 + (size_t)(b * 128 + g * 4) * N1;
  float sums[4] = {suma.x, suma.y, sumb.x, sumb.y};
  float a0[4] = {Aa0.x, Aa0.y, Ab0.x, Ab0.y};
  float a1[4] = {Aa1.x, Aa1.y, Ab1.x, Ab1.y};
  float a2[4] = {Aa2.x, Aa2.y, Ab2.x, Ab2.y};
  float a3[4] = {Aa3.x, Aa3.y, Ab3.x, Ab3.y};
  #pragma unroll
  for (int i2 = 0; i2 < 4; i2++) {
    if (!vld[i2]) continue;
    int n = nr[i2];
    float inv = 1.0f / sums[i2];
    o1p[n] = a0[i2] * inv;
    o1p[N1 + n] = a1[i2] * inv;
    o1p[2 * N1 + n] = a2[i2] * inv;
    o1p[3 * N1 + n] = a3[i2] * inv;
    if (g < 16) rowstat[(size_t)(b * 16 + g) * N1 + n] = inv;
  }
}

// coarse v3: 4 cols/thread, strided 16-way n-split. grid = 64 bg x 16 chunks.
__global__ __launch_bounds__(256) void k_coarse(const float* __restrict__ xd,
                                                const float* __restrict__ wqkv,
                                                const float* __restrict__ bqkv,
                                                const float* __restrict__ rowstat,
                                                float* __restrict__ coarse) {
  __shared__ float4 kS[N1];
  __shared__ float rs[N1];
  int tid = threadIdx.x;
  int chunk = blockIdx.x & 15;
  int bg = blockIdx.x >> 4;
  int b = bg >> 4, g = bg & 15;
  const float* xp0 = xd + (size_t)(b * 128 + g * 4) * N1;
  const float* rp = rowstat + (size_t)(b * 16 + g) * N1;
  for (int nn = tid; nn < N1; nn += 256) {
    float t0 = xp0[nn], t1 = xp0[N1 + nn], t2 = xp0[2 * N1 + nn], t3 = xp0[3 * N1 + nn];
    kS[nn] = QKV_G(4);
    rs[nn] = rp[nn];
  }
  __syncthreads();
  int wv = tid >> 6, lane = tid & 63;
  int oc = lane >> 2;
  int c0 = chunk * 64 + wv * 16 + (lane & 3);
  if (c0 >= N1) return;  // reduce-partners share c0 -> exit together
  int cr[4]; bool vld[4];
  float4 qr[4];
  #pragma unroll
  for (int i2 = 0; i2 < 4; i2++) {
    int c = c0 + 4 * i2; cr[i2] = c; vld[i2] = c < N1;
    int cc = vld[i2] ? c : c0;
    float t0 = xp0[cc], t1 = xp0[N1 + cc], t2 = xp0[2 * N1 + cc], t3 = xp0[3 * N1 + cc];
    float4 qq = QKV_G(0);
    qr[i2] = make_float4(qq.x * L2E, qq.y * L2E, qq.z * L2E, qq.w * L2E);
  }
  v2f qax = {qr[0].x, qr[1].x}, qay = {qr[0].y, qr[1].y};
  v2f qaz = {qr[0].z, qr[1].z}, qaw = {qr[0].w, qr[1].w};
  v2f qbx = {qr[2].x, qr[3].x}, qby = {qr[2].y, qr[3].y};
  v2f qbz = {qr[2].z, qr[3].z}, qbw = {qr[2].w, qr[3].w};
  v2f ca = {0.f, 0.f}, cb = {0.f, 0.f};
  #pragma unroll 4
  for (int n = oc; n < N1; n += 16) {
    float4 k = kS[n];
    float r = rs[n];
    v2f sa = qax * k.x + qay * k.y + qaz * k.z + qaw * k.w;
    v2f sb = qbx * k.x + qby * k.y + qbz * k.z + qbw * k.w;
    v2f ea, eb;
    ea.x = __builtin_amdgcn_exp2f(sa.x); ea.y = __builtin_amdgcn_exp2f(sa.y);
    eb.x = __builtin_amdgcn_exp2f(sb.x); eb.y = __builtin_amdgcn_exp2f(sb.y);
    ca += ea * r; cb += eb * r;
  }
  #pragma unroll
  for (int off = 4; off <= 32; off <<= 1) {
    red2(ca, off); red2(cb, off);
  }
  if (oc != 0) return;
  float* cp = coarse + (size_t)(b * 16 + g) * N1;
  float cv[4] = {ca.x, ca.y, cb.x, cb.y};
  #pragma unroll
  for (int i2 = 0; i2 < 4; i2++)
    if (vld[i2]) cp[cr[i2]] = cv[i2];
}

// top-240 per (b,g<16): bitonic over 1024 packed keys
__global__ __launch_bounds__(256) void k_topk(const float* __restrict__ coarse,
                                              int* __restrict__ topk) {
  __shared__ unsigned long long keys[1024];
  int tid = threadIdx.x;
  int bg = blockIdx.x;
  const float* cp = coarse + (size_t)bg * N1;
  for (int i = tid; i < 1024; i += 256) {
    unsigned long long key = 0ull;
    if (i < N1) {
      unsigned fb = __float_as_uint(cp[i]);
      key = ((unsigned long long)fb << 32) | (unsigned)(N1 - 1 - i);
    }
    keys[i] = key;
  }
  __syncthreads();
  for (int k2 = 2; k2 <= 1024; k2 <<= 1) {
    for (int j = k2 >> 1; j > 0; j >>= 1) {
      for (int i = tid; i < 1024; i += 256) {
        int ixj = i ^ j;
        if (ixj > i) {
          unsigned long long a = keys[i], bb = keys[ixj];
          bool up = ((i & k2) == 0);
          if ((a > bb) == up) { keys[i] = bb; keys[ixj] = a; }
        }
      }
      __syncthreads();
    }
  }
  if (tid < KF) {
    unsigned long long key = keys[1023 - tid];
    topk[(size_t)bg * KF + tid] = (N1 - 1) - (int)(unsigned)(key & 0xffffffffull);
  }
}

// transposed conv, per-parity: o1(4,128,31,31) -> yacc = 2*coarse_out (4,64,62,62)
// weights via scalar path (s_load) from pre-transposed wT.
__global__ __launch_bounds__(256) void k_upconv(const float* __restrict__ o1,
                                                const float* __restrict__ wT,
                                                const float* __restrict__ bias,
                                                float* __restrict__ yacc) {
  __shared__ float iS[16][9][12];
  int tid = threadIdx.x;
  int bid = blockIdx.x;
  int b = bid >> 8;
  int cog = (bid >> 6) & 3;
  int par = (bid >> 4) & 3;
  int py = par >> 1, px = par & 1;
  int tile = bid & 15;
  int r0 = (tile >> 2) * 8, c0 = (tile & 3) * 8;
  int wv = tid >> 6, lane = tid & 63;
  int pr = lane >> 3, pc = lane & 7;
  int cwu = __builtin_amdgcn_readfirstlane(cog * 4 + wv);  // co-quad 0..15, wave-uniform
  const float4* wq = (const float4*)wT + ((size_t)par * 2048 + cwu) * 4;
  int cobase = cog * 16 + wv * 4;
  float acc[4] = {0.f, 0.f, 0.f, 0.f};
  const float* ob = o1 + (size_t)b * 128 * N1;
  for (int ch = 0; ch < 8; ch++) {
    __syncthreads();
    for (int e = tid; e < 16 * 81; e += 256) {
      int dx = e % 9; int t = e / 9;
      int dy = t % 9; int ci = t / 9;
      int iy = r0 + py - 1 + dy, ix = c0 + px - 1 + dx;
      float v = 0.f;
      if (iy >= 0 && iy < 31 && ix >= 0 && ix < 31)
        v = ob[(size_t)(ch * 16 + ci) * N1 + iy * 31 + ix];
      iS[ci][dy][dx] = v;
    }
    __syncthreads();
    #pragma unroll
    for (int ci = 0; ci < 16; ci++) {
      int cig = ch * 16 + ci;
      float4 w0 = wq[(size_t)cig * 64 + 0];
      float4 w1 = wq[(size_t)cig * 64 + 1];
      float4 w2 = wq[(size_t)cig * 64 + 2];
      float4 w3 = wq[(size_t)cig * 64 + 3];
      float x00 = iS[ci][pr][pc],     x01 = iS[ci][pr][pc + 1];
      float x10 = iS[ci][pr + 1][pc], x11 = iS[ci][pr + 1][pc + 1];
      acc[0] += w0.x * x00; acc[1] += w0.y * x00; acc[2] += w0.z * x00; acc[3] += w0.w * x00;
      acc[0] += w1.x * x01; acc[1] += w1.y * x01; acc[2] += w1.z * x01; acc[3] += w1.w * x01;
      acc[0] += w2.x * x10; acc[1] += w2.y * x10; acc[2] += w2.z * x10; acc[3] += w2.w * x10;
      acc[0] += w3.x * x11; acc[1] += w3.y * x11; acc[2] += w3.z * x11; acc[3] += w3.w * x11;
    }
  }
  int r = r0 + pr, c = c0 + pc;
  if (r >= 31 || c >= 31) return;
  int y = 2 * r + py, xx = 2 * c + px;
  #pragma unroll
  for (int cc = 0; cc < 4; cc++) {
    int co = cobase + cc;
    yacc[(size_t)(b * 64 + co) * HW2 + y * 62 + xx] = 2.0f * (acc[cc] + bias[co]);
  }
}

// attention 2 v3: 4 rows/thread, strided 8-way m-split. grid = 64 bg x 8 chunks.
__global__ __launch_bounds__(256) void k_attn2(const float* __restrict__ yacc,
                                               const float* __restrict__ wqkv,
                                               const float* __restrict__ bqkv,
                                               const int* __restrict__ topk,
                                               float4* __restrict__ o2,
                                               int* __restrict__ coordg) {
  __shared__ float4 qvv[2 * N2];
  int tid = threadIdx.x;
  int chunk = blockIdx.x & 7;
  int bg = blockIdx.x >> 3;
  int b = bg >> 4, g = bg & 15;
  const float* yp0 = yacc + (size_t)(b * 64 + g * 4) * HW2;
  const int* ip = topk + (size_t)bg * KF;
  for (int nn = tid; nn < N2; nn += 256) {
    int tt = nn >> 2, i = (nn >> 1) & 1, j = nn & 1;
    int p = ip[tt];
    int ph = p / 31, pw = p - ph * 31;
    int cc = (2 * ph + i) * 62 + (2 * pw + j);
    float t0 = 0.5f * yp0[cc], t1 = 0.5f * yp0[HW2 + cc];
    float t2 = 0.5f * yp0[2 * HW2 + cc], t3 = 0.5f * yp0[3 * HW2 + cc];
    qvv[2 * nn]     = QKV_G(0);
    qvv[2 * nn + 1] = QKV_G(8);
  }
  __syncthreads();
  int wv = tid >> 6, lane = tid & 63;
  int oc = lane >> 3;
  int n0 = chunk * 128 + wv * 32 + (lane & 7);
  if (n0 >= N2) return;
  int nr[4]; int ccr[4]; bool vld[4];
  float4 kr[4];
  #pragma unroll
  for (int i2 = 0; i2 < 4; i2++) {
    int n = n0 + 8 * i2; nr[i2] = n; vld[i2] = n < N2;
    int nc = vld[i2] ? n : n0;
    int tt = nc >> 2, ii = (nc >> 1) & 1, jj = nc & 1;
    int p = ip[tt];
    int ph = p / 31, pw = p - ph * 31;
    int cc = (2 * ph + ii) * 62 + (2 * pw + jj);
    ccr[i2] = cc;
    float t0 = 0.5f * yp0[cc], t1 = 0.5f * yp0[HW2 + cc];
    float t2 = 0.5f * yp0[2 * HW2 + cc], t3 = 0.5f * yp0[3 * HW2 + cc];
    float4 kk = QKV_G(4);
    kr[i2] = make_float4(kk.x * L2E, kk.y * L2E, kk.z * L2E, kk.w * L2E);
  }
  v2f kax = {kr[0].x, kr[1].x}, kay = {kr[0].y, kr[1].y};
  v2f kaz = {kr[0].z, kr[1].z}, kaw = {kr[0].w, kr[1].w};
  v2f kbx = {kr[2].x, kr[3].x}, kby = {kr[2].y, kr[3].y};
  v2f kbz = {kr[2].z, kr[3].z}, kbw = {kr[2].w, kr[3].w};
  v2f suma = {0.f, 0.f}, sumb = {0.f, 0.f};
  v2f Aa0 = {0.f, 0.f}, Aa1 = {0.f, 0.f}, Aa2 = {0.f, 0.f}, Aa3 = {0.f, 0.f};
  v2f Ab0 = {0.f, 0.f}, Ab1 = {0.f, 0.f}, Ab2 = {0.f, 0.f}, Ab3 = {0.f, 0.f};
  #pragma unroll 4
  for (int m = oc; m < N2; m += 8) {
    float4 q = qvv[2 * m];
    float4 v = qvv[2 * m + 1];
    v2f sa = kax * q.x + kay * q.y + kaz * q.z + kaw * q.w;
    v2f sb = kbx * q.x + kby * q.y + kbz * q.z + kbw * q.w;
    v2f ea, eb;
    ea.x = __builtin_amdgcn_exp2f(sa.x); ea.y = __builtin_amdgcn_exp2f(sa.y);
    eb.x = __builtin_amdgcn_exp2f(sb.x); eb.y = __builtin_amdgcn_exp2f(sb.y);
    suma += ea; sumb += eb;
    Aa0 += ea * v.x; Aa1 += ea * v.y; Aa2 += ea * v.z; Aa3 += ea * v.w;
    Ab0 += eb * v.x; Ab1 += eb * v.y; Ab2 += eb * v.z; Ab3 += eb * v.w;
  }
  #pragma unroll
  for (int off = 8; off <= 32; off <<= 1) {
    red2(suma, off); red2(sumb, off);
    red2(Aa0, off); red2(Aa1, off); red2(Aa2, off); red2(Aa3, off);
    red2(Ab0, off); red2(Ab1, off); red2(Ab2, off); red2(Ab3, off);
  }
  if (oc != 0) return;
  float sums[4] = {suma.x, suma.y, sumb.x, sumb.y};
  float a0[4] = {Aa0.x, Aa0.y, Ab0.x, Ab0.y};
  float a1[4] = {Aa1.x, Aa1.y, Ab1.x, Ab1.y};
  float a2[4] = {Aa2.x, Aa2.y, Ab2.x, Ab2.y};
  float a3[4] = {Aa3.x, Aa3.y, Ab3.x, Ab3.y};
  #pragma unroll
  for (int i2 = 0; i2 < 4; i2++) {
    if (!vld[i2]) continue;
    float inv = 1.0f / sums[i2];
    size_t oi = (size_t)bg * N2 + nr[i2];
    o2[oi] = make_float4(a0[i2] * inv, a1[i2] * inv, a2[i2] * inv, a3[i2] * inv);
    coordg[oi] = ccr[i2];
  }
}

// scatter-add attn2 output into yacc (disjoint targets)
__global__ __launch_bounds__(256) void k_scatter(float* __restrict__ yacc,
                                                 const float4* __restrict__ o2,
                                                 const int* __restrict__ coordg) {
  int idx = blockIdx.x * 256 + threadIdx.x;
  if (idx >= 64 * N2) return;
  int bg = idx / N2;
  int b = bg >> 4, g = bg & 15;
  float4 o = o2[idx];
  int cc = coordg[idx];
  float* yp0 = yacc + (size_t)(b * 64 + g * 4) * HW2;
  yp0[cc] += o.x;
  yp0[HW2 + cc] += o.y;
  yp0[2 * HW2 + cc] += o.z;
  yp0[3 * HW2 + cc] += o.w;
}

// depthwise 3x3, pad 1
__global__ __launch_bounds__(256) void k_dwconv(const float* __restrict__ yin,
                                                const float* __restrict__ w,
                                                float* __restrict__ z1) {
  int idx = blockIdx.x * 256 + threadIdx.x;
  if (idx >= 64 * NPIX) return;
  int x = idx % 62; int t = idx / 62;
  int y = t % 62; t /= 62;
  int c = t % 64;
  int plane = idx / HW2;
  const float* yp = yin + (size_t)plane * HW2;
  const float* wp = w + c * 9;
  float acc = 0.f;
  #pragma unroll
  for (int ky = 0; ky < 3; ky++) {
    int yy = y + ky - 1;
    if (yy < 0 || yy > 61) continue;
    #pragma unroll
    for (int kx = 0; kx < 3; kx++) {
      int xx = x + kx - 1;
      if (xx < 0 || xx > 61) continue;
      acc += yp[yy * 62 + xx] * wp[ky * 3 + kx];
    }
  }
  z1[idx] = acc;
}

__device__ __forceinline__ float wave_sum(float x) {
  #pragma unroll
  for (int off = 32; off > 0; off >>= 1) x += __shfl_xor(x, off, 64);
  return x;
}

// per-channel sum/sumsq; grid 1024 = c(64) x b(4) x seg(4: 961 px each)
__global__ __launch_bounds__(256) void k_stats(const float* __restrict__ buf,
                                               float* __restrict__ stats) {
  __shared__ float red[8];
  int bid = blockIdx.x;
  int seg = bid & 3;
  int b = (bid >> 2) & 3;
  int c = bid >> 4;
  const float* p = buf + (size_t)(b * 64 + c) * HW2;
  int i0 = seg * 961;
  float s = 0.f, s2 = 0.f;
  for (int i = i0 + threadIdx.x; i < i0 + 961; i += 256) {
    float z = p[i]; s += z; s2 += z * z;
  }
  s = wave_sum(s); s2 = wave_sum(s2);
  int wave = threadIdx.x >> 6, lane = threadIdx.x & 63;
  if (lane == 0) { red[wave] = s; red[4 + wave] = s2; }
  __syncthreads();
  if (threadIdx.x == 0) {
    atomicAdd(&stats[c], red[0] + red[1] + red[2] + red[3]);
    atomicAdd(&stats[64 + c], red[4] + red[5] + red[6] + red[7]);
  }
}

__global__ void k_bnparam(const float* __restrict__ stats, const float* __restrict__ gamma,
                          const float* __restrict__ beta, float* __restrict__ par) {
  int c = threadIdx.x;
  if (c < 64) {
    float m = stats[c] * (1.0f / NPIX);
    float v = stats[64 + c] * (1.0f / NPIX) - m * m;
    float a = gamma[c] * rsqrtf(v + 1e-5f);
    par[c] = a; par[64 + c] = beta[c] - m * a;
  }
}

// pointwise 1x1, co-split x16 (4 co/block): grid = pixblocks(61) x cog(16)
__global__ __launch_bounds__(256) void k_pwconv(const float* __restrict__ z1,
                                                const float* __restrict__ wpw,
                                                const float* __restrict__ par,
                                                float* __restrict__ z2) {
  __shared__ float w[4 * 64];
  __shared__ float aa[64], cb[64];
  int tid = threadIdx.x;
  int cog = blockIdx.x & 15;
  int pb = blockIdx.x >> 4;
  if (tid < 64) { aa[tid] = par[tid]; cb[tid] = par[64 + tid]; }
  for (int i = tid; i < 256; i += 256) w[i] = wpw[cog * 256 + i];
  __syncthreads();
  int pix = pb * 256 + tid;
  if (pix >= NPIX) return;
  int b = pix / HW2, p = pix - b * HW2;
  float h[64];
  #pragma unroll
  for (int ci = 0; ci < 64; ci++) {
    float z = z1[(size_t)(b * 64 + ci) * HW2 + p];
    z = aa[ci] * z + cb[ci];
    h[ci] = fminf(fmaxf(z, 0.f), 6.f);
  }
  #pragma unroll
  for (int cc = 0; cc < 4; cc++) {
    float acc = 0.f;
    #pragma unroll
    for (int ci = 0; ci < 64; ci++) acc += h[ci] * w[cc * 64 + ci];
    z2[(size_t)(b * 64 + cog * 4 + cc) * HW2 + p] = acc;
  }
}

__global__ __launch_bounds__(256) void k_final(const float* __restrict__ z2,
                                               const float* __restrict__ par,
                                               float* __restrict__ out) {
  int idx = blockIdx.x * 256 + threadIdx.x;
  if (idx >= 64 * NPIX) return;
  int c = (idx / HW2) & 63;
  float z = par[c] * z2[idx] + par[64 + c];
  out[idx] = fminf(fmaxf(z, 0.f), 6.f);
}

extern "C" void kernel_launch(void* const* d_in, const int* in_sizes, int n_in,
                              void* d_out, int out_size, void* d_ws, size_t ws_size,
                              hipStream_t stream) {
  const float* x       = (const float*)d_in[0];
  const float* w_down  = (const float*)d_in[1];
  const float* b_down  = (const float*)d_in[2];
  const float* w_qkv_c = (const float*)d_in[3];
  const float* b_qkv_c = (const float*)d_in[4];
  const float* w_up    = (const float*)d_in[5];
  const float* b_up    = (const float*)d_in[6];
  const float* w_qkv_t = (const float*)d_in[7];
  const float* b_qkv_t = (const float*)d_in[8];
  const float* w_dw    = (const float*)d_in[9];
  const float* g_dw    = (const float*)d_in[10];
  const float* be_dw   = (const float*)d_in[11];
  const float* w_pw    = (const float*)d_in[12];
  const float* g_pw    = (const float*)d_in[13];
  const float* be_pw   = (const float*)d_in[14];
  float* out = (float*)d_out;

  float* ws    = (float*)d_ws;
  float* xd    = ws;                       // 492032 = 4*128*961
  float* o1    = xd + 492032;              // 492032
  int*   topk  = (int*)(o1 + 492032);      // 15360 = 4*16*240
  float* yacc  = (float*)(topk + 15360);   // 984064 = 4*64*62*62
  float* z1    = yacc + 984064;            // 984064
  float* z2    = z1 + 984064;              // 984064
  float* stats = z2 + 984064;              // 256
  float* par   = stats + 256;              // 256

  // disjoint-lifetime aliases:
  float*  rowstat = z1;                    // 4*16*961 floats (post-combine)
  float*  coarse  = z1 + 61504;            // 4*16*961 floats
  float4* o2      = (float4*)z2;           // 4*16*960 float4
  int*    coordg  = (int*)(z2 + 245760);   // 61440 ints
  float*  wT      = z2;                    // 131072 floats (combine..upconv window)

  k_zero<<<1, 256, 0, stream>>>(stats, 256);
  k_down<<<1024, 256, 0, stream>>>(x, w_down,
                                   o1, yacc, yacc + 492032, z1, z1 + 492032,
                                   z2, z2 + 492032, xd);
  k_combine<<<(XDSZ + 255) / 256, 256, 0, stream>>>(o1, yacc, yacc + 492032, z1,
                                                    z1 + 492032, z2, z2 + 492032,
                                                    b_down, xd);
  k_wtr<<<512, 256, 0, stream>>>(w_up, wT);
  k_attn1<<<1024, 256, 0, stream>>>(xd, w_qkv_c, b_qkv_c, o1, rowstat);
  k_coarse<<<1024, 256, 0, stream>>>(xd, w_qkv_c, b_qkv_c, rowstat, coarse);
  k_topk<<<64, 256, 0, stream>>>(coarse, topk);
  k_upconv<<<1024, 256, 0, stream>>>(o1, wT, b_up, yacc);
  k_attn2<<<512, 256, 0, stream>>>(yacc, w_qkv_t, b_qkv_t, topk, o2, coordg);
  k_scatter<<<(64 * N2 + 255) / 256, 256, 0, stream>>>(yacc, o2, coordg);
  k_dwconv<<<(64 * NPIX + 255) / 256, 256, 0, stream>>>(yacc, w_dw, z1);
  k_stats<<<1024, 256, 0, stream>>>(z1, stats);
  k_bnparam<<<1, 64, 0, stream>>>(stats, g_dw, be_dw, par);
  k_pwconv<<<61 * 16, 256, 0, stream>>>(z1, w_pw, par, z2);
  k_stats<<<1024, 256, 0, stream>>>(z2, stats + 128);
  k_bnparam<<<1, 64, 0, stream>>>(stats + 128, g_pw, be_pw, par + 128);
  k_final<<<(64 * NPIX + 255) / 256, 256, 0, stream>>>(z2, par + 128, out);
}

// Round 3
// 298.984 us; speedup vs baseline: 1.0588x; 1.0251x over previous
//
#include <hip/hip_runtime.h>
#include <math.h>

#define N1 961
#define N2 960
#define KF 240
#define HW2 3844   // 62*62
#define NPIX 15376 // 4*62*62
#define XDSZ 492032 // 4*128*961
#define L2E 1.44269504f

typedef float v2f __attribute__((ext_vector_type(2)));

// down conv v5: 2x2 px x 4 co per thread, K-split x8 (1024 blocks = 4/CU).
// Weights via SCALAR path from pre-transposed wdT (no wS LDS, no b128 broadcasts).
__global__ __launch_bounds__(256) void k_down(const float* __restrict__ x,
                                              const float* __restrict__ wdT,
                                              float* __restrict__ p0, float* __restrict__ p1,
                                              float* __restrict__ p2, float* __restrict__ p3,
                                              float* __restrict__ p4, float* __restrict__ p5,
                                              float* __restrict__ p6, float* __restrict__ p7) {
  __shared__ float iS[4][18][72];
  int tid = threadIdx.x;
  int bid = blockIdx.x;
  int kchunk = bid & 7;
  int rowtile = (bid >> 3) & 3;
  int cog = (bid >> 5) & 7;
  int b = bid >> 8;
  int r0 = rowtile * 8;
  int wv = tid >> 6, lane = tid & 63;
  int pc = lane & 15, pr = lane >> 4;
  // wave-uniform co-quad index 0..31; wdT layout [(q*64 + ci)*16 + tap][c4]
  int qd = __builtin_amdgcn_readfirstlane(cog * 4 + wv);
  const float4* wqd = (const float4*)wdT + (size_t)qd * 1024;  // 64 ci x 16 taps
  float acc[4][4];  // [px][co]
  #pragma unroll
  for (int i = 0; i < 4; i++)
    #pragma unroll
    for (int j = 0; j < 4; j++) acc[i][j] = 0.f;
  const float* xb = x + (size_t)b * 64 * 4096;
  for (int sub = 0; sub < 2; sub++) {
    int cibase = kchunk * 8 + sub * 4;
    __syncthreads();
    for (int e = tid; e < 4 * 18 * 66; e += 256) {
      int dx = e % 66; int t = e / 66;
      int dy = t % 18; int ci = t / 18;
      int iy = 2 * r0 + dy;
      iS[ci][dy][dx] = (dx < 64 && iy < 64)
                           ? xb[(size_t)(cibase + ci) * 4096 + iy * 64 + dx] : 0.f;
    }
    __syncthreads();
    #pragma unroll
    for (int ci = 0; ci < 4; ci++) {
      const float4* wc = wqd + (size_t)(cibase + ci) * 16;  // uniform -> s_load
      float xr[6][6];
      #pragma unroll
      for (int rr = 0; rr < 6; rr++)
        #pragma unroll
        for (int jj = 0; jj < 3; jj++) {
          float2 v2 = *(const float2*)&iS[ci][4 * pr + rr][4 * pc + 2 * jj];
          xr[rr][2 * jj] = v2.x; xr[rr][2 * jj + 1] = v2.y;
        }
      #pragma unroll
      for (int ky = 0; ky < 4; ky++)
        #pragma unroll
        for (int kx = 0; kx < 4; kx++) {
          float4 wq = wc[ky * 4 + kx];  // SGPR
          #pragma unroll
          for (int dy2 = 0; dy2 < 2; dy2++)
            #pragma unroll
            for (int dx2 = 0; dx2 < 2; dx2++) {
              float xv = xr[2 * dy2 + ky][2 * dx2 + kx];
              int px = dy2 * 2 + dx2;
              acc[px][0] += wq.x * xv; acc[px][1] += wq.y * xv;
              acc[px][2] += wq.z * xv; acc[px][3] += wq.w * xv;
            }
        }
    }
  }
  float* parts[8] = {p0, p1, p2, p3, p4, p5, p6, p7};
  float* xo = parts[kchunk] + (size_t)b * 128 * N1;
  #pragma unroll
  for (int dy2 = 0; dy2 < 2; dy2++) {
    int r = r0 + 2 * pr + dy2;
    if (r >= 31) continue;
    #pragma unroll
    for (int dx2 = 0; dx2 < 2; dx2++) {
      int c = 2 * pc + dx2;
      if (c >= 31) continue;
      #pragma unroll
      for (int cc = 0; cc < 4; cc++)
        xo[(size_t)(cog * 16 + wv * 4 + cc) * N1 + r * 31 + c] = acc[dy2 * 2 + dx2][cc];
    }
  }
}

// combine 7 K-partials + xd(8th partial) + bias -> xd
__global__ __launch_bounds__(256) void k_combine(const float* __restrict__ p0,
                                                 const float* __restrict__ p1,
                                                 const float* __restrict__ p2,
                                                 const float* __restrict__ p3,
                                                 const float* __restrict__ p4,
                                                 const float* __restrict__ p5,
                                                 const float* __restrict__ p6,
                                                 const float* __restrict__ bias,
                                                 float* __restrict__ xd) {
  int i = blockIdx.x * 256 + threadIdx.x;
  if (i >= XDSZ) return;
  int co = (i / N1) & 127;
  float s = ((p0[i] + p1[i]) + (p2[i] + p3[i])) + ((p4[i] + p5[i]) + (p6[i] + xd[i]));
  xd[i] = bias[co] + s;
}

// weight pre-transposes (upconv wT + downconv wdT) + stats zeroing.
// blocks 0..511:   wT[((par*128 + ci)*16 + cw)*16 + t*4 + c] = w_up[ci][cw*4+c][wo_par(t)]
// blocks 512..1023: wdT[((q*64 + ci)*16 + tap)*4 + c] = w_down[q*4+c][ci][tap]
__global__ __launch_bounds__(256) void k_wtr(const float* __restrict__ wup,
                                             const float* __restrict__ wdn,
                                             float* __restrict__ wT,
                                             float* __restrict__ wdT,
                                             float* __restrict__ stats) {
  int tid = threadIdx.x;
  int bid = blockIdx.x;
  if (bid == 0) stats[tid] = 0.f;
  if (bid < 512) {
    int idx = bid * 256 + tid;
    int c = idx & 3;
    int t = (idx >> 2) & 3;
    int cw = (idx >> 4) & 15;
    int ci = (idx >> 8) & 127;
    int par = idx >> 15;
    int py = par >> 1, px = par & 1;
    int a = t >> 1, d = t & 1;
    int tap = (3 - (py + 2 * a)) * 4 + (3 - (px + 2 * d));
    int co = cw * 4 + c;
    wT[idx] = wup[(size_t)ci * 1024 + co * 16 + tap];
  } else {
    int idx = (bid - 512) * 256 + tid;
    int c = idx & 3;
    int tap = (idx >> 2) & 15;
    int ci = (idx >> 6) & 63;
    int q = idx >> 12;  // 0..31
    wdT[idx] = wdn[(size_t)(q * 4 + c) * 1024 + ci * 16 + tap];
  }
}

// QKV projection with weights read via the SCALAR path (uniform s_load; SGPR
// operand feeds v_fma directly). L2E folded into callers' k/q registers.
#define QKV_G(off) make_float4( \
    t0 * wqkv[(off)] + t1 * wqkv[12 + (off)] + t2 * wqkv[24 + (off)] + t3 * wqkv[36 + (off)] + bqkv[(off)], \
    t0 * wqkv[(off)+1] + t1 * wqkv[12 + (off)+1] + t2 * wqkv[24 + (off)+1] + t3 * wqkv[36 + (off)+1] + bqkv[(off)+1], \
    t0 * wqkv[(off)+2] + t1 * wqkv[12 + (off)+2] + t2 * wqkv[24 + (off)+2] + t3 * wqkv[36 + (off)+2] + bqkv[(off)+2], \
    t0 * wqkv[(off)+3] + t1 * wqkv[12 + (off)+3] + t2 * wqkv[24 + (off)+3] + t3 * wqkv[36 + (off)+3] + bqkv[(off)+3])

__device__ __forceinline__ void red2(v2f& a, int off) {
  a.x += __shfl_xor(a.x, off, 64);
  a.y += __shfl_xor(a.y, off, 64);
}

// attention 1: 4 rows/thread, strided 8-way m-split. grid = 128 bg x 8 chunks.
__global__ __launch_bounds__(256) void k_attn1(const float* __restrict__ xd,
                                               const float* __restrict__ wqkv,
                                               const float* __restrict__ bqkv,
                                               float* __restrict__ o1,
                                               float* __restrict__ rowstat) {
  __shared__ float4 qvv[2 * N1];
  int tid = threadIdx.x;
  int chunk = blockIdx.x & 7;
  int bg = blockIdx.x >> 3;
  int b = bg >> 5, g = bg & 31;
  const float* xp0 = xd + (size_t)(b * 128 + g * 4) * N1;
  for (int nn = tid; nn < N1; nn += 256) {
    float t0 = xp0[nn], t1 = xp0[N1 + nn], t2 = xp0[2 * N1 + nn], t3 = xp0[3 * N1 + nn];
    qvv[2 * nn]     = QKV_G(0);
    qvv[2 * nn + 1] = QKV_G(8);
  }
  __syncthreads();
  int wv = tid >> 6, lane = tid & 63;
  int oc = lane >> 3;
  int n0 = chunk * 128 + wv * 32 + (lane & 7);
  if (n0 >= N1) return;  // reduce-partners share n0 -> exit together
  int nr[4]; bool vld[4];
  float4 kr[4];
  #pragma unroll
  for (int i2 = 0; i2 < 4; i2++) {
    int n = n0 + 8 * i2; nr[i2] = n; vld[i2] = n < N1;
    int nc = vld[i2] ? n : n0;
    float t0 = xp0[nc], t1 = xp0[N1 + nc], t2 = xp0[2 * N1 + nc], t3 = xp0[3 * N1 + nc];
    float4 kk = QKV_G(4);
    kr[i2] = make_float4(kk.x * L2E, kk.y * L2E, kk.z * L2E, kk.w * L2E);
  }
  v2f kax = {kr[0].x, kr[1].x}, kay = {kr[0].y, kr[1].y};
  v2f kaz = {kr[0].z, kr[1].z}, kaw = {kr[0].w, kr[1].w};
  v2f kbx = {kr[2].x, kr[3].x}, kby = {kr[2].y, kr[3].y};
  v2f kbz = {kr[2].z, kr[3].z}, kbw = {kr[2].w, kr[3].w};
  v2f suma = {0.f, 0.f}, sumb = {0.f, 0.f};
  v2f Aa0 = {0.f, 0.f}, Aa1 = {0.f, 0.f}, Aa2 = {0.f, 0.f}, Aa3 = {0.f, 0.f};
  v2f Ab0 = {0.f, 0.f}, Ab1 = {0.f, 0.f}, Ab2 = {0.f, 0.f}, Ab3 = {0.f, 0.f};
  #pragma unroll 4
  for (int m = oc; m < N1; m += 8) {
    float4 q = qvv[2 * m];
    float4 v = qvv[2 * m + 1];
    v2f sa = kax * q.x + kay * q.y + kaz * q.z + kaw * q.w;
    v2f sb = kbx * q.x + kby * q.y + kbz * q.z + kbw * q.w;
    v2f ea, eb;
    ea.x = __builtin_amdgcn_exp2f(sa.x); ea.y = __builtin_amdgcn_exp2f(sa.y);
    eb.x = __builtin_amdgcn_exp2f(sb.x); eb.y = __builtin_amdgcn_exp2f(sb.y);
    suma += ea; sumb += eb;
    Aa0 += ea * v.x; Aa1 += ea * v.y; Aa2 += ea * v.z; Aa3 += ea * v.w;
    Ab0 += eb * v.x; Ab1 += eb * v.y; Ab2 += eb * v.z; Ab3 += eb * v.w;
  }
  #pragma unroll
  for (int off = 8; off <= 32; off <<= 1) {
    red2(suma, off); red2(sumb, off);
    red2(Aa0, off); red2(Aa1, off); red2(Aa2, off); red2(Aa3, off);
    red2(Ab0, off); red2(Ab1, off); red2(Ab2, off); red2(Ab3, off);
  }
  if (oc != 0) return;
  float* o1p = o1 + (size_t)(b * 128 + g * 4) * N1;
  float sums[4] = {suma.x, suma.y, sumb.x, sumb.y};
  float a0[4] = {Aa0.x, Aa0.y, Ab0.x, Ab0.y};
  float a1[4] = {Aa1.x, Aa1.y, Ab1.x, Ab1.y};
  float a2[4] = {Aa2.x, Aa2.y, Ab2.x, Ab2.y};
  float a3[4] = {Aa3.x, Aa3.y, Ab3.x, Ab3.y};
  #pragma unroll
  for (int i2 = 0; i2 < 4; i2++) {
    if (!vld[i2]) continue;
    int n = nr[i2];
    float inv = 1.0f / sums[i2];
    o1p[n] = a0[i2] * inv;
    o1p[N1 + n] = a1[i2] * inv;
    o1p[2 * N1 + n] = a2[i2] * inv;
    o1p[3 * N1 + n] = a3[i2] * inv;
    if (g < 16) rowstat[(size_t)(b * 16 + g) * N1 + n] = inv;
  }
}

// coarse: 4 cols/thread, strided 16-way n-split. grid = 64 bg x 16 chunks.
__global__ __launch_bounds__(256) void k_coarse(const float* __restrict__ xd,
                                                const float* __restrict__ wqkv,
                                                const float* __restrict__ bqkv,
                                                const float* __restrict__ rowstat,
                                                float* __restrict__ coarse) {
  __shared__ float4 kS[N1];
  __shared__ float rs[N1];
  int tid = threadIdx.x;
  int chunk = blockIdx.x & 15;
  int bg = blockIdx.x >> 4;
  int b = bg >> 4, g = bg & 15;
  const float* xp0 = xd + (size_t)(b * 128 + g * 4) * N1;
  const float* rp = rowstat + (size_t)(b * 16 + g) * N1;
  for (int nn = tid; nn < N1; nn += 256) {
    float t0 = xp0[nn], t1 = xp0[N1 + nn], t2 = xp0[2 * N1 + nn], t3 = xp0[3 * N1 + nn];
    kS[nn] = QKV_G(4);
    rs[nn] = rp[nn];
  }
  __syncthreads();
  int wv = tid >> 6, lane = tid & 63;
  int oc = lane >> 2;
  int c0 = chunk * 64 + wv * 16 + (lane & 3);
  if (c0 >= N1) return;  // reduce-partners share c0 -> exit together
  int cr[4]; bool vld[4];
  float4 qr[4];
  #pragma unroll
  for (int i2 = 0; i2 < 4; i2++) {
    int c = c0 + 4 * i2; cr[i2] = c; vld[i2] = c < N1;
    int cc = vld[i2] ? c : c0;
    float t0 = xp0[cc], t1 = xp0[N1 + cc], t2 = xp0[2 * N1 + cc], t3 = xp0[3 * N1 + cc];
    float4 qq = QKV_G(0);
    qr[i2] = make_float4(qq.x * L2E, qq.y * L2E, qq.z * L2E, qq.w * L2E);
  }
  v2f qax = {qr[0].x, qr[1].x}, qay = {qr[0].y, qr[1].y};
  v2f qaz = {qr[0].z, qr[1].z}, qaw = {qr[0].w, qr[1].w};
  v2f qbx = {qr[2].x, qr[3].x}, qby = {qr[2].y, qr[3].y};
  v2f qbz = {qr[2].z, qr[3].z}, qbw = {qr[2].w, qr[3].w};
  v2f ca = {0.f, 0.f}, cb = {0.f, 0.f};
  #pragma unroll 4
  for (int n = oc; n < N1; n += 16) {
    float4 k = kS[n];
    float r = rs[n];
    v2f sa = qax * k.x + qay * k.y + qaz * k.z + qaw * k.w;
    v2f sb = qbx * k.x + qby * k.y + qbz * k.z + qbw * k.w;
    v2f ea, eb;
    ea.x = __builtin_amdgcn_exp2f(sa.x); ea.y = __builtin_amdgcn_exp2f(sa.y);
    eb.x = __builtin_amdgcn_exp2f(sb.x); eb.y = __builtin_amdgcn_exp2f(sb.y);
    ca += ea * r; cb += eb * r;
  }
  #pragma unroll
  for (int off = 4; off <= 32; off <<= 1) {
    red2(ca, off); red2(cb, off);
  }
  if (oc != 0) return;
  float* cp = coarse + (size_t)(b * 16 + g) * N1;
  float cv[4] = {ca.x, ca.y, cb.x, cb.y};
  #pragma unroll
  for (int i2 = 0; i2 < 4; i2++)
    if (vld[i2]) cp[cr[i2]] = cv[i2];
}

// top-240 per (b,g<16): bitonic over 1024 packed keys
__global__ __launch_bounds__(256) void k_topk(const float* __restrict__ coarse,
                                              int* __restrict__ topk) {
  __shared__ unsigned long long keys[1024];
  int tid = threadIdx.x;
  int bg = blockIdx.x;
  const float* cp = coarse + (size_t)bg * N1;
  for (int i = tid; i < 1024; i += 256) {
    unsigned long long key = 0ull;
    if (i < N1) {
      unsigned fb = __float_as_uint(cp[i]);
      key = ((unsigned long long)fb << 32) | (unsigned)(N1 - 1 - i);
    }
    keys[i] = key;
  }
  __syncthreads();
  for (int k2 = 2; k2 <= 1024; k2 <<= 1) {
    for (int j = k2 >> 1; j > 0; j >>= 1) {
      for (int i = tid; i < 1024; i += 256) {
        int ixj = i ^ j;
        if (ixj > i) {
          unsigned long long a = keys[i], bb = keys[ixj];
          bool up = ((i & k2) == 0);
          if ((a > bb) == up) { keys[i] = bb; keys[ixj] = a; }
        }
      }
      __syncthreads();
    }
  }
  if (tid < KF) {
    unsigned long long key = keys[1023 - tid];
    topk[(size_t)bg * KF + tid] = (N1 - 1) - (int)(unsigned)(key & 0xffffffffull);
  }
}

// transposed conv, per-parity: o1(4,128,31,31) -> yacc = 2*coarse_out (4,64,62,62)
__global__ __launch_bounds__(256) void k_upconv(const float* __restrict__ o1,
                                                const float* __restrict__ wT,
                                                const float* __restrict__ bias,
                                                float* __restrict__ yacc) {
  __shared__ float iS[16][9][12];
  int tid = threadIdx.x;
  int bid = blockIdx.x;
  int b = bid >> 8;
  int cog = (bid >> 6) & 3;
  int par = (bid >> 4) & 3;
  int py = par >> 1, px = par & 1;
  int tile = bid & 15;
  int r0 = (tile >> 2) * 8, c0 = (tile & 3) * 8;
  int wv = tid >> 6, lane = tid & 63;
  int pr = lane >> 3, pc = lane & 7;
  int cwu = __builtin_amdgcn_readfirstlane(cog * 4 + wv);  // co-quad 0..15, wave-uniform
  const float4* wq = (const float4*)wT + ((size_t)par * 2048 + cwu) * 4;
  int cobase = cog * 16 + wv * 4;
  float acc[4] = {0.f, 0.f, 0.f, 0.f};
  const float* ob = o1 + (size_t)b * 128 * N1;
  for (int ch = 0; ch < 8; ch++) {
    __syncthreads();
    for (int e = tid; e < 16 * 81; e += 256) {
      int dx = e % 9; int t = e / 9;
      int dy = t % 9; int ci = t / 9;
      int iy = r0 + py - 1 + dy, ix = c0 + px - 1 + dx;
      float v = 0.f;
      if (iy >= 0 && iy < 31 && ix >= 0 && ix < 31)
        v = ob[(size_t)(ch * 16 + ci) * N1 + iy * 31 + ix];
      iS[ci][dy][dx] = v;
    }
    __syncthreads();
    #pragma unroll
    for (int ci = 0; ci < 16; ci++) {
      int cig = ch * 16 + ci;
      float4 w0 = wq[(size_t)cig * 64 + 0];
      float4 w1 = wq[(size_t)cig * 64 + 1];
      float4 w2 = wq[(size_t)cig * 64 + 2];
      float4 w3 = wq[(size_t)cig * 64 + 3];
      float x00 = iS[ci][pr][pc],     x01 = iS[ci][pr][pc + 1];
      float x10 = iS[ci][pr + 1][pc], x11 = iS[ci][pr + 1][pc + 1];
      acc[0] += w0.x * x00; acc[1] += w0.y * x00; acc[2] += w0.z * x00; acc[3] += w0.w * x00;
      acc[0] += w1.x * x01; acc[1] += w1.y * x01; acc[2] += w1.z * x01; acc[3] += w1.w * x01;
      acc[0] += w2.x * x10; acc[1] += w2.y * x10; acc[2] += w2.z * x10; acc[3] += w2.w * x10;
      acc[0] += w3.x * x11; acc[1] += w3.y * x11; acc[2] += w3.z * x11; acc[3] += w3.w * x11;
    }
  }
  int r = r0 + pr, c = c0 + pc;
  if (r >= 31 || c >= 31) return;
  int y = 2 * r + py, xx = 2 * c + px;
  #pragma unroll
  for (int cc = 0; cc < 4; cc++) {
    int co = cobase + cc;
    yacc[(size_t)(b * 64 + co) * HW2 + y * 62 + xx] = 2.0f * (acc[cc] + bias[co]);
  }
}

// attention 2: 4 rows/thread, strided 8-way m-split. grid = 64 bg x 8 chunks.
__global__ __launch_bounds__(256) void k_attn2(const float* __restrict__ yacc,
                                               const float* __restrict__ wqkv,
                                               const float* __restrict__ bqkv,
                                               const int* __restrict__ topk,
                                               float4* __restrict__ o2,
                                               int* __restrict__ coordg) {
  __shared__ float4 qvv[2 * N2];
  int tid = threadIdx.x;
  int chunk = blockIdx.x & 7;
  int bg = blockIdx.x >> 3;
  int b = bg >> 4, g = bg & 15;
  const float* yp0 = yacc + (size_t)(b * 64 + g * 4) * HW2;
  const int* ip = topk + (size_t)bg * KF;
  for (int nn = tid; nn < N2; nn += 256) {
    int tt = nn >> 2, i = (nn >> 1) & 1, j = nn & 1;
    int p = ip[tt];
    int ph = p / 31, pw = p - ph * 31;
    int cc = (2 * ph + i) * 62 + (2 * pw + j);
    float t0 = 0.5f * yp0[cc], t1 = 0.5f * yp0[HW2 + cc];
    float t2 = 0.5f * yp0[2 * HW2 + cc], t3 = 0.5f * yp0[3 * HW2 + cc];
    qvv[2 * nn]     = QKV_G(0);
    qvv[2 * nn + 1] = QKV_G(8);
  }
  __syncthreads();
  int wv = tid >> 6, lane = tid & 63;
  int oc = lane >> 3;
  int n0 = chunk * 128 + wv * 32 + (lane & 7);
  if (n0 >= N2) return;
  int nr[4]; int ccr[4]; bool vld[4];
  float4 kr[4];
  #pragma unroll
  for (int i2 = 0; i2 < 4; i2++) {
    int n = n0 + 8 * i2; nr[i2] = n; vld[i2] = n < N2;
    int nc = vld[i2] ? n : n0;
    int tt = nc >> 2, ii = (nc >> 1) & 1, jj = nc & 1;
    int p = ip[tt];
    int ph = p / 31, pw = p - ph * 31;
    int cc = (2 * ph + ii) * 62 + (2 * pw + jj);
    ccr[i2] = cc;
    float t0 = 0.5f * yp0[cc], t1 = 0.5f * yp0[HW2 + cc];
    float t2 = 0.5f * yp0[2 * HW2 + cc], t3 = 0.5f * yp0[3 * HW2 + cc];
    float4 kk = QKV_G(4);
    kr[i2] = make_float4(kk.x * L2E, kk.y * L2E, kk.z * L2E, kk.w * L2E);
  }
  v2f kax = {kr[0].x, kr[1].x}, kay = {kr[0].y, kr[1].y};
  v2f kaz = {kr[0].z, kr[1].z}, kaw = {kr[0].w, kr[1].w};
  v2f kbx = {kr[2].x, kr[3].x}, kby = {kr[2].y, kr[3].y};
  v2f kbz = {kr[2].z, kr[3].z}, kbw = {kr[2].w, kr[3].w};
  v2f suma = {0.f, 0.f}, sumb = {0.f, 0.f};
  v2f Aa0 = {0.f, 0.f}, Aa1 = {0.f, 0.f}, Aa2 = {0.f, 0.f}, Aa3 = {0.f, 0.f};
  v2f Ab0 = {0.f, 0.f}, Ab1 = {0.f, 0.f}, Ab2 = {0.f, 0.f}, Ab3 = {0.f, 0.f};
  #pragma unroll 4
  for (int m = oc; m < N2; m += 8) {
    float4 q = qvv[2 * m];
    float4 v = qvv[2 * m + 1];
    v2f sa = kax * q.x + kay * q.y + kaz * q.z + kaw * q.w;
    v2f sb = kbx * q.x + kby * q.y + kbz * q.z + kbw * q.w;
    v2f ea, eb;
    ea.x = __builtin_amdgcn_exp2f(sa.x); ea.y = __builtin_amdgcn_exp2f(sa.y);
    eb.x = __builtin_amdgcn_exp2f(sb.x); eb.y = __builtin_amdgcn_exp2f(sb.y);
    suma += ea; sumb += eb;
    Aa0 += ea * v.x; Aa1 += ea * v.y; Aa2 += ea * v.z; Aa3 += ea * v.w;
    Ab0 += eb * v.x; Ab1 += eb * v.y; Ab2 += eb * v.z; Ab3 += eb * v.w;
  }
  #pragma unroll
  for (int off = 8; off <= 32; off <<= 1) {
    red2(suma, off); red2(sumb, off);
    red2(Aa0, off); red2(Aa1, off); red2(Aa2, off); red2(Aa3, off);
    red2(Ab0, off); red2(Ab1, off); red2(Ab2, off); red2(Ab3, off);
  }
  if (oc != 0) return;
  float sums[4] = {suma.x, suma.y, sumb.x, sumb.y};
  float a0[4] = {Aa0.x, Aa0.y, Ab0.x, Ab0.y};
  float a1[4] = {Aa1.x, Aa1.y, Ab1.x, Ab1.y};
  float a2[4] = {Aa2.x, Aa2.y, Ab2.x, Ab2.y};
  float a3[4] = {Aa3.x, Aa3.y, Ab3.x, Ab3.y};
  #pragma unroll
  for (int i2 = 0; i2 < 4; i2++) {
    if (!vld[i2]) continue;
    float inv = 1.0f / sums[i2];
    size_t oi = (size_t)bg * N2 + nr[i2];
    o2[oi] = make_float4(a0[i2] * inv, a1[i2] * inv, a2[i2] * inv, a3[i2] * inv);
    coordg[oi] = ccr[i2];
  }
}

// scatter-add attn2 output into yacc (disjoint targets)
__global__ __launch_bounds__(256) void k_scatter(float* __restrict__ yacc,
                                                 const float4* __restrict__ o2,
                                                 const int* __restrict__ coordg) {
  int idx = blockIdx.x * 256 + threadIdx.x;
  if (idx >= 64 * N2) return;
  int bg = idx / N2;
  int b = bg >> 4, g = bg & 15;
  float4 o = o2[idx];
  int cc = coordg[idx];
  float* yp0 = yacc + (size_t)(b * 64 + g * 4) * HW2;
  yp0[cc] += o.x;
  yp0[HW2 + cc] += o.y;
  yp0[2 * HW2 + cc] += o.z;
  yp0[3 * HW2 + cc] += o.w;
}

__device__ __forceinline__ float wave_sum(float x) {
  #pragma unroll
  for (int off = 32; off > 0; off >>= 1) x += __shfl_xor(x, off, 64);
  return x;
}

// depthwise 3x3 + fused per-channel stats. grid = plane(256) x seg(4).
__global__ __launch_bounds__(256) void k_dwconv(const float* __restrict__ yin,
                                                const float* __restrict__ w,
                                                float* __restrict__ z1,
                                                float* __restrict__ stats) {
  __shared__ float red[8];
  int tid = threadIdx.x;
  int bid = blockIdx.x;
  int plane = bid >> 2, seg = bid & 3;  // plane = b*64 + c
  int c = plane & 63;
  const float* yp = yin + (size_t)plane * HW2;
  const float* wp = w + c * 9;  // uniform -> s_load
  float s = 0.f, s2 = 0.f;
  int i0 = seg * 961;
  for (int i = i0 + tid; i < i0 + 961; i += 256) {
    int y = i / 62, x = i - (i / 62) * 62;
    float acc = 0.f;
    #pragma unroll
    for (int ky = 0; ky < 3; ky++) {
      int yy = y + ky - 1;
      if (yy < 0 || yy > 61) continue;
      #pragma unroll
      for (int kx = 0; kx < 3; kx++) {
        int xx = x + kx - 1;
        if (xx < 0 || xx > 61) continue;
        acc += yp[yy * 62 + xx] * wp[ky * 3 + kx];
      }
    }
    z1[(size_t)plane * HW2 + i] = acc;
    s += acc; s2 += acc * acc;
  }
  s = wave_sum(s); s2 = wave_sum(s2);
  int wave = tid >> 6, lane = tid & 63;
  if (lane == 0) { red[wave] = s; red[4 + wave] = s2; }
  __syncthreads();
  if (tid == 0) {
    atomicAdd(&stats[c], red[0] + red[1] + red[2] + red[3]);
    atomicAdd(&stats[64 + c], red[4] + red[5] + red[6] + red[7]);
  }
}

__global__ void k_bnparam(const float* __restrict__ stats, const float* __restrict__ gamma,
                          const float* __restrict__ beta, float* __restrict__ par) {
  int c = threadIdx.x;
  if (c < 64) {
    float m = stats[c] * (1.0f / NPIX);
    float v = stats[64 + c] * (1.0f / NPIX) - m * m;
    float a = gamma[c] * rsqrtf(v + 1e-5f);
    par[c] = a; par[64 + c] = beta[c] - m * a;
  }
}

// pointwise 1x1 + fused z2 stats, co-split x16 (4 co/block): grid = 61 x 16
__global__ __launch_bounds__(256) void k_pwconv(const float* __restrict__ z1,
                                                const float* __restrict__ wpw,
                                                const float* __restrict__ par,
                                                float* __restrict__ z2,
                                                float* __restrict__ stats2) {
  __shared__ float w[4 * 64];
  __shared__ float aa[64], cb[64];
  __shared__ float redS[4][4], redQ[4][4];
  int tid = threadIdx.x;
  int cog = blockIdx.x & 15;
  int pb = blockIdx.x >> 4;
  if (tid < 64) { aa[tid] = par[tid]; cb[tid] = par[64 + tid]; }
  for (int i = tid; i < 256; i += 256) w[i] = wpw[cog * 256 + i];
  __syncthreads();
  int pix = pb * 256 + tid;
  bool valid = pix < NPIX;
  int pixc = valid ? pix : NPIX - 1;
  int b = pixc / HW2, p = pixc - b * HW2;
  float h[64];
  #pragma unroll
  for (int ci = 0; ci < 64; ci++) {
    float z = z1[(size_t)(b * 64 + ci) * HW2 + p];
    z = aa[ci] * z + cb[ci];
    h[ci] = fminf(fmaxf(z, 0.f), 6.f);
  }
  float ssum[4], ssq[4];
  #pragma unroll
  for (int cc = 0; cc < 4; cc++) {
    float acc = 0.f;
    #pragma unroll
    for (int ci = 0; ci < 64; ci++) acc += h[ci] * w[cc * 64 + ci];
    if (valid) z2[(size_t)(b * 64 + cog * 4 + cc) * HW2 + p] = acc;
    ssum[cc] = valid ? acc : 0.f;
    ssq[cc] = valid ? acc * acc : 0.f;
  }
  int wv = tid >> 6, lane = tid & 63;
  #pragma unroll
  for (int cc = 0; cc < 4; cc++) {
    ssum[cc] = wave_sum(ssum[cc]);
    ssq[cc] = wave_sum(ssq[cc]);
  }
  if (lane == 0) {
    #pragma unroll
    for (int cc = 0; cc < 4; cc++) { redS[wv][cc] = ssum[cc]; redQ[wv][cc] = ssq[cc]; }
  }
  __syncthreads();
  if (tid < 4) {
    float ts = redS[0][tid] + redS[1][tid] + redS[2][tid] + redS[3][tid];
    float tq = redQ[0][tid] + redQ[1][tid] + redQ[2][tid] + redQ[3][tid];
    atomicAdd(&stats2[cog * 4 + tid], ts);
    atomicAdd(&stats2[64 + cog * 4 + tid], tq);
  }
}

__global__ __launch_bounds__(256) void k_final(const float* __restrict__ z2,
                                               const float* __restrict__ par,
                                               float* __restrict__ out) {
  int idx = blockIdx.x * 256 + threadIdx.x;
  if (idx >= 64 * NPIX) return;
  int c = (idx / HW2) & 63;
  float z = par[c] * z2[idx] + par[64 + c];
  out[idx] = fminf(fmaxf(z, 0.f), 6.f);
}

extern "C" void kernel_launch(void* const* d_in, const int* in_sizes, int n_in,
                              void* d_out, int out_size, void* d_ws, size_t ws_size,
                              hipStream_t stream) {
  const float* x       = (const float*)d_in[0];
  const float* w_down  = (const float*)d_in[1];
  const float* b_down  = (const float*)d_in[2];
  const float* w_qkv_c = (const float*)d_in[3];
  const float* b_qkv_c = (const float*)d_in[4];
  const float* w_up    = (const float*)d_in[5];
  const float* b_up    = (const float*)d_in[6];
  const float* w_qkv_t = (const float*)d_in[7];
  const float* b_qkv_t = (const float*)d_in[8];
  const float* w_dw    = (const float*)d_in[9];
  const float* g_dw    = (const float*)d_in[10];
  const float* be_dw   = (const float*)d_in[11];
  const float* w_pw    = (const float*)d_in[12];
  const float* g_pw    = (const float*)d_in[13];
  const float* be_pw   = (const float*)d_in[14];
  float* out = (float*)d_out;

  float* ws    = (float*)d_ws;
  float* xd    = ws;                       // 492032 = 4*128*961
  float* o1    = xd + 492032;              // 492032
  int*   topk  = (int*)(o1 + 492032);      // 15360 = 4*16*240
  float* yacc  = (float*)(topk + 15360);   // 984064 = 4*64*62*62
  float* z1    = yacc + 984064;            // 984064
  float* z2    = z1 + 984064;              // 984064
  float* stats = z2 + 984064;              // 256
  float* par   = stats + 256;              // 256
  float* wT    = par + 256;                // 131072 (dedicated)
  float* wdT   = wT + 131072;              // 131072 (dedicated)

  // disjoint-lifetime aliases:
  float*  rowstat = z1;                    // 4*16*961 floats (post-combine)
  float*  coarse  = z1 + 61504;            // 4*16*961 floats
  float4* o2      = (float4*)z2;           // 4*16*960 float4
  int*    coordg  = (int*)(z2 + 245760);   // 61440 ints

  k_wtr<<<1024, 256, 0, stream>>>(w_up, w_down, wT, wdT, stats);
  k_down<<<1024, 256, 0, stream>>>(x, wdT,
                                   o1, yacc, yacc + 492032, z1, z1 + 492032,
                                   z2, z2 + 492032, xd);
  k_combine<<<(XDSZ + 255) / 256, 256, 0, stream>>>(o1, yacc, yacc + 492032, z1,
                                                    z1 + 492032, z2, z2 + 492032,
                                                    b_down, xd);
  k_attn1<<<1024, 256, 0, stream>>>(xd, w_qkv_c, b_qkv_c, o1, rowstat);
  k_coarse<<<1024, 256, 0, stream>>>(xd, w_qkv_c, b_qkv_c, rowstat, coarse);
  k_topk<<<64, 256, 0, stream>>>(coarse, topk);
  k_upconv<<<1024, 256, 0, stream>>>(o1, wT, b_up, yacc);
  k_attn2<<<512, 256, 0, stream>>>(yacc, w_qkv_t, b_qkv_t, topk, o2, coordg);
  k_scatter<<<(64 * N2 + 255) / 256, 256, 0, stream>>>(yacc, o2, coordg);
  k_dwconv<<<1024, 256, 0, stream>>>(yacc, w_dw, z1, stats);
  k_bnparam<<<1, 64, 0, stream>>>(stats, g_dw, be_dw, par);
  k_pwconv<<<61 * 16, 256, 0, stream>>>(z1, w_pw, par, z2, stats + 128);
  k_bnparam<<<1, 64, 0, stream>>>(stats + 128, g_pw, be_pw, par + 128);
  k_final<<<(64 * NPIX + 255) / 256, 256, 0, stream>>>(z2, par + 128, out);
}

// Round 5
// 298.451 us; speedup vs baseline: 1.0607x; 1.0018x over previous
//
#include <hip/hip_runtime.h>
#include <math.h>

#define N1 961
#define N2 960
#define KF 240
#define HW2 3844   // 62*62
#define NPIX 15376 // 4*62*62
#define XDSZ 492032 // 4*128*961
#define L2E 1.44269504f

typedef float v2f __attribute__((ext_vector_type(2)));

// down conv: 2x2 px x 4 co per thread, K-split x8 (1024 blocks = 4/CU).
// Weights via SCALAR path from pre-transposed wdT.
__global__ __launch_bounds__(256) void k_down(const float* __restrict__ x,
                                              const float* __restrict__ wdT,
                                              float* __restrict__ p0, float* __restrict__ p1,
                                              float* __restrict__ p2, float* __restrict__ p3,
                                              float* __restrict__ p4, float* __restrict__ p5,
                                              float* __restrict__ p6, float* __restrict__ p7) {
  __shared__ float iS[4][18][72];
  int tid = threadIdx.x;
  int bid = blockIdx.x;
  int kchunk = bid & 7;
  int rowtile = (bid >> 3) & 3;
  int cog = (bid >> 5) & 7;
  int b = bid >> 8;
  int r0 = rowtile * 8;
  int wv = tid >> 6, lane = tid & 63;
  int pc = lane & 15, pr = lane >> 4;
  int qd = __builtin_amdgcn_readfirstlane(cog * 4 + wv);
  const float4* wqd = (const float4*)wdT + (size_t)qd * 1024;  // 64 ci x 16 taps
  float acc[4][4];  // [px][co]
  #pragma unroll
  for (int i = 0; i < 4; i++)
    #pragma unroll
    for (int j = 0; j < 4; j++) acc[i][j] = 0.f;
  const float* xb = x + (size_t)b * 64 * 4096;
  for (int sub = 0; sub < 2; sub++) {
    int cibase = kchunk * 8 + sub * 4;
    __syncthreads();
    for (int e = tid; e < 4 * 18 * 66; e += 256) {
      int dx = e % 66; int t = e / 66;
      int dy = t % 18; int ci = t / 18;
      int iy = 2 * r0 + dy;
      iS[ci][dy][dx] = (dx < 64 && iy < 64)
                           ? xb[(size_t)(cibase + ci) * 4096 + iy * 64 + dx] : 0.f;
    }
    __syncthreads();
    #pragma unroll
    for (int ci = 0; ci < 4; ci++) {
      const float4* wc = wqd + (size_t)(cibase + ci) * 16;  // uniform -> s_load
      float xr[6][6];
      #pragma unroll
      for (int rr = 0; rr < 6; rr++)
        #pragma unroll
        for (int jj = 0; jj < 3; jj++) {
          float2 v2 = *(const float2*)&iS[ci][4 * pr + rr][4 * pc + 2 * jj];
          xr[rr][2 * jj] = v2.x; xr[rr][2 * jj + 1] = v2.y;
        }
      #pragma unroll
      for (int ky = 0; ky < 4; ky++)
        #pragma unroll
        for (int kx = 0; kx < 4; kx++) {
          float4 wq = wc[ky * 4 + kx];  // SGPR
          #pragma unroll
          for (int dy2 = 0; dy2 < 2; dy2++)
            #pragma unroll
            for (int dx2 = 0; dx2 < 2; dx2++) {
              float xv = xr[2 * dy2 + ky][2 * dx2 + kx];
              int px = dy2 * 2 + dx2;
              acc[px][0] += wq.x * xv; acc[px][1] += wq.y * xv;
              acc[px][2] += wq.z * xv; acc[px][3] += wq.w * xv;
            }
        }
    }
  }
  float* parts[8] = {p0, p1, p2, p3, p4, p5, p6, p7};
  float* xo = parts[kchunk] + (size_t)b * 128 * N1;
  #pragma unroll
  for (int dy2 = 0; dy2 < 2; dy2++) {
    int r = r0 + 2 * pr + dy2;
    if (r >= 31) continue;
    #pragma unroll
    for (int dx2 = 0; dx2 < 2; dx2++) {
      int c = 2 * pc + dx2;
      if (c >= 31) continue;
      #pragma unroll
      for (int cc = 0; cc < 4; cc++)
        xo[(size_t)(cog * 16 + wv * 4 + cc) * N1 + r * 31 + c] = acc[dy2 * 2 + dx2][cc];
    }
  }
}

// combine 7 K-partials + xd(8th partial) + bias -> xd
__global__ __launch_bounds__(256) void k_combine(const float* __restrict__ p0,
                                                 const float* __restrict__ p1,
                                                 const float* __restrict__ p2,
                                                 const float* __restrict__ p3,
                                                 const float* __restrict__ p4,
                                                 const float* __restrict__ p5,
                                                 const float* __restrict__ p6,
                                                 const float* __restrict__ bias,
                                                 float* __restrict__ xd) {
  int i = blockIdx.x * 256 + threadIdx.x;
  if (i >= XDSZ) return;
  int co = (i / N1) & 127;
  float s = ((p0[i] + p1[i]) + (p2[i] + p3[i])) + ((p4[i] + p5[i]) + (p6[i] + xd[i]));
  xd[i] = bias[co] + s;
}

// weight pre-transposes (upconv wT + downconv wdT) + stats zeroing.
__global__ __launch_bounds__(256) void k_wtr(const float* __restrict__ wup,
                                             const float* __restrict__ wdn,
                                             float* __restrict__ wT,
                                             float* __restrict__ wdT,
                                             float* __restrict__ stats) {
  int tid = threadIdx.x;
  int bid = blockIdx.x;
  if (bid == 0) stats[tid] = 0.f;
  if (bid < 512) {
    int idx = bid * 256 + tid;
    int c = idx & 3;
    int t = (idx >> 2) & 3;
    int cw = (idx >> 4) & 15;
    int ci = (idx >> 8) & 127;
    int par = idx >> 15;
    int py = par >> 1, px = par & 1;
    int a = t >> 1, d = t & 1;
    int tap = (3 - (py + 2 * a)) * 4 + (3 - (px + 2 * d));
    int co = cw * 4 + c;
    wT[idx] = wup[(size_t)ci * 1024 + co * 16 + tap];
  } else {
    int idx = (bid - 512) * 256 + tid;
    int c = idx & 3;
    int tap = (idx >> 2) & 15;
    int ci = (idx >> 6) & 63;
    int q = idx >> 12;  // 0..31
    wdT[idx] = wdn[(size_t)(q * 4 + c) * 1024 + ci * 16 + tap];
  }
}

// QKV projection with weights via SCALAR path (uniform s_load -> SGPR operand).
#define QKV_G(off) make_float4( \
    t0 * wqkv[(off)] + t1 * wqkv[12 + (off)] + t2 * wqkv[24 + (off)] + t3 * wqkv[36 + (off)] + bqkv[(off)], \
    t0 * wqkv[(off)+1] + t1 * wqkv[12 + (off)+1] + t2 * wqkv[24 + (off)+1] + t3 * wqkv[36 + (off)+1] + bqkv[(off)+1], \
    t0 * wqkv[(off)+2] + t1 * wqkv[12 + (off)+2] + t2 * wqkv[24 + (off)+2] + t3 * wqkv[36 + (off)+2] + bqkv[(off)+2], \
    t0 * wqkv[(off)+3] + t1 * wqkv[12 + (off)+3] + t2 * wqkv[24 + (off)+3] + t3 * wqkv[36 + (off)+3] + bqkv[(off)+3])

__device__ __forceinline__ void red2(v2f& a, int off) {
  a.x += __shfl_xor(a.x, off, 64);
  a.y += __shfl_xor(a.y, off, 64);
}

// attention 1 v4: 8 rows/thread (4x v2f pairs), strided 8-way m-split.
// grid = 128 bg x 4 chunks (256 rows/block). Halves LDS b128 traffic vs R=4.
__global__ __launch_bounds__(256) void k_attn1(const float* __restrict__ xd,
                                               const float* __restrict__ wqkv,
                                               const float* __restrict__ bqkv,
                                               float* __restrict__ o1,
                                               float* __restrict__ rowstat) {
  __shared__ float4 qvv[2 * N1];
  int tid = threadIdx.x;
  int chunk = blockIdx.x & 3;
  int bg = blockIdx.x >> 2;
  int b = bg >> 5, g = bg & 31;
  const float* xp0 = xd + (size_t)(b * 128 + g * 4) * N1;
  for (int nn = tid; nn < N1; nn += 256) {
    float t0 = xp0[nn], t1 = xp0[N1 + nn], t2 = xp0[2 * N1 + nn], t3 = xp0[3 * N1 + nn];
    qvv[2 * nn]     = QKV_G(0);
    qvv[2 * nn + 1] = QKV_G(8);
  }
  __syncthreads();
  int wv = tid >> 6, lane = tid & 63;
  int oc = lane >> 3;
  int n0 = chunk * 256 + wv * 64 + (lane & 7);
  if (n0 >= N1) return;  // reduce-partners share n0 -> exit together
  int nr[8]; bool vld[8];
  float4 kr[8];
  #pragma unroll
  for (int i2 = 0; i2 < 8; i2++) {
    int n = n0 + 8 * i2; nr[i2] = n; vld[i2] = n < N1;
    int nc = vld[i2] ? n : n0;
    float t0 = xp0[nc], t1 = xp0[N1 + nc], t2 = xp0[2 * N1 + nc], t3 = xp0[3 * N1 + nc];
    float4 kk = QKV_G(4);
    kr[i2] = make_float4(kk.x * L2E, kk.y * L2E, kk.z * L2E, kk.w * L2E);
  }
  v2f kx[4], ky[4], kz[4], kw[4];
  #pragma unroll
  for (int p = 0; p < 4; p++) {
    kx[p] = (v2f){kr[2*p].x, kr[2*p+1].x};
    ky[p] = (v2f){kr[2*p].y, kr[2*p+1].y};
    kz[p] = (v2f){kr[2*p].z, kr[2*p+1].z};
    kw[p] = (v2f){kr[2*p].w, kr[2*p+1].w};
  }
  v2f sum[4], A0[4], A1[4], A2[4], A3[4];
  #pragma unroll
  for (int p = 0; p < 4; p++) {
    sum[p] = (v2f){0.f, 0.f};
    A0[p] = (v2f){0.f, 0.f}; A1[p] = (v2f){0.f, 0.f};
    A2[p] = (v2f){0.f, 0.f}; A3[p] = (v2f){0.f, 0.f};
  }
  #pragma unroll 2
  for (int m = oc; m < N1; m += 8) {
    float4 q = qvv[2 * m];
    float4 v = qvv[2 * m + 1];
    #pragma unroll
    for (int p = 0; p < 4; p++) {
      v2f s = kx[p] * q.x + ky[p] * q.y + kz[p] * q.z + kw[p] * q.w;
      v2f e;
      e.x = __builtin_amdgcn_exp2f(s.x);
      e.y = __builtin_amdgcn_exp2f(s.y);
      sum[p] += e;
      A0[p] += e * v.x; A1[p] += e * v.y; A2[p] += e * v.z; A3[p] += e * v.w;
    }
  }
  #pragma unroll
  for (int off = 8; off <= 32; off <<= 1) {
    #pragma unroll
    for (int p = 0; p < 4; p++) {
      red2(sum[p], off);
      red2(A0[p], off); red2(A1[p], off); red2(A2[p], off); red2(A3[p], off);
    }
  }
  if (oc != 0) return;
  float* o1p = o1 + (size_t)(b * 128 + g * 4) * N1;
  #pragma unroll
  for (int i2 = 0; i2 < 8; i2++) {
    if (!vld[i2]) continue;
    int p = i2 >> 1;
    int n = nr[i2];
    float sv = (i2 & 1) ? sum[p].y : sum[p].x;
    float inv = 1.0f / sv;
    float a0 = (i2 & 1) ? A0[p].y : A0[p].x;
    float a1 = (i2 & 1) ? A1[p].y : A1[p].x;
    float a2 = (i2 & 1) ? A2[p].y : A2[p].x;
    float a3 = (i2 & 1) ? A3[p].y : A3[p].x;
    o1p[n] = a0 * inv;
    o1p[N1 + n] = a1 * inv;
    o1p[2 * N1 + n] = a2 * inv;
    o1p[3 * N1 + n] = a3 * inv;
    if (g < 16) rowstat[(size_t)(b * 16 + g) * N1 + n] = inv;
  }
}

// coarse v4: 8 cols/thread, strided 16-way n-split. grid = 64 bg x 8 chunks.
__global__ __launch_bounds__(256) void k_coarse(const float* __restrict__ xd,
                                                const float* __restrict__ wqkv,
                                                const float* __restrict__ bqkv,
                                                const float* __restrict__ rowstat,
                                                float* __restrict__ coarse) {
  __shared__ float4 kS[N1];
  __shared__ float rs[N1];
  int tid = threadIdx.x;
  int chunk = blockIdx.x & 7;
  int bg = blockIdx.x >> 3;
  int b = bg >> 4, g = bg & 15;
  const float* xp0 = xd + (size_t)(b * 128 + g * 4) * N1;
  const float* rp = rowstat + (size_t)(b * 16 + g) * N1;
  for (int nn = tid; nn < N1; nn += 256) {
    float t0 = xp0[nn], t1 = xp0[N1 + nn], t2 = xp0[2 * N1 + nn], t3 = xp0[3 * N1 + nn];
    kS[nn] = QKV_G(4);
    rs[nn] = rp[nn];
  }
  __syncthreads();
  int wv = tid >> 6, lane = tid & 63;
  int oc = lane >> 2;
  int c0 = chunk * 128 + wv * 32 + (lane & 3);
  if (c0 >= N1) return;  // reduce-partners share c0 -> exit together
  int cr[8]; bool vld[8];
  float4 qr[8];
  #pragma unroll
  for (int i2 = 0; i2 < 8; i2++) {
    int c = c0 + 4 * i2; cr[i2] = c; vld[i2] = c < N1;
    int cc = vld[i2] ? c : c0;
    float t0 = xp0[cc], t1 = xp0[N1 + cc], t2 = xp0[2 * N1 + cc], t3 = xp0[3 * N1 + cc];
    float4 qq = QKV_G(0);
    qr[i2] = make_float4(qq.x * L2E, qq.y * L2E, qq.z * L2E, qq.w * L2E);
  }
  v2f qx[4], qy[4], qz[4], qw[4];
  #pragma unroll
  for (int p = 0; p < 4; p++) {
    qx[p] = (v2f){qr[2*p].x, qr[2*p+1].x};
    qy[p] = (v2f){qr[2*p].y, qr[2*p+1].y};
    qz[p] = (v2f){qr[2*p].z, qr[2*p+1].z};
    qw[p] = (v2f){qr[2*p].w, qr[2*p+1].w};
  }
  v2f cs[4];
  #pragma unroll
  for (int p = 0; p < 4; p++) cs[p] = (v2f){0.f, 0.f};
  #pragma unroll 2
  for (int n = oc; n < N1; n += 16) {
    float4 k = kS[n];
    float r = rs[n];
    #pragma unroll
    for (int p = 0; p < 4; p++) {
      v2f s = qx[p] * k.x + qy[p] * k.y + qz[p] * k.z + qw[p] * k.w;
      v2f e;
      e.x = __builtin_amdgcn_exp2f(s.x);
      e.y = __builtin_amdgcn_exp2f(s.y);
      cs[p] += e * r;
    }
  }
  #pragma unroll
  for (int off = 4; off <= 32; off <<= 1) {
    #pragma unroll
    for (int p = 0; p < 4; p++) red2(cs[p], off);
  }
  if (oc != 0) return;
  float* cp = coarse + (size_t)(b * 16 + g) * N1;
  #pragma unroll
  for (int i2 = 0; i2 < 8; i2++) {
    if (!vld[i2]) continue;
    int p = i2 >> 1;
    cp[cr[i2]] = (i2 & 1) ? cs[p].y : cs[p].x;
  }
}

// top-240 per (b,g<16): bitonic over 1024 packed keys
__global__ __launch_bounds__(256) void k_topk(const float* __restrict__ coarse,
                                              int* __restrict__ topk) {
  __shared__ unsigned long long keys[1024];
  int tid = threadIdx.x;
  int bg = blockIdx.x;
  const float* cp = coarse + (size_t)bg * N1;
  for (int i = tid; i < 1024; i += 256) {
    unsigned long long key = 0ull;
    if (i < N1) {
      unsigned fb = __float_as_uint(cp[i]);
      key = ((unsigned long long)fb << 32) | (unsigned)(N1 - 1 - i);
    }
    keys[i] = key;
  }
  __syncthreads();
  for (int k2 = 2; k2 <= 1024; k2 <<= 1) {
    for (int j = k2 >> 1; j > 0; j >>= 1) {
      for (int i = tid; i < 1024; i += 256) {
        int ixj = i ^ j;
        if (ixj > i) {
          unsigned long long a = keys[i], bb = keys[ixj];
          bool up = ((i & k2) == 0);
          if ((a > bb) == up) { keys[i] = bb; keys[ixj] = a; }
        }
      }
      __syncthreads();
    }
  }
  if (tid < KF) {
    unsigned long long key = keys[1023 - tid];
    topk[(size_t)bg * KF + tid] = (N1 - 1) - (int)(unsigned)(key & 0xffffffffull);
  }
}

// transposed conv, per-parity: o1(4,128,31,31) -> yacc = 2*coarse_out (4,64,62,62)
__global__ __launch_bounds__(256) void k_upconv(const float* __restrict__ o1,
                                                const float* __restrict__ wT,
                                                const float* __restrict__ bias,
                                                float* __restrict__ yacc) {
  __shared__ float iS[16][9][12];
  int tid = threadIdx.x;
  int bid = blockIdx.x;
  int b = bid >> 8;
  int cog = (bid >> 6) & 3;
  int par = (bid >> 4) & 3;
  int py = par >> 1, px = par & 1;
  int tile = bid & 15;
  int r0 = (tile >> 2) * 8, c0 = (tile & 3) * 8;
  int wv = tid >> 6, lane = tid & 63;
  int pr = lane >> 3, pc = lane & 7;
  int cwu = __builtin_amdgcn_readfirstlane(cog * 4 + wv);  // co-quad 0..15, wave-uniform
  const float4* wq = (const float4*)wT + ((size_t)par * 2048 + cwu) * 4;
  int cobase = cog * 16 + wv * 4;
  float acc[4] = {0.f, 0.f, 0.f, 0.f};
  const float* ob = o1 + (size_t)b * 128 * N1;
  for (int ch = 0; ch < 8; ch++) {
    __syncthreads();
    for (int e = tid; e < 16 * 81; e += 256) {
      int dx = e % 9; int t = e / 9;
      int dy = t % 9; int ci = t / 9;
      int iy = r0 + py - 1 + dy, ix = c0 + px - 1 + dx;
      float v = 0.f;
      if (iy >= 0 && iy < 31 && ix >= 0 && ix < 31)
        v = ob[(size_t)(ch * 16 + ci) * N1 + iy * 31 + ix];
      iS[ci][dy][dx] = v;
    }
    __syncthreads();
    #pragma unroll
    for (int ci = 0; ci < 16; ci++) {
      int cig = ch * 16 + ci;
      float4 w0 = wq[(size_t)cig * 64 + 0];
      float4 w1 = wq[(size_t)cig * 64 + 1];
      float4 w2 = wq[(size_t)cig * 64 + 2];
      float4 w3 = wq[(size_t)cig * 64 + 3];
      float x00 = iS[ci][pr][pc],     x01 = iS[ci][pr][pc + 1];
      float x10 = iS[ci][pr + 1][pc], x11 = iS[ci][pr + 1][pc + 1];
      acc[0] += w0.x * x00; acc[1] += w0.y * x00; acc[2] += w0.z * x00; acc[3] += w0.w * x00;
      acc[0] += w1.x * x01; acc[1] += w1.y * x01; acc[2] += w1.z * x01; acc[3] += w1.w * x01;
      acc[0] += w2.x * x10; acc[1] += w2.y * x10; acc[2] += w2.z * x10; acc[3] += w2.w * x10;
      acc[0] += w3.x * x11; acc[1] += w3.y * x11; acc[2] += w3.z * x11; acc[3] += w3.w * x11;
    }
  }
  int r = r0 + pr, c = c0 + pc;
  if (r >= 31 || c >= 31) return;
  int y = 2 * r + py, xx = 2 * c + px;
  #pragma unroll
  for (int cc = 0; cc < 4; cc++) {
    int co = cobase + cc;
    yacc[(size_t)(b * 64 + co) * HW2 + y * 62 + xx] = 2.0f * (acc[cc] + bias[co]);
  }
}

// attention 2: 4 rows/thread, strided 8-way m-split. grid = 64 bg x 8 chunks.
__global__ __launch_bounds__(256) void k_attn2(const float* __restrict__ yacc,
                                               const float* __restrict__ wqkv,
                                               const float* __restrict__ bqkv,
                                               const int* __restrict__ topk,
                                               float4* __restrict__ o2,
                                               int* __restrict__ coordg) {
  __shared__ float4 qvv[2 * N2];
  int tid = threadIdx.x;
  int chunk = blockIdx.x & 7;
  int bg = blockIdx.x >> 3;
  int b = bg >> 4, g = bg & 15;
  const float* yp0 = yacc + (size_t)(b * 64 + g * 4) * HW2;
  const int* ip = topk + (size_t)bg * KF;
  for (int nn = tid; nn < N2; nn += 256) {
    int tt = nn >> 2, i = (nn >> 1) & 1, j = nn & 1;
    int p = ip[tt];
    int ph = p / 31, pw = p - ph * 31;
    int cc = (2 * ph + i) * 62 + (2 * pw + j);
    float t0 = 0.5f * yp0[cc], t1 = 0.5f * yp0[HW2 + cc];
    float t2 = 0.5f * yp0[2 * HW2 + cc], t3 = 0.5f * yp0[3 * HW2 + cc];
    qvv[2 * nn]     = QKV_G(0);
    qvv[2 * nn + 1] = QKV_G(8);
  }
  __syncthreads();
  int wv = tid >> 6, lane = tid & 63;
  int oc = lane >> 3;
  int n0 = chunk * 128 + wv * 32 + (lane & 7);
  if (n0 >= N2) return;
  int nr[4]; int ccr[4]; bool vld[4];
  float4 kr[4];
  #pragma unroll
  for (int i2 = 0; i2 < 4; i2++) {
    int n = n0 + 8 * i2; nr[i2] = n; vld[i2] = n < N2;
    int nc = vld[i2] ? n : n0;
    int tt = nc >> 2, ii = (nc >> 1) & 1, jj = nc & 1;
    int p = ip[tt];
    int ph = p / 31, pw = p - ph * 31;
    int cc = (2 * ph + ii) * 62 + (2 * pw + jj);
    ccr[i2] = cc;
    float t0 = 0.5f * yp0[cc], t1 = 0.5f * yp0[HW2 + cc];
    float t2 = 0.5f * yp0[2 * HW2 + cc], t3 = 0.5f * yp0[3 * HW2 + cc];
    float4 kk = QKV_G(4);
    kr[i2] = make_float4(kk.x * L2E, kk.y * L2E, kk.z * L2E, kk.w * L2E);
  }
  v2f kax = {kr[0].x, kr[1].x}, kay = {kr[0].y, kr[1].y};
  v2f kaz = {kr[0].z, kr[1].z}, kaw = {kr[0].w, kr[1].w};
  v2f kbx = {kr[2].x, kr[3].x}, kby = {kr[2].y, kr[3].y};
  v2f kbz = {kr[2].z, kr[3].z}, kbw = {kr[2].w, kr[3].w};
  v2f suma = {0.f, 0.f}, sumb = {0.f, 0.f};
  v2f Aa0 = {0.f, 0.f}, Aa1 = {0.f, 0.f}, Aa2 = {0.f, 0.f}, Aa3 = {0.f, 0.f};
  v2f Ab0 = {0.f, 0.f}, Ab1 = {0.f, 0.f}, Ab2 = {0.f, 0.f}, Ab3 = {0.f, 0.f};
  #pragma unroll 4
  for (int m = oc; m < N2; m += 8) {
    float4 q = qvv[2 * m];
    float4 v = qvv[2 * m + 1];
    v2f sa = kax * q.x + kay * q.y + kaz * q.z + kaw * q.w;
    v2f sb = kbx * q.x + kby * q.y + kbz * q.z + kbw * q.w;
    v2f ea, eb;
    ea.x = __builtin_amdgcn_exp2f(sa.x); ea.y = __builtin_amdgcn_exp2f(sa.y);
    eb.x = __builtin_amdgcn_exp2f(sb.x); eb.y = __builtin_amdgcn_exp2f(sb.y);
    suma += ea; sumb += eb;
    Aa0 += ea * v.x; Aa1 += ea * v.y; Aa2 += ea * v.z; Aa3 += ea * v.w;
    Ab0 += eb * v.x; Ab1 += eb * v.y; Ab2 += eb * v.z; Ab3 += eb * v.w;
  }
  #pragma unroll
  for (int off = 8; off <= 32; off <<= 1) {
    red2(suma, off); red2(sumb, off);
    red2(Aa0, off); red2(Aa1, off); red2(Aa2, off); red2(Aa3, off);
    red2(Ab0, off); red2(Ab1, off); red2(Ab2, off); red2(Ab3, off);
  }
  if (oc != 0) return;
  float sums[4] = {suma.x, suma.y, sumb.x, sumb.y};
  float a0[4] = {Aa0.x, Aa0.y, Ab0.x, Ab0.y};
  float a1[4] = {Aa1.x, Aa1.y, Ab1.x, Ab1.y};
  float a2[4] = {Aa2.x, Aa2.y, Ab2.x, Ab2.y};
  float a3[4] = {Aa3.x, Aa3.y, Ab3.x, Ab3.y};
  #pragma unroll
  for (int i2 = 0; i2 < 4; i2++) {
    if (!vld[i2]) continue;
    float inv = 1.0f / sums[i2];
    size_t oi = (size_t)bg * N2 + nr[i2];
    o2[oi] = make_float4(a0[i2] * inv, a1[i2] * inv, a2[i2] * inv, a3[i2] * inv);
    coordg[oi] = ccr[i2];
  }
}

// scatter-add attn2 output into yacc (disjoint targets)
__global__ __launch_bounds__(256) void k_scatter(float* __restrict__ yacc,
                                                 const float4* __restrict__ o2,
                                                 const int* __restrict__ coordg) {
  int idx = blockIdx.x * 256 + threadIdx.x;
  if (idx >= 64 * N2) return;
  int bg = idx / N2;
  int b = bg >> 4, g = bg & 15;
  float4 o = o2[idx];
  int cc = coordg[idx];
  float* yp0 = yacc + (size_t)(b * 64 + g * 4) * HW2;
  yp0[cc] += o.x;
  yp0[HW2 + cc] += o.y;
  yp0[2 * HW2 + cc] += o.z;
  yp0[3 * HW2 + cc] += o.w;
}

__device__ __forceinline__ float wave_sum(float x) {
  #pragma unroll
  for (int off = 32; off > 0; off >>= 1) x += __shfl_xor(x, off, 64);
  return x;
}

// depthwise 3x3 + fused per-channel stats. grid = plane(256) x seg(4).
__global__ __launch_bounds__(256) void k_dwconv(const float* __restrict__ yin,
                                                const float* __restrict__ w,
                                                float* __restrict__ z1,
                                                float* __restrict__ stats) {
  __shared__ float red[8];
  int tid = threadIdx.x;
  int bid = blockIdx.x;
  int plane = bid >> 2, seg = bid & 3;  // plane = b*64 + c
  int c = plane & 63;
  const float* yp = yin + (size_t)plane * HW2;
  const float* wp = w + c * 9;  // uniform -> s_load
  float s = 0.f, s2 = 0.f;
  int i0 = seg * 961;
  for (int i = i0 + tid; i < i0 + 961; i += 256) {
    int y = i / 62, x = i - (i / 62) * 62;
    float acc = 0.f;
    #pragma unroll
    for (int ky = 0; ky < 3; ky++) {
      int yy = y + ky - 1;
      if (yy < 0 || yy > 61) continue;
      #pragma unroll
      for (int kx = 0; kx < 3; kx++) {
        int xx = x + kx - 1;
        if (xx < 0 || xx > 61) continue;
        acc += yp[yy * 62 + xx] * wp[ky * 3 + kx];
      }
    }
    z1[(size_t)plane * HW2 + i] = acc;
    s += acc; s2 += acc * acc;
  }
  s = wave_sum(s); s2 = wave_sum(s2);
  int wave = tid >> 6, lane = tid & 63;
  if (lane == 0) { red[wave] = s; red[4 + wave] = s2; }
  __syncthreads();
  if (tid == 0) {
    atomicAdd(&stats[c], red[0] + red[1] + red[2] + red[3]);
    atomicAdd(&stats[64 + c], red[4] + red[5] + red[6] + red[7]);
  }
}

// pointwise 1x1 + fused BN-param compute (from stats) + fused z2 stats.
// co-split x16 (4 co/block): grid = 61 x 16
__global__ __launch_bounds__(256) void k_pwconv(const float* __restrict__ z1,
                                                const float* __restrict__ wpw,
                                                const float* __restrict__ stats,
                                                const float* __restrict__ gdw,
                                                const float* __restrict__ bedw,
                                                float* __restrict__ z2,
                                                float* __restrict__ stats2) {
  __shared__ float w[4 * 64];
  __shared__ float aa[64], cb[64];
  __shared__ float redS[4][4], redQ[4][4];
  int tid = threadIdx.x;
  int cog = blockIdx.x & 15;
  int pb = blockIdx.x >> 4;
  if (tid < 64) {
    float m = stats[tid] * (1.0f / NPIX);
    float v = stats[64 + tid] * (1.0f / NPIX) - m * m;
    float a = gdw[tid] * rsqrtf(v + 1e-5f);
    aa[tid] = a; cb[tid] = bedw[tid] - m * a;
  }
  for (int i = tid; i < 256; i += 256) w[i] = wpw[cog * 256 + i];
  __syncthreads();
  int pix = pb * 256 + tid;
  bool valid = pix < NPIX;
  int pixc = valid ? pix : NPIX - 1;
  int b = pixc / HW2, p = pixc - b * HW2;
  float h[64];
  #pragma unroll
  for (int ci = 0; ci < 64; ci++) {
    float z = z1[(size_t)(b * 64 + ci) * HW2 + p];
    z = aa[ci] * z + cb[ci];
    h[ci] = fminf(fmaxf(z, 0.f), 6.f);
  }
  float ssum[4], ssq[4];
  #pragma unroll
  for (int cc = 0; cc < 4; cc++) {
    float acc = 0.f;
    #pragma unroll
    for (int ci = 0; ci < 64; ci++) acc += h[ci] * w[cc * 64 + ci];
    if (valid) z2[(size_t)(b * 64 + cog * 4 + cc) * HW2 + p] = acc;
    ssum[cc] = valid ? acc : 0.f;
    ssq[cc] = valid ? acc * acc : 0.f;
  }
  int wv = tid >> 6, lane = tid & 63;
  #pragma unroll
  for (int cc = 0; cc < 4; cc++) {
    ssum[cc] = wave_sum(ssum[cc]);
    ssq[cc] = wave_sum(ssq[cc]);
  }
  if (lane == 0) {
    #pragma unroll
    for (int cc = 0; cc < 4; cc++) { redS[wv][cc] = ssum[cc]; redQ[wv][cc] = ssq[cc]; }
  }
  __syncthreads();
  if (tid < 4) {
    float ts = redS[0][tid] + redS[1][tid] + redS[2][tid] + redS[3][tid];
    float tq = redQ[0][tid] + redQ[1][tid] + redQ[2][tid] + redQ[3][tid];
    atomicAdd(&stats2[cog * 4 + tid], ts);
    atomicAdd(&stats2[64 + cog * 4 + tid], tq);
  }
}

// final BN+relu6, BN params computed inline from stats2
__global__ __launch_bounds__(256) void k_final(const float* __restrict__ z2,
                                               const float* __restrict__ stats2,
                                               const float* __restrict__ gpw,
                                               const float* __restrict__ bepw,
                                               float* __restrict__ out) {
  int idx = blockIdx.x * 256 + threadIdx.x;
  if (idx >= 64 * NPIX) return;
  int c = (idx / HW2) & 63;
  float m = stats2[c] * (1.0f / NPIX);
  float v = stats2[64 + c] * (1.0f / NPIX) - m * m;
  float a = gpw[c] * rsqrtf(v + 1e-5f);
  float z = a * z2[idx] + (bepw[c] - m * a);
  out[idx] = fminf(fmaxf(z, 0.f), 6.f);
}

extern "C" void kernel_launch(void* const* d_in, const int* in_sizes, int n_in,
                              void* d_out, int out_size, void* d_ws, size_t ws_size,
                              hipStream_t stream) {
  const float* x       = (const float*)d_in[0];
  const float* w_down  = (const float*)d_in[1];
  const float* b_down  = (const float*)d_in[2];
  const float* w_qkv_c = (const float*)d_in[3];
  const float* b_qkv_c = (const float*)d_in[4];
  const float* w_up    = (const float*)d_in[5];
  const float* b_up    = (const float*)d_in[6];
  const float* w_qkv_t = (const float*)d_in[7];
  const float* b_qkv_t = (const float*)d_in[8];
  const float* w_dw    = (const float*)d_in[9];
  const float* g_dw    = (const float*)d_in[10];
  const float* be_dw   = (const float*)d_in[11];
  const float* w_pw    = (const float*)d_in[12];
  const float* g_pw    = (const float*)d_in[13];
  const float* be_pw   = (const float*)d_in[14];
  float* out = (float*)d_out;

  float* ws    = (float*)d_ws;
  float* xd    = ws;                       // 492032 = 4*128*961
  float* o1    = xd + 492032;              // 492032
  int*   topk  = (int*)(o1 + 492032);      // 15360 = 4*16*240
  float* yacc  = (float*)(topk + 15360);   // 984064 = 4*64*62*62
  float* z1    = yacc + 984064;            // 984064
  float* z2    = z1 + 984064;              // 984064
  float* stats = z2 + 984064;              // 256
  float* wT    = stats + 256;              // 131072 (dedicated)
  float* wdT   = wT + 131072;              // 131072 (dedicated)

  // disjoint-lifetime aliases:
  float*  rowstat = z1;                    // 4*16*961 floats (post-combine)
  float*  coarse  = z1 + 61504;            // 4*16*961 floats
  float4* o2      = (float4*)z2;           // 4*16*960 float4
  int*    coordg  = (int*)(z2 + 245760);   // 61440 ints

  k_wtr<<<1024, 256, 0, stream>>>(w_up, w_down, wT, wdT, stats);
  k_down<<<1024, 256, 0, stream>>>(x, wdT,
                                   o1, yacc, yacc + 492032, z1, z1 + 492032,
                                   z2, z2 + 492032, xd);
  k_combine<<<(XDSZ + 255) / 256, 256, 0, stream>>>(o1, yacc, yacc + 492032, z1,
                                                    z1 + 492032, z2, z2 + 492032,
                                                    b_down, xd);
  k_attn1<<<512, 256, 0, stream>>>(xd, w_qkv_c, b_qkv_c, o1, rowstat);
  k_coarse<<<512, 256, 0, stream>>>(xd, w_qkv_c, b_qkv_c, rowstat, coarse);
  k_topk<<<64, 256, 0, stream>>>(coarse, topk);
  k_upconv<<<1024, 256, 0, stream>>>(o1, wT, b_up, yacc);
  k_attn2<<<512, 256, 0, stream>>>(yacc, w_qkv_t, b_qkv_t, topk, o2, coordg);
  k_scatter<<<(64 * N2 + 255) / 256, 256, 0, stream>>>(yacc, o2, coordg);
  k_dwconv<<<1024, 256, 0, stream>>>(yacc, w_dw, z1, stats);
  k_pwconv<<<61 * 16, 256, 0, stream>>>(z1, w_pw, stats, g_dw, be_dw, z2, stats + 128);
  k_final<<<(64 * NPIX + 255) / 256, 256, 0, stream>>>(z2, stats + 128, g_pw, be_pw, out);
}

// Round 6
// 290.690 us; speedup vs baseline: 1.0890x; 1.0267x over previous
//
#include <hip/hip_runtime.h>
#include <math.h>

#define N1 961
#define N2 960
#define KF 240
#define HW2 3844   // 62*62
#define NPIX 15376 // 4*62*62
#define XDSZ 492032 // 4*128*961
#define L2E 1.44269504f

typedef float v2f __attribute__((ext_vector_type(2)));

// down conv: 2x2 px x 4 co per thread, K-split x4 (512 blocks = 2/CU).
// Weights via SCALAR path from pre-transposed wdT.
__global__ __launch_bounds__(256) void k_down(const float* __restrict__ x,
                                              const float* __restrict__ wdT,
                                              float* __restrict__ p0, float* __restrict__ p1,
                                              float* __restrict__ p2, float* __restrict__ p3) {
  __shared__ float iS[4][18][72];
  int tid = threadIdx.x;
  int bid = blockIdx.x;
  int kchunk = bid & 3;
  int rowtile = (bid >> 2) & 3;
  int cog = (bid >> 4) & 7;
  int b = bid >> 7;
  int r0 = rowtile * 8;
  int wv = tid >> 6, lane = tid & 63;
  int pc = lane & 15, pr = lane >> 4;
  int qd = __builtin_amdgcn_readfirstlane(cog * 4 + wv);
  const float4* wqd = (const float4*)wdT + (size_t)qd * 1024;  // 64 ci x 16 taps
  float acc[4][4];  // [px][co]
  #pragma unroll
  for (int i = 0; i < 4; i++)
    #pragma unroll
    for (int j = 0; j < 4; j++) acc[i][j] = 0.f;
  const float* xb = x + (size_t)b * 64 * 4096;
  for (int sub = 0; sub < 4; sub++) {
    int cibase = kchunk * 16 + sub * 4;
    __syncthreads();
    for (int e = tid; e < 4 * 18 * 66; e += 256) {
      int dx = e % 66; int t = e / 66;
      int dy = t % 18; int ci = t / 18;
      int iy = 2 * r0 + dy;
      iS[ci][dy][dx] = (dx < 64 && iy < 64)
                           ? xb[(size_t)(cibase + ci) * 4096 + iy * 64 + dx] : 0.f;
    }
    __syncthreads();
    #pragma unroll
    for (int ci = 0; ci < 4; ci++) {
      const float4* wc = wqd + (size_t)(cibase + ci) * 16;  // uniform -> s_load
      float xr[6][6];
      #pragma unroll
      for (int rr = 0; rr < 6; rr++)
        #pragma unroll
        for (int jj = 0; jj < 3; jj++) {
          float2 v2 = *(const float2*)&iS[ci][4 * pr + rr][4 * pc + 2 * jj];
          xr[rr][2 * jj] = v2.x; xr[rr][2 * jj + 1] = v2.y;
        }
      #pragma unroll
      for (int ky = 0; ky < 4; ky++)
        #pragma unroll
        for (int kx = 0; kx < 4; kx++) {
          float4 wq = wc[ky * 4 + kx];  // SGPR
          #pragma unroll
          for (int dy2 = 0; dy2 < 2; dy2++)
            #pragma unroll
            for (int dx2 = 0; dx2 < 2; dx2++) {
              float xv = xr[2 * dy2 + ky][2 * dx2 + kx];
              int px = dy2 * 2 + dx2;
              acc[px][0] += wq.x * xv; acc[px][1] += wq.y * xv;
              acc[px][2] += wq.z * xv; acc[px][3] += wq.w * xv;
            }
        }
    }
  }
  float* parts[4] = {p0, p1, p2, p3};
  float* xo = parts[kchunk] + (size_t)b * 128 * N1;
  #pragma unroll
  for (int dy2 = 0; dy2 < 2; dy2++) {
    int r = r0 + 2 * pr + dy2;
    if (r >= 31) continue;
    #pragma unroll
    for (int dx2 = 0; dx2 < 2; dx2++) {
      int c = 2 * pc + dx2;
      if (c >= 31) continue;
      #pragma unroll
      for (int cc = 0; cc < 4; cc++)
        xo[(size_t)(cog * 16 + wv * 4 + cc) * N1 + r * 31 + c] = acc[dy2 * 2 + dx2][cc];
    }
  }
}

// combine 3 K-partials + xd(4th partial) + bias -> xd
__global__ __launch_bounds__(256) void k_combine(const float* __restrict__ p0,
                                                 const float* __restrict__ p1,
                                                 const float* __restrict__ p2,
                                                 const float* __restrict__ bias,
                                                 float* __restrict__ xd) {
  int i = blockIdx.x * 256 + threadIdx.x;
  if (i >= XDSZ) return;
  int co = (i / N1) & 127;
  float s = (p0[i] + p1[i]) + (p2[i] + xd[i]);
  xd[i] = bias[co] + s;
}

// weight pre-transposes (upconv wT + downconv wdT) + stats zeroing.
__global__ __launch_bounds__(256) void k_wtr(const float* __restrict__ wup,
                                             const float* __restrict__ wdn,
                                             float* __restrict__ wT,
                                             float* __restrict__ wdT,
                                             float* __restrict__ stats) {
  int tid = threadIdx.x;
  int bid = blockIdx.x;
  if (bid == 0) stats[tid] = 0.f;
  if (bid < 512) {
    int idx = bid * 256 + tid;
    int c = idx & 3;
    int t = (idx >> 2) & 3;
    int cw = (idx >> 4) & 15;
    int ci = (idx >> 8) & 127;
    int par = idx >> 15;
    int py = par >> 1, px = par & 1;
    int a = t >> 1, d = t & 1;
    int tap = (3 - (py + 2 * a)) * 4 + (3 - (px + 2 * d));
    int co = cw * 4 + c;
    wT[idx] = wup[(size_t)ci * 1024 + co * 16 + tap];
  } else {
    int idx = (bid - 512) * 256 + tid;
    int c = idx & 3;
    int tap = (idx >> 2) & 15;
    int ci = (idx >> 6) & 63;
    int q = idx >> 12;  // 0..31
    wdT[idx] = wdn[(size_t)(q * 4 + c) * 1024 + ci * 16 + tap];
  }
}

// QKV projection with weights via SCALAR path (uniform s_load -> SGPR operand).
#define QKV_G(off) make_float4( \
    t0 * wqkv[(off)] + t1 * wqkv[12 + (off)] + t2 * wqkv[24 + (off)] + t3 * wqkv[36 + (off)] + bqkv[(off)], \
    t0 * wqkv[(off)+1] + t1 * wqkv[12 + (off)+1] + t2 * wqkv[24 + (off)+1] + t3 * wqkv[36 + (off)+1] + bqkv[(off)+1], \
    t0 * wqkv[(off)+2] + t1 * wqkv[12 + (off)+2] + t2 * wqkv[24 + (off)+2] + t3 * wqkv[36 + (off)+2] + bqkv[(off)+2], \
    t0 * wqkv[(off)+3] + t1 * wqkv[12 + (off)+3] + t2 * wqkv[24 + (off)+3] + t3 * wqkv[36 + (off)+3] + bqkv[(off)+3])

__device__ __forceinline__ void red2(v2f& a, int off) {
  a.x += __shfl_xor(a.x, off, 64);
  a.y += __shfl_xor(a.y, off, 64);
}

// attention 1: 8 rows/thread (4x v2f pairs), strided 8-way m-split.
// grid = 128 bg x 4 chunks (256 rows/block).
__global__ __launch_bounds__(256) void k_attn1(const float* __restrict__ xd,
                                               const float* __restrict__ wqkv,
                                               const float* __restrict__ bqkv,
                                               float* __restrict__ o1,
                                               float* __restrict__ rowstat) {
  __shared__ float4 qvv[2 * N1];
  int tid = threadIdx.x;
  int chunk = blockIdx.x & 3;
  int bg = blockIdx.x >> 2;
  int b = bg >> 5, g = bg & 31;
  const float* xp0 = xd + (size_t)(b * 128 + g * 4) * N1;
  for (int nn = tid; nn < N1; nn += 256) {
    float t0 = xp0[nn], t1 = xp0[N1 + nn], t2 = xp0[2 * N1 + nn], t3 = xp0[3 * N1 + nn];
    qvv[2 * nn]     = QKV_G(0);
    qvv[2 * nn + 1] = QKV_G(8);
  }
  __syncthreads();
  int wv = tid >> 6, lane = tid & 63;
  int oc = lane >> 3;
  int n0 = chunk * 256 + wv * 64 + (lane & 7);
  if (n0 >= N1) return;  // reduce-partners share n0 -> exit together
  int nr[8]; bool vld[8];
  float4 kr[8];
  #pragma unroll
  for (int i2 = 0; i2 < 8; i2++) {
    int n = n0 + 8 * i2; nr[i2] = n; vld[i2] = n < N1;
    int nc = vld[i2] ? n : n0;
    float t0 = xp0[nc], t1 = xp0[N1 + nc], t2 = xp0[2 * N1 + nc], t3 = xp0[3 * N1 + nc];
    float4 kk = QKV_G(4);
    kr[i2] = make_float4(kk.x * L2E, kk.y * L2E, kk.z * L2E, kk.w * L2E);
  }
  v2f kx[4], ky[4], kz[4], kw[4];
  #pragma unroll
  for (int p = 0; p < 4; p++) {
    kx[p] = (v2f){kr[2*p].x, kr[2*p+1].x};
    ky[p] = (v2f){kr[2*p].y, kr[2*p+1].y};
    kz[p] = (v2f){kr[2*p].z, kr[2*p+1].z};
    kw[p] = (v2f){kr[2*p].w, kr[2*p+1].w};
  }
  v2f sum[4], A0[4], A1[4], A2[4], A3[4];
  #pragma unroll
  for (int p = 0; p < 4; p++) {
    sum[p] = (v2f){0.f, 0.f};
    A0[p] = (v2f){0.f, 0.f}; A1[p] = (v2f){0.f, 0.f};
    A2[p] = (v2f){0.f, 0.f}; A3[p] = (v2f){0.f, 0.f};
  }
  #pragma unroll 2
  for (int m = oc; m < N1; m += 8) {
    float4 q = qvv[2 * m];
    float4 v = qvv[2 * m + 1];
    #pragma unroll
    for (int p = 0; p < 4; p++) {
      v2f s = kx[p] * q.x + ky[p] * q.y + kz[p] * q.z + kw[p] * q.w;
      v2f e;
      e.x = __builtin_amdgcn_exp2f(s.x);
      e.y = __builtin_amdgcn_exp2f(s.y);
      sum[p] += e;
      A0[p] += e * v.x; A1[p] += e * v.y; A2[p] += e * v.z; A3[p] += e * v.w;
    }
  }
  #pragma unroll
  for (int off = 8; off <= 32; off <<= 1) {
    #pragma unroll
    for (int p = 0; p < 4; p++) {
      red2(sum[p], off);
      red2(A0[p], off); red2(A1[p], off); red2(A2[p], off); red2(A3[p], off);
    }
  }
  if (oc != 0) return;
  float* o1p = o1 + (size_t)(b * 128 + g * 4) * N1;
  #pragma unroll
  for (int i2 = 0; i2 < 8; i2++) {
    if (!vld[i2]) continue;
    int p = i2 >> 1;
    int n = nr[i2];
    float sv = (i2 & 1) ? sum[p].y : sum[p].x;
    float inv = 1.0f / sv;
    float a0 = (i2 & 1) ? A0[p].y : A0[p].x;
    float a1 = (i2 & 1) ? A1[p].y : A1[p].x;
    float a2 = (i2 & 1) ? A2[p].y : A2[p].x;
    float a3 = (i2 & 1) ? A3[p].y : A3[p].x;
    o1p[n] = a0 * inv;
    o1p[N1 + n] = a1 * inv;
    o1p[2 * N1 + n] = a2 * inv;
    o1p[3 * N1 + n] = a3 * inv;
    if (g < 16) rowstat[(size_t)(b * 16 + g) * N1 + n] = inv;
  }
}

// coarse: 8 cols/thread, strided 16-way n-split. grid = 64 bg x 8 chunks.
__global__ __launch_bounds__(256) void k_coarse(const float* __restrict__ xd,
                                                const float* __restrict__ wqkv,
                                                const float* __restrict__ bqkv,
                                                const float* __restrict__ rowstat,
                                                float* __restrict__ coarse) {
  __shared__ float4 kS[N1];
  __shared__ float rs[N1];
  int tid = threadIdx.x;
  int chunk = blockIdx.x & 7;
  int bg = blockIdx.x >> 3;
  int b = bg >> 4, g = bg & 15;
  const float* xp0 = xd + (size_t)(b * 128 + g * 4) * N1;
  const float* rp = rowstat + (size_t)(b * 16 + g) * N1;
  for (int nn = tid; nn < N1; nn += 256) {
    float t0 = xp0[nn], t1 = xp0[N1 + nn], t2 = xp0[2 * N1 + nn], t3 = xp0[3 * N1 + nn];
    kS[nn] = QKV_G(4);
    rs[nn] = rp[nn];
  }
  __syncthreads();
  int wv = tid >> 6, lane = tid & 63;
  int oc = lane >> 2;
  int c0 = chunk * 128 + wv * 32 + (lane & 3);
  if (c0 >= N1) return;  // reduce-partners share c0 -> exit together
  int cr[8]; bool vld[8];
  float4 qr[8];
  #pragma unroll
  for (int i2 = 0; i2 < 8; i2++) {
    int c = c0 + 4 * i2; cr[i2] = c; vld[i2] = c < N1;
    int cc = vld[i2] ? c : c0;
    float t0 = xp0[cc], t1 = xp0[N1 + cc], t2 = xp0[2 * N1 + cc], t3 = xp0[3 * N1 + cc];
    float4 qq = QKV_G(0);
    qr[i2] = make_float4(qq.x * L2E, qq.y * L2E, qq.z * L2E, qq.w * L2E);
  }
  v2f qx[4], qy[4], qz[4], qw[4];
  #pragma unroll
  for (int p = 0; p < 4; p++) {
    qx[p] = (v2f){qr[2*p].x, qr[2*p+1].x};
    qy[p] = (v2f){qr[2*p].y, qr[2*p+1].y};
    qz[p] = (v2f){qr[2*p].z, qr[2*p+1].z};
    qw[p] = (v2f){qr[2*p].w, qr[2*p+1].w};
  }
  v2f cs[4];
  #pragma unroll
  for (int p = 0; p < 4; p++) cs[p] = (v2f){0.f, 0.f};
  #pragma unroll 2
  for (int n = oc; n < N1; n += 16) {
    float4 k = kS[n];
    float r = rs[n];
    #pragma unroll
    for (int p = 0; p < 4; p++) {
      v2f s = qx[p] * k.x + qy[p] * k.y + qz[p] * k.z + qw[p] * k.w;
      v2f e;
      e.x = __builtin_amdgcn_exp2f(s.x);
      e.y = __builtin_amdgcn_exp2f(s.y);
      cs[p] += e * r;
    }
  }
  #pragma unroll
  for (int off = 4; off <= 32; off <<= 1) {
    #pragma unroll
    for (int p = 0; p < 4; p++) red2(cs[p], off);
  }
  if (oc != 0) return;
  float* cp = coarse + (size_t)(b * 16 + g) * N1;
  #pragma unroll
  for (int i2 = 0; i2 < 8; i2++) {
    if (!vld[i2]) continue;
    int p = i2 >> 1;
    cp[cr[i2]] = (i2 & 1) ? cs[p].y : cs[p].x;
  }
}

// top-240 per (b,g<16): bitonic over 1024 packed keys, 1024 threads (1 elem/thread)
__global__ __launch_bounds__(1024) void k_topk(const float* __restrict__ coarse,
                                               int* __restrict__ topk) {
  __shared__ unsigned long long keys[1024];
  int tid = threadIdx.x;
  int bg = blockIdx.x;
  const float* cp = coarse + (size_t)bg * N1;
  {
    unsigned long long key = 0ull;
    if (tid < N1) {
      unsigned fb = __float_as_uint(cp[tid]);
      key = ((unsigned long long)fb << 32) | (unsigned)(N1 - 1 - tid);
    }
    keys[tid] = key;
  }
  __syncthreads();
  for (int k2 = 2; k2 <= 1024; k2 <<= 1) {
    for (int j = k2 >> 1; j > 0; j >>= 1) {
      int i = tid;
      int ixj = i ^ j;
      if (ixj > i) {
        unsigned long long a = keys[i], bb = keys[ixj];
        bool up = ((i & k2) == 0);
        if ((a > bb) == up) { keys[i] = bb; keys[ixj] = a; }
      }
      __syncthreads();
    }
  }
  if (tid < KF) {
    unsigned long long key = keys[1023 - tid];
    topk[(size_t)bg * KF + tid] = (N1 - 1) - (int)(unsigned)(key & 0xffffffffull);
  }
}

// transposed conv, per-parity: o1(4,128,31,31) -> yacc = 2*coarse_out (4,64,62,62)
__global__ __launch_bounds__(256) void k_upconv(const float* __restrict__ o1,
                                                const float* __restrict__ wT,
                                                const float* __restrict__ bias,
                                                float* __restrict__ yacc) {
  __shared__ float iS[16][9][12];
  int tid = threadIdx.x;
  int bid = blockIdx.x;
  int b = bid >> 8;
  int cog = (bid >> 6) & 3;
  int par = (bid >> 4) & 3;
  int py = par >> 1, px = par & 1;
  int tile = bid & 15;
  int r0 = (tile >> 2) * 8, c0 = (tile & 3) * 8;
  int wv = tid >> 6, lane = tid & 63;
  int pr = lane >> 3, pc = lane & 7;
  int cwu = __builtin_amdgcn_readfirstlane(cog * 4 + wv);  // co-quad 0..15, wave-uniform
  const float4* wq = (const float4*)wT + ((size_t)par * 2048 + cwu) * 4;
  int cobase = cog * 16 + wv * 4;
  float acc[4] = {0.f, 0.f, 0.f, 0.f};
  const float* ob = o1 + (size_t)b * 128 * N1;
  for (int ch = 0; ch < 8; ch++) {
    __syncthreads();
    for (int e = tid; e < 16 * 81; e += 256) {
      int dx = e % 9; int t = e / 9;
      int dy = t % 9; int ci = t / 9;
      int iy = r0 + py - 1 + dy, ix = c0 + px - 1 + dx;
      float v = 0.f;
      if (iy >= 0 && iy < 31 && ix >= 0 && ix < 31)
        v = ob[(size_t)(ch * 16 + ci) * N1 + iy * 31 + ix];
      iS[ci][dy][dx] = v;
    }
    __syncthreads();
    #pragma unroll
    for (int ci = 0; ci < 16; ci++) {
      int cig = ch * 16 + ci;
      float4 w0 = wq[(size_t)cig * 64 + 0];
      float4 w1 = wq[(size_t)cig * 64 + 1];
      float4 w2 = wq[(size_t)cig * 64 + 2];
      float4 w3 = wq[(size_t)cig * 64 + 3];
      float x00 = iS[ci][pr][pc],     x01 = iS[ci][pr][pc + 1];
      float x10 = iS[ci][pr + 1][pc], x11 = iS[ci][pr + 1][pc + 1];
      acc[0] += w0.x * x00; acc[1] += w0.y * x00; acc[2] += w0.z * x00; acc[3] += w0.w * x00;
      acc[0] += w1.x * x01; acc[1] += w1.y * x01; acc[2] += w1.z * x01; acc[3] += w1.w * x01;
      acc[0] += w2.x * x10; acc[1] += w2.y * x10; acc[2] += w2.z * x10; acc[3] += w2.w * x10;
      acc[0] += w3.x * x11; acc[1] += w3.y * x11; acc[2] += w3.z * x11; acc[3] += w3.w * x11;
    }
  }
  int r = r0 + pr, c = c0 + pc;
  if (r >= 31 || c >= 31) return;
  int y = 2 * r + py, xx = 2 * c + px;
  #pragma unroll
  for (int cc = 0; cc < 4; cc++) {
    int co = cobase + cc;
    yacc[(size_t)(b * 64 + co) * HW2 + y * 62 + xx] = 2.0f * (acc[cc] + bias[co]);
  }
}

// attention 2: 4 rows/thread, strided 8-way m-split. grid = 64 bg x 8 chunks.
__global__ __launch_bounds__(256) void k_attn2(const float* __restrict__ yacc,
                                               const float* __restrict__ wqkv,
                                               const float* __restrict__ bqkv,
                                               const int* __restrict__ topk,
                                               float4* __restrict__ o2,
                                               int* __restrict__ coordg) {
  __shared__ float4 qvv[2 * N2];
  int tid = threadIdx.x;
  int chunk = blockIdx.x & 7;
  int bg = blockIdx.x >> 3;
  int b = bg >> 4, g = bg & 15;
  const float* yp0 = yacc + (size_t)(b * 64 + g * 4) * HW2;
  const int* ip = topk + (size_t)bg * KF;
  for (int nn = tid; nn < N2; nn += 256) {
    int tt = nn >> 2, i = (nn >> 1) & 1, j = nn & 1;
    int p = ip[tt];
    int ph = p / 31, pw = p - ph * 31;
    int cc = (2 * ph + i) * 62 + (2 * pw + j);
    float t0 = 0.5f * yp0[cc], t1 = 0.5f * yp0[HW2 + cc];
    float t2 = 0.5f * yp0[2 * HW2 + cc], t3 = 0.5f * yp0[3 * HW2 + cc];
    qvv[2 * nn]     = QKV_G(0);
    qvv[2 * nn + 1] = QKV_G(8);
  }
  __syncthreads();
  int wv = tid >> 6, lane = tid & 63;
  int oc = lane >> 3;
  int n0 = chunk * 128 + wv * 32 + (lane & 7);
  if (n0 >= N2) return;
  int nr[4]; int ccr[4]; bool vld[4];
  float4 kr[4];
  #pragma unroll
  for (int i2 = 0; i2 < 4; i2++) {
    int n = n0 + 8 * i2; nr[i2] = n; vld[i2] = n < N2;
    int nc = vld[i2] ? n : n0;
    int tt = nc >> 2, ii = (nc >> 1) & 1, jj = nc & 1;
    int p = ip[tt];
    int ph = p / 31, pw = p - ph * 31;
    int cc = (2 * ph + ii) * 62 + (2 * pw + jj);
    ccr[i2] = cc;
    float t0 = 0.5f * yp0[cc], t1 = 0.5f * yp0[HW2 + cc];
    float t2 = 0.5f * yp0[2 * HW2 + cc], t3 = 0.5f * yp0[3 * HW2 + cc];
    float4 kk = QKV_G(4);
    kr[i2] = make_float4(kk.x * L2E, kk.y * L2E, kk.z * L2E, kk.w * L2E);
  }
  v2f kax = {kr[0].x, kr[1].x}, kay = {kr[0].y, kr[1].y};
  v2f kaz = {kr[0].z, kr[1].z}, kaw = {kr[0].w, kr[1].w};
  v2f kbx = {kr[2].x, kr[3].x}, kby = {kr[2].y, kr[3].y};
  v2f kbz = {kr[2].z, kr[3].z}, kbw = {kr[2].w, kr[3].w};
  v2f suma = {0.f, 0.f}, sumb = {0.f, 0.f};
  v2f Aa0 = {0.f, 0.f}, Aa1 = {0.f, 0.f}, Aa2 = {0.f, 0.f}, Aa3 = {0.f, 0.f};
  v2f Ab0 = {0.f, 0.f}, Ab1 = {0.f, 0.f}, Ab2 = {0.f, 0.f}, Ab3 = {0.f, 0.f};
  #pragma unroll 4
  for (int m = oc; m < N2; m += 8) {
    float4 q = qvv[2 * m];
    float4 v = qvv[2 * m + 1];
    v2f sa = kax * q.x + kay * q.y + kaz * q.z + kaw * q.w;
    v2f sb = kbx * q.x + kby * q.y + kbz * q.z + kbw * q.w;
    v2f ea, eb;
    ea.x = __builtin_amdgcn_exp2f(sa.x); ea.y = __builtin_amdgcn_exp2f(sa.y);
    eb.x = __builtin_amdgcn_exp2f(sb.x); eb.y = __builtin_amdgcn_exp2f(sb.y);
    suma += ea; sumb += eb;
    Aa0 += ea * v.x; Aa1 += ea * v.y; Aa2 += ea * v.z; Aa3 += ea * v.w;
    Ab0 += eb * v.x; Ab1 += eb * v.y; Ab2 += eb * v.z; Ab3 += eb * v.w;
  }
  #pragma unroll
  for (int off = 8; off <= 32; off <<= 1) {
    red2(suma, off); red2(sumb, off);
    red2(Aa0, off); red2(Aa1, off); red2(Aa2, off); red2(Aa3, off);
    red2(Ab0, off); red2(Ab1, off); red2(Ab2, off); red2(Ab3, off);
  }
  if (oc != 0) return;
  float sums[4] = {suma.x, suma.y, sumb.x, sumb.y};
  float a0[4] = {Aa0.x, Aa0.y, Ab0.x, Ab0.y};
  float a1[4] = {Aa1.x, Aa1.y, Ab1.x, Ab1.y};
  float a2[4] = {Aa2.x, Aa2.y, Ab2.x, Ab2.y};
  float a3[4] = {Aa3.x, Aa3.y, Ab3.x, Ab3.y};
  #pragma unroll
  for (int i2 = 0; i2 < 4; i2++) {
    if (!vld[i2]) continue;
    float inv = 1.0f / sums[i2];
    size_t oi = (size_t)bg * N2 + nr[i2];
    o2[oi] = make_float4(a0[i2] * inv, a1[i2] * inv, a2[i2] * inv, a3[i2] * inv);
    coordg[oi] = ccr[i2];
  }
}

// scatter-add attn2 output into yacc (disjoint targets)
__global__ __launch_bounds__(256) void k_scatter(float* __restrict__ yacc,
                                                 const float4* __restrict__ o2,
                                                 const int* __restrict__ coordg) {
  int idx = blockIdx.x * 256 + threadIdx.x;
  if (idx >= 64 * N2) return;
  int bg = idx / N2;
  int b = bg >> 4, g = bg & 15;
  float4 o = o2[idx];
  int cc = coordg[idx];
  float* yp0 = yacc + (size_t)(b * 64 + g * 4) * HW2;
  yp0[cc] += o.x;
  yp0[HW2 + cc] += o.y;
  yp0[2 * HW2 + cc] += o.z;
  yp0[3 * HW2 + cc] += o.w;
}

__device__ __forceinline__ float wave_sum(float x) {
  #pragma unroll
  for (int off = 32; off > 0; off >>= 1) x += __shfl_xor(x, off, 64);
  return x;
}

// depthwise 3x3 + fused per-channel stats. grid = plane(256) x seg(4).
__global__ __launch_bounds__(256) void k_dwconv(const float* __restrict__ yin,
                                                const float* __restrict__ w,
                                                float* __restrict__ z1,
                                                float* __restrict__ stats) {
  __shared__ float red[8];
  int tid = threadIdx.x;
  int bid = blockIdx.x;
  int plane = bid >> 2, seg = bid & 3;  // plane = b*64 + c
  int c = plane & 63;
  const float* yp = yin + (size_t)plane * HW2;
  const float* wp = w + c * 9;  // uniform -> s_load
  float s = 0.f, s2 = 0.f;
  int i0 = seg * 961;
  for (int i = i0 + tid; i < i0 + 961; i += 256) {
    int y = i / 62, x = i - (i / 62) * 62;
    float acc = 0.f;
    #pragma unroll
    for (int ky = 0; ky < 3; ky++) {
      int yy = y + ky - 1;
      if (yy < 0 || yy > 61) continue;
      #pragma unroll
      for (int kx = 0; kx < 3; kx++) {
        int xx = x + kx - 1;
        if (xx < 0 || xx > 61) continue;
        acc += yp[yy * 62 + xx] * wp[ky * 3 + kx];
      }
    }
    z1[(size_t)plane * HW2 + i] = acc;
    s += acc; s2 += acc * acc;
  }
  s = wave_sum(s); s2 = wave_sum(s2);
  int wave = tid >> 6, lane = tid & 63;
  if (lane == 0) { red[wave] = s; red[4 + wave] = s2; }
  __syncthreads();
  if (tid == 0) {
    atomicAdd(&stats[c], red[0] + red[1] + red[2] + red[3]);
    atomicAdd(&stats[64 + c], red[4] + red[5] + red[6] + red[7]);
  }
}

// pointwise 1x1 + fused BN-param compute (from stats) + fused z2 stats.
// co-split x16 (4 co/block): grid = 61 x 16
__global__ __launch_bounds__(256) void k_pwconv(const float* __restrict__ z1,
                                                const float* __restrict__ wpw,
                                                const float* __restrict__ stats,
                                                const float* __restrict__ gdw,
                                                const float* __restrict__ bedw,
                                                float* __restrict__ z2,
                                                float* __restrict__ stats2) {
  __shared__ float w[4 * 64];
  __shared__ float aa[64], cb[64];
  __shared__ float redS[4][4], redQ[4][4];
  int tid = threadIdx.x;
  int cog = blockIdx.x & 15;
  int pb = blockIdx.x >> 4;
  if (tid < 64) {
    float m = stats[tid] * (1.0f / NPIX);
    float v = stats[64 + tid] * (1.0f / NPIX) - m * m;
    float a = gdw[tid] * rsqrtf(v + 1e-5f);
    aa[tid] = a; cb[tid] = bedw[tid] - m * a;
  }
  for (int i = tid; i < 256; i += 256) w[i] = wpw[cog * 256 + i];
  __syncthreads();
  int pix = pb * 256 + tid;
  bool valid = pix < NPIX;
  int pixc = valid ? pix : NPIX - 1;
  int b = pixc / HW2, p = pixc - b * HW2;
  float h[64];
  #pragma unroll
  for (int ci = 0; ci < 64; ci++) {
    float z = z1[(size_t)(b * 64 + ci) * HW2 + p];
    z = aa[ci] * z + cb[ci];
    h[ci] = fminf(fmaxf(z, 0.f), 6.f);
  }
  float ssum[4], ssq[4];
  #pragma unroll
  for (int cc = 0; cc < 4; cc++) {
    float acc = 0.f;
    #pragma unroll
    for (int ci = 0; ci < 64; ci++) acc += h[ci] * w[cc * 64 + ci];
    if (valid) z2[(size_t)(b * 64 + cog * 4 + cc) * HW2 + p] = acc;
    ssum[cc] = valid ? acc : 0.f;
    ssq[cc] = valid ? acc * acc : 0.f;
  }
  int wv = tid >> 6, lane = tid & 63;
  #pragma unroll
  for (int cc = 0; cc < 4; cc++) {
    ssum[cc] = wave_sum(ssum[cc]);
    ssq[cc] = wave_sum(ssq[cc]);
  }
  if (lane == 0) {
    #pragma unroll
    for (int cc = 0; cc < 4; cc++) { redS[wv][cc] = ssum[cc]; redQ[wv][cc] = ssq[cc]; }
  }
  __syncthreads();
  if (tid < 4) {
    float ts = redS[0][tid] + redS[1][tid] + redS[2][tid] + redS[3][tid];
    float tq = redQ[0][tid] + redQ[1][tid] + redQ[2][tid] + redQ[3][tid];
    atomicAdd(&stats2[cog * 4 + tid], ts);
    atomicAdd(&stats2[64 + cog * 4 + tid], tq);
  }
}

// final BN+relu6, BN params computed inline from stats2
__global__ __launch_bounds__(256) void k_final(const float* __restrict__ z2,
                                               const float* __restrict__ stats2,
                                               const float* __restrict__ gpw,
                                               const float* __restrict__ bepw,
                                               float* __restrict__ out) {
  int idx = blockIdx.x * 256 + threadIdx.x;
  if (idx >= 64 * NPIX) return;
  int c = (idx / HW2) & 63;
  float m = stats2[c] * (1.0f / NPIX);
  float v = stats2[64 + c] * (1.0f / NPIX) - m * m;
  float a = gpw[c] * rsqrtf(v + 1e-5f);
  float z = a * z2[idx] + (bepw[c] - m * a);
  out[idx] = fminf(fmaxf(z, 0.f), 6.f);
}

extern "C" void kernel_launch(void* const* d_in, const int* in_sizes, int n_in,
                              void* d_out, int out_size, void* d_ws, size_t ws_size,
                              hipStream_t stream) {
  const float* x       = (const float*)d_in[0];
  const float* w_down  = (const float*)d_in[1];
  const float* b_down  = (const float*)d_in[2];
  const float* w_qkv_c = (const float*)d_in[3];
  const float* b_qkv_c = (const float*)d_in[4];
  const float* w_up    = (const float*)d_in[5];
  const float* b_up    = (const float*)d_in[6];
  const float* w_qkv_t = (const float*)d_in[7];
  const float* b_qkv_t = (const float*)d_in[8];
  const float* w_dw    = (const float*)d_in[9];
  const float* g_dw    = (const float*)d_in[10];
  const float* be_dw   = (const float*)d_in[11];
  const float* w_pw    = (const float*)d_in[12];
  const float* g_pw    = (const float*)d_in[13];
  const float* be_pw   = (const float*)d_in[14];
  float* out = (float*)d_out;

  float* ws    = (float*)d_ws;
  float* xd    = ws;                       // 492032 = 4*128*961
  float* o1    = xd + 492032;              // 492032
  int*   topk  = (int*)(o1 + 492032);      // 15360 = 4*16*240
  float* yacc  = (float*)(topk + 15360);   // 984064 = 4*64*62*62
  float* z1    = yacc + 984064;            // 984064
  float* z2    = z1 + 984064;              // 984064
  float* stats = z2 + 984064;              // 256
  float* wT    = stats + 256;              // 131072 (dedicated)
  float* wdT   = wT + 131072;              // 131072 (dedicated)

  // disjoint-lifetime aliases:
  // k_down partials (pre-combine): o1, yacc, yacc+492032 (3 partials) + xd (4th)
  float*  rowstat = z1;                    // 4*16*961 floats (post-combine)
  float*  coarse  = z1 + 61504;            // 4*16*961 floats
  float4* o2      = (float4*)z2;           // 4*16*960 float4
  int*    coordg  = (int*)(z2 + 245760);   // 61440 ints

  k_wtr<<<1024, 256, 0, stream>>>(w_up, w_down, wT, wdT, stats);
  k_down<<<512, 256, 0, stream>>>(x, wdT, o1, yacc, yacc + 492032, xd);
  k_combine<<<(XDSZ + 255) / 256, 256, 0, stream>>>(o1, yacc, yacc + 492032,
                                                    b_down, xd);
  k_attn1<<<512, 256, 0, stream>>>(xd, w_qkv_c, b_qkv_c, o1, rowstat);
  k_coarse<<<512, 256, 0, stream>>>(xd, w_qkv_c, b_qkv_c, rowstat, coarse);
  k_topk<<<64, 1024, 0, stream>>>(coarse, topk);
  k_upconv<<<1024, 256, 0, stream>>>(o1, wT, b_up, yacc);
  k_attn2<<<512, 256, 0, stream>>>(yacc, w_qkv_t, b_qkv_t, topk, o2, coordg);
  k_scatter<<<(64 * N2 + 255) / 256, 256, 0, stream>>>(yacc, o2, coordg);
  k_dwconv<<<1024, 256, 0, stream>>>(yacc, w_dw, z1, stats);
  k_pwconv<<<61 * 16, 256, 0, stream>>>(z1, w_pw, stats, g_dw, be_dw, z2, stats + 128);
  k_final<<<(64 * NPIX + 255) / 256, 256, 0, stream>>>(z2, stats + 128, g_pw, be_pw, out);
}

// Round 7
// 277.715 us; speedup vs baseline: 1.1399x; 1.0467x over previous
//
#include <hip/hip_runtime.h>
#include <math.h>

#define N1 961
#define N2 960
#define KF 240
#define HW2 3844   // 62*62
#define NPIX 15376 // 4*62*62
#define XDSZ 492032 // 4*128*961
#define L2E 1.44269504f

typedef float v2f __attribute__((ext_vector_type(2)));

// down conv: 2x2 px x 4 co per thread, K-split x8 (1024 blocks = 4/CU).
// Weights via SCALAR path from pre-transposed wdT.
__global__ __launch_bounds__(256) void k_down(const float* __restrict__ x,
                                              const float* __restrict__ wdT,
                                              float* __restrict__ p0, float* __restrict__ p1,
                                              float* __restrict__ p2, float* __restrict__ p3,
                                              float* __restrict__ p4, float* __restrict__ p5,
                                              float* __restrict__ p6, float* __restrict__ p7) {
  __shared__ float iS[4][18][72];
  int tid = threadIdx.x;
  int bid = blockIdx.x;
  int kchunk = bid & 7;
  int rowtile = (bid >> 3) & 3;
  int cog = (bid >> 5) & 7;
  int b = bid >> 8;
  int r0 = rowtile * 8;
  int wv = tid >> 6, lane = tid & 63;
  int pc = lane & 15, pr = lane >> 4;
  int qd = __builtin_amdgcn_readfirstlane(cog * 4 + wv);
  const float4* wqd = (const float4*)wdT + (size_t)qd * 1024;  // 64 ci x 16 taps
  float acc[4][4];  // [px][co]
  #pragma unroll
  for (int i = 0; i < 4; i++)
    #pragma unroll
    for (int j = 0; j < 4; j++) acc[i][j] = 0.f;
  const float* xb = x + (size_t)b * 64 * 4096;
  for (int sub = 0; sub < 2; sub++) {
    int cibase = kchunk * 8 + sub * 4;
    __syncthreads();
    for (int e = tid; e < 4 * 18 * 66; e += 256) {
      int dx = e % 66; int t = e / 66;
      int dy = t % 18; int ci = t / 18;
      int iy = 2 * r0 + dy;
      iS[ci][dy][dx] = (dx < 64 && iy < 64)
                           ? xb[(size_t)(cibase + ci) * 4096 + iy * 64 + dx] : 0.f;
    }
    __syncthreads();
    #pragma unroll
    for (int ci = 0; ci < 4; ci++) {
      const float4* wc = wqd + (size_t)(cibase + ci) * 16;  // uniform -> s_load
      float xr[6][6];
      #pragma unroll
      for (int rr = 0; rr < 6; rr++)
        #pragma unroll
        for (int jj = 0; jj < 3; jj++) {
          float2 v2 = *(const float2*)&iS[ci][4 * pr + rr][4 * pc + 2 * jj];
          xr[rr][2 * jj] = v2.x; xr[rr][2 * jj + 1] = v2.y;
        }
      #pragma unroll
      for (int ky = 0; ky < 4; ky++)
        #pragma unroll
        for (int kx = 0; kx < 4; kx++) {
          float4 wq = wc[ky * 4 + kx];  // SGPR
          #pragma unroll
          for (int dy2 = 0; dy2 < 2; dy2++)
            #pragma unroll
            for (int dx2 = 0; dx2 < 2; dx2++) {
              float xv = xr[2 * dy2 + ky][2 * dx2 + kx];
              int px = dy2 * 2 + dx2;
              acc[px][0] += wq.x * xv; acc[px][1] += wq.y * xv;
              acc[px][2] += wq.z * xv; acc[px][3] += wq.w * xv;
            }
        }
    }
  }
  float* parts[8] = {p0, p1, p2, p3, p4, p5, p6, p7};
  float* xo = parts[kchunk] + (size_t)b * 128 * N1;
  #pragma unroll
  for (int dy2 = 0; dy2 < 2; dy2++) {
    int r = r0 + 2 * pr + dy2;
    if (r >= 31) continue;
    #pragma unroll
    for (int dx2 = 0; dx2 < 2; dx2++) {
      int c = 2 * pc + dx2;
      if (c >= 31) continue;
      #pragma unroll
      for (int cc = 0; cc < 4; cc++)
        xo[(size_t)(cog * 16 + wv * 4 + cc) * N1 + r * 31 + c] = acc[dy2 * 2 + dx2][cc];
    }
  }
}

// combine 7 K-partials + xd(8th partial) + bias -> xd
__global__ __launch_bounds__(256) void k_combine(const float* __restrict__ p0,
                                                 const float* __restrict__ p1,
                                                 const float* __restrict__ p2,
                                                 const float* __restrict__ p3,
                                                 const float* __restrict__ p4,
                                                 const float* __restrict__ p5,
                                                 const float* __restrict__ p6,
                                                 const float* __restrict__ bias,
                                                 float* __restrict__ xd) {
  int i = blockIdx.x * 256 + threadIdx.x;
  if (i >= XDSZ) return;
  int co = (i / N1) & 127;
  float s = ((p0[i] + p1[i]) + (p2[i] + p3[i])) + ((p4[i] + p5[i]) + (p6[i] + xd[i]));
  xd[i] = bias[co] + s;
}

// weight pre-transposes (upconv wT + downconv wdT) + stats zeroing.
__global__ __launch_bounds__(256) void k_wtr(const float* __restrict__ wup,
                                             const float* __restrict__ wdn,
                                             float* __restrict__ wT,
                                             float* __restrict__ wdT,
                                             float* __restrict__ stats) {
  int tid = threadIdx.x;
  int bid = blockIdx.x;
  if (bid == 0) stats[tid] = 0.f;
  if (bid < 512) {
    int idx = bid * 256 + tid;
    int c = idx & 3;
    int t = (idx >> 2) & 3;
    int cw = (idx >> 4) & 15;
    int ci = (idx >> 8) & 127;
    int par = idx >> 15;
    int py = par >> 1, px = par & 1;
    int a = t >> 1, d = t & 1;
    int tap = (3 - (py + 2 * a)) * 4 + (3 - (px + 2 * d));
    int co = cw * 4 + c;
    wT[idx] = wup[(size_t)ci * 1024 + co * 16 + tap];
  } else {
    int idx = (bid - 512) * 256 + tid;
    int c = idx & 3;
    int tap = (idx >> 2) & 15;
    int ci = (idx >> 6) & 63;
    int q = idx >> 12;  // 0..31
    wdT[idx] = wdn[(size_t)(q * 4 + c) * 1024 + ci * 16 + tap];
  }
}

// QKV projection with weights via SCALAR path (uniform s_load -> SGPR operand).
#define QKV_G(off) make_float4( \
    t0 * wqkv[(off)] + t1 * wqkv[12 + (off)] + t2 * wqkv[24 + (off)] + t3 * wqkv[36 + (off)] + bqkv[(off)], \
    t0 * wqkv[(off)+1] + t1 * wqkv[12 + (off)+1] + t2 * wqkv[24 + (off)+1] + t3 * wqkv[36 + (off)+1] + bqkv[(off)+1], \
    t0 * wqkv[(off)+2] + t1 * wqkv[12 + (off)+2] + t2 * wqkv[24 + (off)+2] + t3 * wqkv[36 + (off)+2] + bqkv[(off)+2], \
    t0 * wqkv[(off)+3] + t1 * wqkv[12 + (off)+3] + t2 * wqkv[24 + (off)+3] + t3 * wqkv[36 + (off)+3] + bqkv[(off)+3])

__device__ __forceinline__ void red2(v2f& a, int off) {
  a.x += __shfl_xor(a.x, off, 64);
  a.y += __shfl_xor(a.y, off, 64);
}

// attention 1: 8 rows/thread (4x v2f pairs), strided 8-way m-split.
// grid = 128 bg x 4 chunks (256 rows/block).
__global__ __launch_bounds__(256) void k_attn1(const float* __restrict__ xd,
                                               const float* __restrict__ wqkv,
                                               const float* __restrict__ bqkv,
                                               float* __restrict__ o1,
                                               float* __restrict__ rowstat) {
  __shared__ float4 qvv[2 * N1];
  int tid = threadIdx.x;
  int chunk = blockIdx.x & 3;
  int bg = blockIdx.x >> 2;
  int b = bg >> 5, g = bg & 31;
  const float* xp0 = xd + (size_t)(b * 128 + g * 4) * N1;
  for (int nn = tid; nn < N1; nn += 256) {
    float t0 = xp0[nn], t1 = xp0[N1 + nn], t2 = xp0[2 * N1 + nn], t3 = xp0[3 * N1 + nn];
    qvv[2 * nn]     = QKV_G(0);
    qvv[2 * nn + 1] = QKV_G(8);
  }
  __syncthreads();
  int wv = tid >> 6, lane = tid & 63;
  int oc = lane >> 3;
  int n0 = chunk * 256 + wv * 64 + (lane & 7);
  if (n0 >= N1) return;  // reduce-partners share n0 -> exit together
  int nr[8]; bool vld[8];
  float4 kr[8];
  #pragma unroll
  for (int i2 = 0; i2 < 8; i2++) {
    int n = n0 + 8 * i2; nr[i2] = n; vld[i2] = n < N1;
    int nc = vld[i2] ? n : n0;
    float t0 = xp0[nc], t1 = xp0[N1 + nc], t2 = xp0[2 * N1 + nc], t3 = xp0[3 * N1 + nc];
    float4 kk = QKV_G(4);
    kr[i2] = make_float4(kk.x * L2E, kk.y * L2E, kk.z * L2E, kk.w * L2E);
  }
  v2f kx[4], ky[4], kz[4], kw[4];
  #pragma unroll
  for (int p = 0; p < 4; p++) {
    kx[p] = (v2f){kr[2*p].x, kr[2*p+1].x};
    ky[p] = (v2f){kr[2*p].y, kr[2*p+1].y};
    kz[p] = (v2f){kr[2*p].z, kr[2*p+1].z};
    kw[p] = (v2f){kr[2*p].w, kr[2*p+1].w};
  }
  v2f sum[4], A0[4], A1[4], A2[4], A3[4];
  #pragma unroll
  for (int p = 0; p < 4; p++) {
    sum[p] = (v2f){0.f, 0.f};
    A0[p] = (v2f){0.f, 0.f}; A1[p] = (v2f){0.f, 0.f};
    A2[p] = (v2f){0.f, 0.f}; A3[p] = (v2f){0.f, 0.f};
  }
  #pragma unroll 2
  for (int m = oc; m < N1; m += 8) {
    float4 q = qvv[2 * m];
    float4 v = qvv[2 * m + 1];
    #pragma unroll
    for (int p = 0; p < 4; p++) {
      v2f s = kx[p] * q.x + ky[p] * q.y + kz[p] * q.z + kw[p] * q.w;
      v2f e;
      e.x = __builtin_amdgcn_exp2f(s.x);
      e.y = __builtin_amdgcn_exp2f(s.y);
      sum[p] += e;
      A0[p] += e * v.x; A1[p] += e * v.y; A2[p] += e * v.z; A3[p] += e * v.w;
    }
  }
  #pragma unroll
  for (int off = 8; off <= 32; off <<= 1) {
    #pragma unroll
    for (int p = 0; p < 4; p++) {
      red2(sum[p], off);
      red2(A0[p], off); red2(A1[p], off); red2(A2[p], off); red2(A3[p], off);
    }
  }
  if (oc != 0) return;
  float* o1p = o1 + (size_t)(b * 128 + g * 4) * N1;
  #pragma unroll
  for (int i2 = 0; i2 < 8; i2++) {
    if (!vld[i2]) continue;
    int p = i2 >> 1;
    int n = nr[i2];
    float sv = (i2 & 1) ? sum[p].y : sum[p].x;
    float inv = 1.0f / sv;
    float a0 = (i2 & 1) ? A0[p].y : A0[p].x;
    float a1 = (i2 & 1) ? A1[p].y : A1[p].x;
    float a2 = (i2 & 1) ? A2[p].y : A2[p].x;
    float a3 = (i2 & 1) ? A3[p].y : A3[p].x;
    o1p[n] = a0 * inv;
    o1p[N1 + n] = a1 * inv;
    o1p[2 * N1 + n] = a2 * inv;
    o1p[3 * N1 + n] = a3 * inv;
    if (g < 16) rowstat[(size_t)(b * 16 + g) * N1 + n] = inv;
  }
}

// coarse: 8 cols/thread, strided 16-way n-split. grid = 64 bg x 8 chunks.
__global__ __launch_bounds__(256) void k_coarse(const float* __restrict__ xd,
                                                const float* __restrict__ wqkv,
                                                const float* __restrict__ bqkv,
                                                const float* __restrict__ rowstat,
                                                float* __restrict__ coarse) {
  __shared__ float4 kS[N1];
  __shared__ float rs[N1];
  int tid = threadIdx.x;
  int chunk = blockIdx.x & 7;
  int bg = blockIdx.x >> 3;
  int b = bg >> 4, g = bg & 15;
  const float* xp0 = xd + (size_t)(b * 128 + g * 4) * N1;
  const float* rp = rowstat + (size_t)(b * 16 + g) * N1;
  for (int nn = tid; nn < N1; nn += 256) {
    float t0 = xp0[nn], t1 = xp0[N1 + nn], t2 = xp0[2 * N1 + nn], t3 = xp0[3 * N1 + nn];
    kS[nn] = QKV_G(4);
    rs[nn] = rp[nn];
  }
  __syncthreads();
  int wv = tid >> 6, lane = tid & 63;
  int oc = lane >> 2;
  int c0 = chunk * 128 + wv * 32 + (lane & 3);
  if (c0 >= N1) return;  // reduce-partners share c0 -> exit together
  int cr[8]; bool vld[8];
  float4 qr[8];
  #pragma unroll
  for (int i2 = 0; i2 < 8; i2++) {
    int c = c0 + 4 * i2; cr[i2] = c; vld[i2] = c < N1;
    int cc = vld[i2] ? c : c0;
    float t0 = xp0[cc], t1 = xp0[N1 + cc], t2 = xp0[2 * N1 + cc], t3 = xp0[3 * N1 + cc];
    float4 qq = QKV_G(0);
    qr[i2] = make_float4(qq.x * L2E, qq.y * L2E, qq.z * L2E, qq.w * L2E);
  }
  v2f qx[4], qy[4], qz[4], qw[4];
  #pragma unroll
  for (int p = 0; p < 4; p++) {
    qx[p] = (v2f){qr[2*p].x, qr[2*p+1].x};
    qy[p] = (v2f){qr[2*p].y, qr[2*p+1].y};
    qz[p] = (v2f){qr[2*p].z, qr[2*p+1].z};
    qw[p] = (v2f){qr[2*p].w, qr[2*p+1].w};
  }
  v2f cs[4];
  #pragma unroll
  for (int p = 0; p < 4; p++) cs[p] = (v2f){0.f, 0.f};
  #pragma unroll 2
  for (int n = oc; n < N1; n += 16) {
    float4 k = kS[n];
    float r = rs[n];
    #pragma unroll
    for (int p = 0; p < 4; p++) {
      v2f s = qx[p] * k.x + qy[p] * k.y + qz[p] * k.z + qw[p] * k.w;
      v2f e;
      e.x = __builtin_amdgcn_exp2f(s.x);
      e.y = __builtin_amdgcn_exp2f(s.y);
      cs[p] += e * r;
    }
  }
  #pragma unroll
  for (int off = 4; off <= 32; off <<= 1) {
    #pragma unroll
    for (int p = 0; p < 4; p++) red2(cs[p], off);
  }
  if (oc != 0) return;
  float* cp = coarse + (size_t)(b * 16 + g) * N1;
  #pragma unroll
  for (int i2 = 0; i2 < 8; i2++) {
    if (!vld[i2]) continue;
    int p = i2 >> 1;
    cp[cr[i2]] = (i2 & 1) ? cs[p].y : cs[p].x;
  }
}

// top-240 per (b,g<16): bitonic over 1024 packed keys, 1024 threads (1 elem/thread)
__global__ __launch_bounds__(1024) void k_topk(const float* __restrict__ coarse,
                                               int* __restrict__ topk) {
  __shared__ unsigned long long keys[1024];
  int tid = threadIdx.x;
  int bg = blockIdx.x;
  const float* cp = coarse + (size_t)bg * N1;
  {
    unsigned long long key = 0ull;
    if (tid < N1) {
      unsigned fb = __float_as_uint(cp[tid]);
      key = ((unsigned long long)fb << 32) | (unsigned)(N1 - 1 - tid);
    }
    keys[tid] = key;
  }
  __syncthreads();
  for (int k2 = 2; k2 <= 1024; k2 <<= 1) {
    for (int j = k2 >> 1; j > 0; j >>= 1) {
      int i = tid;
      int ixj = i ^ j;
      if (ixj > i) {
        unsigned long long a = keys[i], bb = keys[ixj];
        bool up = ((i & k2) == 0);
        if ((a > bb) == up) { keys[i] = bb; keys[ixj] = a; }
      }
      __syncthreads();
    }
  }
  if (tid < KF) {
    unsigned long long key = keys[1023 - tid];
    topk[(size_t)bg * KF + tid] = (N1 - 1) - (int)(unsigned)(key & 0xffffffffull);
  }
}

// transposed conv, per-parity: o1(4,128,31,31) -> yacc = 2*coarse_out (4,64,62,62)
__global__ __launch_bounds__(256) void k_upconv(const float* __restrict__ o1,
                                                const float* __restrict__ wT,
                                                const float* __restrict__ bias,
                                                float* __restrict__ yacc) {
  __shared__ float iS[16][9][12];
  int tid = threadIdx.x;
  int bid = blockIdx.x;
  int b = bid >> 8;
  int cog = (bid >> 6) & 3;
  int par = (bid >> 4) & 3;
  int py = par >> 1, px = par & 1;
  int tile = bid & 15;
  int r0 = (tile >> 2) * 8, c0 = (tile & 3) * 8;
  int wv = tid >> 6, lane = tid & 63;
  int pr = lane >> 3, pc = lane & 7;
  int cwu = __builtin_amdgcn_readfirstlane(cog * 4 + wv);  // co-quad 0..15, wave-uniform
  const float4* wq = (const float4*)wT + ((size_t)par * 2048 + cwu) * 4;
  int cobase = cog * 16 + wv * 4;
  float acc[4] = {0.f, 0.f, 0.f, 0.f};
  const float* ob = o1 + (size_t)b * 128 * N1;
  for (int ch = 0; ch < 8; ch++) {
    __syncthreads();
    for (int e = tid; e < 16 * 81; e += 256) {
      int dx = e % 9; int t = e / 9;
      int dy = t % 9; int ci = t / 9;
      int iy = r0 + py - 1 + dy, ix = c0 + px - 1 + dx;
      float v = 0.f;
      if (iy >= 0 && iy < 31 && ix >= 0 && ix < 31)
        v = ob[(size_t)(ch * 16 + ci) * N1 + iy * 31 + ix];
      iS[ci][dy][dx] = v;
    }
    __syncthreads();
    #pragma unroll
    for (int ci = 0; ci < 16; ci++) {
      int cig = ch * 16 + ci;
      float4 w0 = wq[(size_t)cig * 64 + 0];
      float4 w1 = wq[(size_t)cig * 64 + 1];
      float4 w2 = wq[(size_t)cig * 64 + 2];
      float4 w3 = wq[(size_t)cig * 64 + 3];
      float x00 = iS[ci][pr][pc],     x01 = iS[ci][pr][pc + 1];
      float x10 = iS[ci][pr + 1][pc], x11 = iS[ci][pr + 1][pc + 1];
      acc[0] += w0.x * x00; acc[1] += w0.y * x00; acc[2] += w0.z * x00; acc[3] += w0.w * x00;
      acc[0] += w1.x * x01; acc[1] += w1.y * x01; acc[2] += w1.z * x01; acc[3] += w1.w * x01;
      acc[0] += w2.x * x10; acc[1] += w2.y * x10; acc[2] += w2.z * x10; acc[3] += w2.w * x10;
      acc[0] += w3.x * x11; acc[1] += w3.y * x11; acc[2] += w3.z * x11; acc[3] += w3.w * x11;
    }
  }
  int r = r0 + pr, c = c0 + pc;
  if (r >= 31 || c >= 31) return;
  int y = 2 * r + py, xx = 2 * c + px;
  #pragma unroll
  for (int cc = 0; cc < 4; cc++) {
    int co = cobase + cc;
    yacc[(size_t)(b * 64 + co) * HW2 + y * 62 + xx] = 2.0f * (acc[cc] + bias[co]);
  }
}

// attention 2: 4 rows/thread, strided 8-way m-split. grid = 64 bg x 8 chunks.
__global__ __launch_bounds__(256) void k_attn2(const float* __restrict__ yacc,
                                               const float* __restrict__ wqkv,
                                               const float* __restrict__ bqkv,
                                               const int* __restrict__ topk,
                                               float4* __restrict__ o2,
                                               int* __restrict__ coordg) {
  __shared__ float4 qvv[2 * N2];
  int tid = threadIdx.x;
  int chunk = blockIdx.x & 7;
  int bg = blockIdx.x >> 3;
  int b = bg >> 4, g = bg & 15;
  const float* yp0 = yacc + (size_t)(b * 64 + g * 4) * HW2;
  const int* ip = topk + (size_t)bg * KF;
  for (int nn = tid; nn < N2; nn += 256) {
    int tt = nn >> 2, i = (nn >> 1) & 1, j = nn & 1;
    int p = ip[tt];
    int ph = p / 31, pw = p - ph * 31;
    int cc = (2 * ph + i) * 62 + (2 * pw + j);
    float t0 = 0.5f * yp0[cc], t1 = 0.5f * yp0[HW2 + cc];
    float t2 = 0.5f * yp0[2 * HW2 + cc], t3 = 0.5f * yp0[3 * HW2 + cc];
    qvv[2 * nn]     = QKV_G(0);
    qvv[2 * nn + 1] = QKV_G(8);
  }
  __syncthreads();
  int wv = tid >> 6, lane = tid & 63;
  int oc = lane >> 3;
  int n0 = chunk * 128 + wv * 32 + (lane & 7);
  if (n0 >= N2) return;
  int nr[4]; int ccr[4]; bool vld[4];
  float4 kr[4];
  #pragma unroll
  for (int i2 = 0; i2 < 4; i2++) {
    int n = n0 + 8 * i2; nr[i2] = n; vld[i2] = n < N2;
    int nc = vld[i2] ? n : n0;
    int tt = nc >> 2, ii = (nc >> 1) & 1, jj = nc & 1;
    int p = ip[tt];
    int ph = p / 31, pw = p - ph * 31;
    int cc = (2 * ph + ii) * 62 + (2 * pw + jj);
    ccr[i2] = cc;
    float t0 = 0.5f * yp0[cc], t1 = 0.5f * yp0[HW2 + cc];
    float t2 = 0.5f * yp0[2 * HW2 + cc], t3 = 0.5f * yp0[3 * HW2 + cc];
    float4 kk = QKV_G(4);
    kr[i2] = make_float4(kk.x * L2E, kk.y * L2E, kk.z * L2E, kk.w * L2E);
  }
  v2f kax = {kr[0].x, kr[1].x}, kay = {kr[0].y, kr[1].y};
  v2f kaz = {kr[0].z, kr[1].z}, kaw = {kr[0].w, kr[1].w};
  v2f kbx = {kr[2].x, kr[3].x}, kby = {kr[2].y, kr[3].y};
  v2f kbz = {kr[2].z, kr[3].z}, kbw = {kr[2].w, kr[3].w};
  v2f suma = {0.f, 0.f}, sumb = {0.f, 0.f};
  v2f Aa0 = {0.f, 0.f}, Aa1 = {0.f, 0.f}, Aa2 = {0.f, 0.f}, Aa3 = {0.f, 0.f};
  v2f Ab0 = {0.f, 0.f}, Ab1 = {0.f, 0.f}, Ab2 = {0.f, 0.f}, Ab3 = {0.f, 0.f};
  #pragma unroll 4
  for (int m = oc; m < N2; m += 8) {
    float4 q = qvv[2 * m];
    float4 v = qvv[2 * m + 1];
    v2f sa = kax * q.x + kay * q.y + kaz * q.z + kaw * q.w;
    v2f sb = kbx * q.x + kby * q.y + kbz * q.z + kbw * q.w;
    v2f ea, eb;
    ea.x = __builtin_amdgcn_exp2f(sa.x); ea.y = __builtin_amdgcn_exp2f(sa.y);
    eb.x = __builtin_amdgcn_exp2f(sb.x); eb.y = __builtin_amdgcn_exp2f(sb.y);
    suma += ea; sumb += eb;
    Aa0 += ea * v.x; Aa1 += ea * v.y; Aa2 += ea * v.z; Aa3 += ea * v.w;
    Ab0 += eb * v.x; Ab1 += eb * v.y; Ab2 += eb * v.z; Ab3 += eb * v.w;
  }
  #pragma unroll
  for (int off = 8; off <= 32; off <<= 1) {
    red2(suma, off); red2(sumb, off);
    red2(Aa0, off); red2(Aa1, off); red2(Aa2, off); red2(Aa3, off);
    red2(Ab0, off); red2(Ab1, off); red2(Ab2, off); red2(Ab3, off);
  }
  if (oc != 0) return;
  float sums[4] = {suma.x, suma.y, sumb.x, sumb.y};
  float a0[4] = {Aa0.x, Aa0.y, Ab0.x, Ab0.y};
  float a1[4] = {Aa1.x, Aa1.y, Ab1.x, Ab1.y};
  float a2[4] = {Aa2.x, Aa2.y, Ab2.x, Ab2.y};
  float a3[4] = {Aa3.x, Aa3.y, Ab3.x, Ab3.y};
  #pragma unroll
  for (int i2 = 0; i2 < 4; i2++) {
    if (!vld[i2]) continue;
    float inv = 1.0f / sums[i2];
    size_t oi = (size_t)bg * N2 + nr[i2];
    o2[oi] = make_float4(a0[i2] * inv, a1[i2] * inv, a2[i2] * inv, a3[i2] * inv);
    coordg[oi] = ccr[i2];
  }
}

// scatter-add attn2 output into yacc (disjoint targets)
__global__ __launch_bounds__(256) void k_scatter(float* __restrict__ yacc,
                                                 const float4* __restrict__ o2,
                                                 const int* __restrict__ coordg) {
  int idx = blockIdx.x * 256 + threadIdx.x;
  if (idx >= 64 * N2) return;
  int bg = idx / N2;
  int b = bg >> 4, g = bg & 15;
  float4 o = o2[idx];
  int cc = coordg[idx];
  float* yp0 = yacc + (size_t)(b * 64 + g * 4) * HW2;
  yp0[cc] += o.x;
  yp0[HW2 + cc] += o.y;
  yp0[2 * HW2 + cc] += o.z;
  yp0[3 * HW2 + cc] += o.w;
}

__device__ __forceinline__ float wave_sum(float x) {
  #pragma unroll
  for (int off = 32; off > 0; off >>= 1) x += __shfl_xor(x, off, 64);
  return x;
}

// depthwise 3x3 + fused per-channel stats. grid = plane(256) x seg(4).
__global__ __launch_bounds__(256) void k_dwconv(const float* __restrict__ yin,
                                                const float* __restrict__ w,
                                                float* __restrict__ z1,
                                                float* __restrict__ stats) {
  __shared__ float red[8];
  int tid = threadIdx.x;
  int bid = blockIdx.x;
  int plane = bid >> 2, seg = bid & 3;  // plane = b*64 + c
  int c = plane & 63;
  const float* yp = yin + (size_t)plane * HW2;
  const float* wp = w + c * 9;  // uniform -> s_load
  float s = 0.f, s2 = 0.f;
  int i0 = seg * 961;
  for (int i = i0 + tid; i < i0 + 961; i += 256) {
    int y = i / 62, x = i - (i / 62) * 62;
    float acc = 0.f;
    #pragma unroll
    for (int ky = 0; ky < 3; ky++) {
      int yy = y + ky - 1;
      if (yy < 0 || yy > 61) continue;
      #pragma unroll
      for (int kx = 0; kx < 3; kx++) {
        int xx = x + kx - 1;
        if (xx < 0 || xx > 61) continue;
        acc += yp[yy * 62 + xx] * wp[ky * 3 + kx];
      }
    }
    z1[(size_t)plane * HW2 + i] = acc;
    s += acc; s2 += acc * acc;
  }
  s = wave_sum(s); s2 = wave_sum(s2);
  int wave = tid >> 6, lane = tid & 63;
  if (lane == 0) { red[wave] = s; red[4 + wave] = s2; }
  __syncthreads();
  if (tid == 0) {
    atomicAdd(&stats[c], red[0] + red[1] + red[2] + red[3]);
    atomicAdd(&stats[64 + c], red[4] + red[5] + red[6] + red[7]);
  }
}

// pointwise 1x1 + fused BN-param compute (from stats) + fused z2 stats.
// co-split x16 (4 co/block): grid = 61 x 16
__global__ __launch_bounds__(256) void k_pwconv(const float* __restrict__ z1,
                                                const float* __restrict__ wpw,
                                                const float* __restrict__ stats,
                                                const float* __restrict__ gdw,
                                                const float* __restrict__ bedw,
                                                float* __restrict__ z2,
                                                float* __restrict__ stats2) {
  __shared__ float w[4 * 64];
  __shared__ float aa[64], cb[64];
  __shared__ float redS[4][4], redQ[4][4];
  int tid = threadIdx.x;
  int cog = blockIdx.x & 15;
  int pb = blockIdx.x >> 4;
  if (tid < 64) {
    float m = stats[tid] * (1.0f / NPIX);
    float v = stats[64 + tid] * (1.0f / NPIX) - m * m;
    float a = gdw[tid] * rsqrtf(v + 1e-5f);
    aa[tid] = a; cb[tid] = bedw[tid] - m * a;
  }
  for (int i = tid; i < 256; i += 256) w[i] = wpw[cog * 256 + i];
  __syncthreads();
  int pix = pb * 256 + tid;
  bool valid = pix < NPIX;
  int pixc = valid ? pix : NPIX - 1;
  int b = pixc / HW2, p = pixc - b * HW2;
  float h[64];
  #pragma unroll
  for (int ci = 0; ci < 64; ci++) {
    float z = z1[(size_t)(b * 64 + ci) * HW2 + p];
    z = aa[ci] * z + cb[ci];
    h[ci] = fminf(fmaxf(z, 0.f), 6.f);
  }
  float ssum[4], ssq[4];
  #pragma unroll
  for (int cc = 0; cc < 4; cc++) {
    float acc = 0.f;
    #pragma unroll
    for (int ci = 0; ci < 64; ci++) acc += h[ci] * w[cc * 64 + ci];
    if (valid) z2[(size_t)(b * 64 + cog * 4 + cc) * HW2 + p] = acc;
    ssum[cc] = valid ? acc : 0.f;
    ssq[cc] = valid ? acc * acc : 0.f;
  }
  int wv = tid >> 6, lane = tid & 63;
  #pragma unroll
  for (int cc = 0; cc < 4; cc++) {
    ssum[cc] = wave_sum(ssum[cc]);
    ssq[cc] = wave_sum(ssq[cc]);
  }
  if (lane == 0) {
    #pragma unroll
    for (int cc = 0; cc < 4; cc++) { redS[wv][cc] = ssum[cc]; redQ[wv][cc] = ssq[cc]; }
  }
  __syncthreads();
  if (tid < 4) {
    float ts = redS[0][tid] + redS[1][tid] + redS[2][tid] + redS[3][tid];
    float tq = redQ[0][tid] + redQ[1][tid] + redQ[2][tid] + redQ[3][tid];
    atomicAdd(&stats2[cog * 4 + tid], ts);
    atomicAdd(&stats2[64 + cog * 4 + tid], tq);
  }
}

// final BN+relu6, BN params computed inline from stats2
__global__ __launch_bounds__(256) void k_final(const float* __restrict__ z2,
                                               const float* __restrict__ stats2,
                                               const float* __restrict__ gpw,
                                               const float* __restrict__ bepw,
                                               float* __restrict__ out) {
  int idx = blockIdx.x * 256 + threadIdx.x;
  if (idx >= 64 * NPIX) return;
  int c = (idx / HW2) & 63;
  float m = stats2[c] * (1.0f / NPIX);
  float v = stats2[64 + c] * (1.0f / NPIX) - m * m;
  float a = gpw[c] * rsqrtf(v + 1e-5f);
  float z = a * z2[idx] + (bepw[c] - m * a);
  out[idx] = fminf(fmaxf(z, 0.f), 6.f);
}

extern "C" void kernel_launch(void* const* d_in, const int* in_sizes, int n_in,
                              void* d_out, int out_size, void* d_ws, size_t ws_size,
                              hipStream_t stream) {
  const float* x       = (const float*)d_in[0];
  const float* w_down  = (const float*)d_in[1];
  const float* b_down  = (const float*)d_in[2];
  const float* w_qkv_c = (const float*)d_in[3];
  const float* b_qkv_c = (const float*)d_in[4];
  const float* w_up    = (const float*)d_in[5];
  const float* b_up    = (const float*)d_in[6];
  const float* w_qkv_t = (const float*)d_in[7];
  const float* b_qkv_t = (const float*)d_in[8];
  const float* w_dw    = (const float*)d_in[9];
  const float* g_dw    = (const float*)d_in[10];
  const float* be_dw   = (const float*)d_in[11];
  const float* w_pw    = (const float*)d_in[12];
  const float* g_pw    = (const float*)d_in[13];
  const float* be_pw   = (const float*)d_in[14];
  float* out = (float*)d_out;

  float* ws    = (float*)d_ws;
  float* xd    = ws;                       // 492032 = 4*128*961
  float* o1    = xd + 492032;              // 492032
  int*   topk  = (int*)(o1 + 492032);      // 15360 = 4*16*240
  float* yacc  = (float*)(topk + 15360);   // 984064 = 4*64*62*62
  float* z1    = yacc + 984064;            // 984064
  float* z2    = z1 + 984064;              // 984064
  float* stats = z2 + 984064;              // 256
  float* wT    = stats + 256;              // 131072 (dedicated)
  float* wdT   = wT + 131072;              // 131072 (dedicated)

  // disjoint-lifetime aliases:
  // k_down partials (pre-combine): o1, yacc(x2), z1(x2), z2(x2) + xd (8th)
  float*  rowstat = z1;                    // 4*16*961 floats (post-combine)
  float*  coarse  = z1 + 61504;            // 4*16*961 floats
  float4* o2      = (float4*)z2;           // 4*16*960 float4
  int*    coordg  = (int*)(z2 + 245760);   // 61440 ints

  k_wtr<<<1024, 256, 0, stream>>>(w_up, w_down, wT, wdT, stats);
  k_down<<<1024, 256, 0, stream>>>(x, wdT,
                                   o1, yacc, yacc + 492032, z1, z1 + 492032,
                                   z2, z2 + 492032, xd);
  k_combine<<<(XDSZ + 255) / 256, 256, 0, stream>>>(o1, yacc, yacc + 492032, z1,
                                                    z1 + 492032, z2, z2 + 492032,
                                                    b_down, xd);
  k_attn1<<<512, 256, 0, stream>>>(xd, w_qkv_c, b_qkv_c, o1, rowstat);
  k_coarse<<<512, 256, 0, stream>>>(xd, w_qkv_c, b_qkv_c, rowstat, coarse);
  k_topk<<<64, 1024, 0, stream>>>(coarse, topk);
  k_upconv<<<1024, 256, 0, stream>>>(o1, wT, b_up, yacc);
  k_attn2<<<512, 256, 0, stream>>>(yacc, w_qkv_t, b_qkv_t, topk, o2, coordg);
  k_scatter<<<(64 * N2 + 255) / 256, 256, 0, stream>>>(yacc, o2, coordg);
  k_dwconv<<<1024, 256, 0, stream>>>(yacc, w_dw, z1, stats);
  k_pwconv<<<61 * 16, 256, 0, stream>>>(z1, w_pw, stats, g_dw, be_dw, z2, stats + 128);
  k_final<<<(64 * NPIX + 255) / 256, 256, 0, stream>>>(z2, stats + 128, g_pw, be_pw, out);
}